// Round 1
// baseline (1648.055 us; speedup 1.0000x reference)
//
#include <hip/hip_runtime.h>
#include <math.h>

#define N_NODES 100000
#define N_EDGES 600000
#define H 128
#define LH 256
#define CDIM 8
#define NB_STATS 256

// ---------------- workspace layout (in 4-byte words) ----------------
// partials: NB_STATS*11 | params: 8 | h0: N*3 | deg: N (int) | agg1: N*3 |
// h1: N*H | buf2: N*H (agg2, then h2 in-place) | Wl2T: H*H | Wr2T: H*H | W1T: H*LH
#define OFF_PART   0
#define OFF_PARAMS (OFF_PART + NB_STATS*11)
#define OFF_H0     (OFF_PARAMS + 8)
#define OFF_DEG    (OFF_H0 + N_NODES*3)
#define OFF_AGG1   (OFF_DEG + N_NODES)
#define OFF_H1     (OFF_AGG1 + N_NODES*3)
#define OFF_BUF2   (OFF_H1 + (size_t)N_NODES*H)
#define OFF_WL2T   (OFF_BUF2 + (size_t)N_NODES*H)
#define OFF_WR2T   (OFF_WL2T + H*H)
#define OFF_W1T    (OFF_WR2T + H*H)
#define OFF_END    (OFF_W1T + H*LH)
// total ~26.4M words = ~105.5 MB

__device__ __forceinline__ float rot_c() {
    const float theta = 1.57079632679489661923f;
    return cosf(theta);
}
__device__ __forceinline__ float rot_s() {
    const float theta = 1.57079632679489661923f;
    return sinf(theta);
}

// 11 stats: mn0, mx0, mn1, mx1, s0, s1, sr0, sr1, mxr0, mxr1, mxa
__global__ void stats_partial_k(const float* __restrict__ x, float* __restrict__ part) {
    const float c = rot_c(), sn = rot_s();
    float mn0 = INFINITY, mx0 = -INFINITY, mn1 = INFINITY, mx1 = -INFINITY;
    float s0 = 0.f, s1 = 0.f, sr0 = 0.f, sr1 = 0.f;
    float mxr0 = -INFINITY, mxr1 = -INFINITY, mxa = -INFINITY;
    for (int i = blockIdx.x * blockDim.x + threadIdx.x; i < N_NODES;
         i += gridDim.x * blockDim.x) {
        float x0 = x[3*i], x1 = x[3*i+1], a = x[3*i+2];
        float r0 = c*x0 - sn*x1;
        float r1 = sn*x0 + c*x1;
        mn0 = fminf(mn0, x0); mx0 = fmaxf(mx0, x0);
        mn1 = fminf(mn1, x1); mx1 = fmaxf(mx1, x1);
        s0 += x0; s1 += x1; sr0 += r0; sr1 += r1;
        mxr0 = fmaxf(mxr0, r0); mxr1 = fmaxf(mxr1, r1);
        mxa = fmaxf(mxa, a);
    }
    __shared__ float red[256];
    float vals[11] = {mn0, mx0, mn1, mx1, s0, s1, sr0, sr1, mxr0, mxr1, mxa};
    const int ops[11] = {0,1,0,1,2,2,2,2,1,1,1}; // 0=min 1=max 2=sum
    for (int v = 0; v < 11; v++) {
        red[threadIdx.x] = vals[v];
        __syncthreads();
        for (int s = 128; s > 0; s >>= 1) {
            if ((int)threadIdx.x < s) {
                float a = red[threadIdx.x], b = red[threadIdx.x + s];
                red[threadIdx.x] = (ops[v] == 0) ? fminf(a, b)
                                 : (ops[v] == 1) ? fmaxf(a, b) : (a + b);
            }
            __syncthreads();
        }
        if (threadIdx.x == 0) part[blockIdx.x * 11 + v] = red[0];
        __syncthreads();
    }
}

__global__ void stats_final_k(const float* __restrict__ part, float* __restrict__ params) {
    __shared__ float red[256];
    __shared__ float res[11];
    float vals[11];
    for (int v = 0; v < 11; v++) vals[v] = part[threadIdx.x * 11 + v];
    const int ops[11] = {0,1,0,1,2,2,2,2,1,1,1};
    for (int v = 0; v < 11; v++) {
        red[threadIdx.x] = vals[v];
        __syncthreads();
        for (int s = 128; s > 0; s >>= 1) {
            if ((int)threadIdx.x < s) {
                float a = red[threadIdx.x], b = red[threadIdx.x + s];
                red[threadIdx.x] = (ops[v] == 0) ? fminf(a, b)
                                 : (ops[v] == 1) ? fmaxf(a, b) : (a + b);
            }
            __syncthreads();
        }
        if (threadIdx.x == 0) res[v] = red[0];
        __syncthreads();
    }
    if (threadIdx.x == 0) {
        float mn0 = res[0], mx0 = res[1], mn1 = res[2], mx1 = res[3];
        float s0 = res[4], s1 = res[5], sr0 = res[6], sr1 = res[7];
        float mxr0 = res[8], mxr1 = res[9], mxa = res[10];
        int rotate = (mx1 - mn1) > (mx0 - mn0);
        params[0] = (float)rotate;
        params[1] = (rotate ? sr0 : s0) / (float)N_NODES;
        params[2] = (rotate ? sr1 : s1) / (float)N_NODES;
        params[3] = rotate ? mxr0 : mx0;
        params[4] = rotate ? mxr1 : mx1;
        params[5] = mxa;
    }
}

__global__ void normalize_k(const float* __restrict__ x, const float* __restrict__ params,
                            float* __restrict__ h0) {
    int i = blockIdx.x * blockDim.x + threadIdx.x;
    if (i >= N_NODES) return;
    const float c = rot_c(), sn = rot_s();
    float x0 = x[3*i], x1 = x[3*i+1], a = x[3*i+2];
    bool rot = params[0] != 0.f;
    float u0 = rot ? (c*x0 - sn*x1) : x0;
    float u1 = rot ? (sn*x0 + c*x1) : x1;
    h0[3*i]   = (u0 - params[1]) / params[3];
    h0[3*i+1] = (u1 - params[2]) / params[4];
    h0[3*i+2] = a / params[5];
}

__global__ void edge1_k(const int* __restrict__ ei, const float* __restrict__ h0,
                        float* __restrict__ agg1, int* __restrict__ deg) {
    int e = blockIdx.x * blockDim.x + threadIdx.x;
    if (e >= N_EDGES) return;
    int s = ei[e], d = ei[N_EDGES + e];
    atomicAdd(&agg1[3*d],   h0[3*s]);
    atomicAdd(&agg1[3*d+1], h0[3*s+1]);
    atomicAdd(&agg1[3*d+2], h0[3*s+2]);
    atomicAdd(&deg[d], 1);
}

__global__ void conv1_k(const float* __restrict__ h0, const float* __restrict__ agg1,
                        const int* __restrict__ deg,
                        const float* __restrict__ Wl1, const float* __restrict__ bl1,
                        const float* __restrict__ Wr1, float* __restrict__ h1) {
    int n = blockIdx.x, j = threadIdx.x;
    float inv = 1.0f / (float)max(deg[n], 1);
    float a0 = agg1[3*n] * inv, a1 = agg1[3*n+1] * inv, a2 = agg1[3*n+2] * inv;
    float x0 = h0[3*n], x1 = h0[3*n+1], x2 = h0[3*n+2];
    float acc = Wl1[3*j]*a0 + Wl1[3*j+1]*a1 + Wl1[3*j+2]*a2 + bl1[j]
              + Wr1[3*j]*x0 + Wr1[3*j+1]*x1 + Wr1[3*j+2]*x2;
    h1[(size_t)n*H + j] = tanhf(acc);
}

__global__ void edge2_k(const int* __restrict__ ei, const float* __restrict__ h1,
                        float* __restrict__ buf2) {
    int e = blockIdx.x, j = threadIdx.x;
    int s = ei[e], d = ei[N_EDGES + e];
    atomicAdd(&buf2[(size_t)d*H + j], h1[(size_t)s*H + j]);
}

// buf2 holds agg2 on entry, h2 on exit (in-place; block owns its row)
__global__ void conv2_k(float* __restrict__ buf2, const float* __restrict__ h1,
                        const int* __restrict__ deg,
                        const float* __restrict__ Wl2T, const float* __restrict__ Wr2T,
                        const float* __restrict__ bl2) {
    int n = blockIdx.x, j = threadIdx.x;
    __shared__ float sa[H];
    __shared__ float sh[H];
    float inv = 1.0f / (float)max(deg[n], 1);
    sa[j] = buf2[(size_t)n*H + j] * inv;
    sh[j] = h1[(size_t)n*H + j];
    __syncthreads();
    float acc = bl2[j];
    #pragma unroll 8
    for (int k = 0; k < H; k++) {
        acc += Wl2T[k*H + j] * sa[k] + Wr2T[k*H + j] * sh[k];
    }
    buf2[(size_t)n*H + j] = tanhf(acc);
}

__global__ void mlp_k(const float* __restrict__ buf2, const float* __restrict__ W1T,
                      const float* __restrict__ b1, const float* __restrict__ W2,
                      const float* __restrict__ b2, float* __restrict__ out) {
    int n = blockIdx.x, j = threadIdx.x;
    __shared__ float sh2[H];
    __shared__ float st[LH];
    __shared__ float slog[CDIM];
    if (j < H) sh2[j] = buf2[(size_t)n*H + j];
    __syncthreads();
    float acc = b1[j];
    #pragma unroll 8
    for (int k = 0; k < H; k++) acc += W1T[k*LH + j] * sh2[k];
    st[j] = tanhf(acc);
    __syncthreads();
    if (j < CDIM) {
        float lg = b2[j];
        for (int k = 0; k < LH; k++) lg += W2[j*LH + k] * st[k];
        slog[j] = lg;
    }
    __syncthreads();
    if (j == 0) {
        float m = -INFINITY;
        for (int q = 0; q < CDIM; q++) m = fmaxf(m, slog[q]);
        float ssum = 0.f;
        float ex[CDIM];
        for (int q = 0; q < CDIM; q++) { ex[q] = expf(slog[q] - m); ssum += ex[q]; }
        for (int q = 0; q < CDIM; q++) out[(size_t)n*CDIM + q] = ex[q] / ssum;
    }
}

__global__ void transpose_k(const float* __restrict__ Wl2, const float* __restrict__ Wr2,
                            const float* __restrict__ W1,
                            float* __restrict__ Wl2T, float* __restrict__ Wr2T,
                            float* __restrict__ W1T) {
    int i = blockIdx.x * blockDim.x + threadIdx.x;
    if (i < H*H) {
        int j = i / H, k = i % H;
        Wl2T[k*H + j] = Wl2[i];
        Wr2T[k*H + j] = Wr2[i];
    }
    if (i < LH*H) {
        int j = i / H, k = i % H;   // W1 is (LH, H): row j, col k
        W1T[k*LH + j] = W1[i];
    }
}

extern "C" void kernel_launch(void* const* d_in, const int* in_sizes, int n_in,
                              void* d_out, int out_size, void* d_ws, size_t ws_size,
                              hipStream_t stream) {
    const float* x   = (const float*)d_in[0];
    const int*   ei  = (const int*)d_in[1];
    const float* Wl1 = (const float*)d_in[2];
    const float* bl1 = (const float*)d_in[3];
    const float* Wr1 = (const float*)d_in[4];
    const float* Wl2 = (const float*)d_in[5];
    const float* bl2 = (const float*)d_in[6];
    const float* Wr2 = (const float*)d_in[7];
    const float* W1  = (const float*)d_in[8];
    const float* b1  = (const float*)d_in[9];
    const float* W2  = (const float*)d_in[10];
    const float* b2  = (const float*)d_in[11];

    float* ws     = (float*)d_ws;
    float* part   = ws + OFF_PART;
    float* params = ws + OFF_PARAMS;
    float* h0     = ws + OFF_H0;
    int*   deg    = (int*)(ws + OFF_DEG);
    float* agg1   = ws + OFF_AGG1;
    float* h1     = ws + OFF_H1;
    float* buf2   = ws + OFF_BUF2;
    float* Wl2T   = ws + OFF_WL2T;
    float* Wr2T   = ws + OFF_WR2T;
    float* W1T    = ws + OFF_W1T;

    // zero deg + agg1 (contiguous 4N words) and buf2 (agg2 accumulator)
    hipMemsetAsync(deg, 0, (size_t)(4 * N_NODES) * sizeof(float), stream);
    hipMemsetAsync(buf2, 0, (size_t)N_NODES * H * sizeof(float), stream);

    transpose_k<<<(LH*H + 255) / 256, 256, 0, stream>>>(Wl2, Wr2, W1, Wl2T, Wr2T, W1T);
    stats_partial_k<<<NB_STATS, 256, 0, stream>>>(x, part);
    stats_final_k<<<1, 256, 0, stream>>>(part, params);
    normalize_k<<<(N_NODES + 255) / 256, 256, 0, stream>>>(x, params, h0);
    edge1_k<<<(N_EDGES + 255) / 256, 256, 0, stream>>>(ei, h0, agg1, deg);
    conv1_k<<<N_NODES, H, 0, stream>>>(h0, agg1, deg, Wl1, bl1, Wr1, h1);
    edge2_k<<<N_EDGES, H, 0, stream>>>(ei, h1, buf2);
    conv2_k<<<N_NODES, H, 0, stream>>>(buf2, h1, deg, Wl2T, Wr2T, bl2);
    mlp_k<<<N_NODES, LH, 0, stream>>>(buf2, W1T, b1, W2, b2, out_size ? (float*)d_out : (float*)d_out);
}

// Round 2
// 595.554 us; speedup vs baseline: 2.7673x; 2.7673x over previous
//
#include <hip/hip_runtime.h>
#include <math.h>

#define N_NODES 100000
#define N_EDGES 600000
#define H 128
#define LH 256
#define CDIM 8
#define NB_STATS 64

// ------------- workspace layout (4-byte words) -------------
// part: 64*11 | params: 8 | deg: N int | rowptr: N int | bsums: 128 |
// X2: N*256 fp32  (row = [h0(3)/agg2(128) | h1(128)] -> h2 in first half)
// csr_src (600000 int) lives in d_out transiently (dead before mlp writes out).
#define OFF_PART   0
#define OFF_PARAMS 704
#define OFF_DEG    712
#define OFF_ROWPTR (OFF_DEG + N_NODES)
#define OFF_BSUMS  (OFF_ROWPTR + N_NODES)
#define OFF_X2     (OFF_BSUMS + 128)          // 200840, %4==0 -> float4-aligned
// end = 200840 + 25,600,000 = 25,800,840 words = 103.2 MB (< 105.5 MB proven)

__device__ __forceinline__ float rot_c() { return cosf(1.57079632679489661923f); }
__device__ __forceinline__ float rot_s() { return sinf(1.57079632679489661923f); }

// ---------------- stats (11): mn0,mx0,mn1,mx1,s0,s1,sr0,sr1,mxr0,mxr1,mxa ----
__global__ void stats_partial_k(const float* __restrict__ x, float* __restrict__ part) {
    const float c = rot_c(), sn = rot_s();
    float mn0 = INFINITY, mx0 = -INFINITY, mn1 = INFINITY, mx1 = -INFINITY;
    float s0 = 0.f, s1 = 0.f, sr0 = 0.f, sr1 = 0.f;
    float mxr0 = -INFINITY, mxr1 = -INFINITY, mxa = -INFINITY;
    for (int i = blockIdx.x * blockDim.x + threadIdx.x; i < N_NODES;
         i += gridDim.x * blockDim.x) {
        float x0 = x[3*i], x1 = x[3*i+1], a = x[3*i+2];
        float r0 = c*x0 - sn*x1;
        float r1 = sn*x0 + c*x1;
        mn0 = fminf(mn0, x0); mx0 = fmaxf(mx0, x0);
        mn1 = fminf(mn1, x1); mx1 = fmaxf(mx1, x1);
        s0 += x0; s1 += x1; sr0 += r0; sr1 += r1;
        mxr0 = fmaxf(mxr0, r0); mxr1 = fmaxf(mxr1, r1);
        mxa = fmaxf(mxa, a);
    }
    __shared__ float red[256];
    float vals[11] = {mn0, mx0, mn1, mx1, s0, s1, sr0, sr1, mxr0, mxr1, mxa};
    const int ops[11] = {0,1,0,1,2,2,2,2,1,1,1};
    for (int v = 0; v < 11; v++) {
        red[threadIdx.x] = vals[v];
        __syncthreads();
        for (int s = 128; s > 0; s >>= 1) {
            if ((int)threadIdx.x < s) {
                float a = red[threadIdx.x], b = red[threadIdx.x + s];
                red[threadIdx.x] = (ops[v]==0) ? fminf(a,b) : (ops[v]==1) ? fmaxf(a,b) : (a+b);
            }
            __syncthreads();
        }
        if (threadIdx.x == 0) part[blockIdx.x * 11 + v] = red[0];
        __syncthreads();
    }
}

__global__ void stats_final_k(const float* __restrict__ part, float* __restrict__ params) {
    __shared__ float red[64];
    __shared__ float res[11];
    const int ops[11] = {0,1,0,1,2,2,2,2,1,1,1};
    for (int v = 0; v < 11; v++) {
        red[threadIdx.x] = part[threadIdx.x * 11 + v];
        __syncthreads();
        for (int s = 32; s > 0; s >>= 1) {
            if ((int)threadIdx.x < s) {
                float a = red[threadIdx.x], b = red[threadIdx.x + s];
                red[threadIdx.x] = (ops[v]==0) ? fminf(a,b) : (ops[v]==1) ? fmaxf(a,b) : (a+b);
            }
            __syncthreads();
        }
        if (threadIdx.x == 0) res[v] = red[0];
        __syncthreads();
    }
    if (threadIdx.x == 0) {
        int rotate = (res[3] - res[2]) > (res[1] - res[0]);
        params[0] = (float)rotate;
        params[1] = (rotate ? res[6] : res[4]) / (float)N_NODES;
        params[2] = (rotate ? res[7] : res[5]) / (float)N_NODES;
        params[3] = rotate ? res[8] : res[1];
        params[4] = rotate ? res[9] : res[3];
        params[5] = res[10];
    }
}

// h0 -> X2[n*256 + 0..2]
__global__ void normalize_k(const float* __restrict__ x, const float* __restrict__ params,
                            float* __restrict__ X2) {
    int i = blockIdx.x * blockDim.x + threadIdx.x;
    if (i >= N_NODES) return;
    const float c = rot_c(), sn = rot_s();
    float x0 = x[3*i], x1 = x[3*i+1], a = x[3*i+2];
    bool rot = params[0] != 0.f;
    float u0 = rot ? (c*x0 - sn*x1) : x0;
    float u1 = rot ? (sn*x0 + c*x1) : x1;
    X2[(size_t)i*256 + 0] = (u0 - params[1]) / params[3];
    X2[(size_t)i*256 + 1] = (u1 - params[2]) / params[4];
    X2[(size_t)i*256 + 2] = a / params[5];
}

// ---------------- CSR build ----------------
__global__ void deg_count_k(const int* __restrict__ ei, int* __restrict__ deg) {
    int e = blockIdx.x * blockDim.x + threadIdx.x;
    if (e >= N_EDGES) return;
    atomicAdd(&deg[ei[N_EDGES + e]], 1);
}

// exclusive scan of deg -> rowptr (per-block, 1024 elems/block), bsums = block totals
__global__ void scan1_k(const int* __restrict__ deg, int* __restrict__ rowptr,
                        int* __restrict__ bsums) {
    __shared__ int s[256];
    int t = threadIdx.x;
    int base = blockIdx.x * 1024 + t * 4;
    int d0 = (base+0 < N_NODES) ? deg[base+0] : 0;
    int d1 = (base+1 < N_NODES) ? deg[base+1] : 0;
    int d2 = (base+2 < N_NODES) ? deg[base+2] : 0;
    int d3 = (base+3 < N_NODES) ? deg[base+3] : 0;
    int tsum = d0 + d1 + d2 + d3;
    s[t] = tsum;
    __syncthreads();
    for (int off = 1; off < 256; off <<= 1) {
        int v = (t >= off) ? s[t - off] : 0;
        __syncthreads();
        s[t] += v;
        __syncthreads();
    }
    int excl = s[t] - tsum;
    if (base+0 < N_NODES) rowptr[base+0] = excl;
    if (base+1 < N_NODES) rowptr[base+1] = excl + d0;
    if (base+2 < N_NODES) rowptr[base+2] = excl + d0 + d1;
    if (base+3 < N_NODES) rowptr[base+3] = excl + d0 + d1 + d2;
    if (t == 255) bsums[blockIdx.x] = s[255];
}

__global__ void scan2_k(int* __restrict__ bsums, int nb) {
    if (threadIdx.x == 0 && blockIdx.x == 0) {
        int run = 0;
        for (int b = 0; b < nb; b++) { int v = bsums[b]; bsums[b] = run; run += v; }
    }
}

__global__ void scan3_k(int* __restrict__ rowptr, const int* __restrict__ bsums) {
    int t = threadIdx.x;
    int base = blockIdx.x * 1024 + t * 4;
    int add = bsums[blockIdx.x];
    if (base+0 < N_NODES) rowptr[base+0] += add;
    if (base+1 < N_NODES) rowptr[base+1] += add;
    if (base+2 < N_NODES) rowptr[base+2] += add;
    if (base+3 < N_NODES) rowptr[base+3] += add;
}

// scatter edges by dst. rowptr[d] is the cursor; afterwards rowptr[n] = end(n),
// start(n) = rowptr[n] - deg[n].
__global__ void scatter_k(const int* __restrict__ ei, int* __restrict__ rowptr,
                          int* __restrict__ csr) {
    int e = blockIdx.x * blockDim.x + threadIdx.x;
    if (e >= N_EDGES) return;
    int d = ei[N_EDGES + e];
    int pos = atomicAdd(&rowptr[d], 1);
    csr[pos] = ei[e];
}

// ---------------- conv1 (agg over h0 + tiny dense), writes h1 -> X2[n][128..255]
__global__ void conv1_k(float* __restrict__ X2, const int* __restrict__ rowptr,
                        const int* __restrict__ deg, const int* __restrict__ csr,
                        const float* __restrict__ Wl1, const float* __restrict__ bl1,
                        const float* __restrict__ Wr1) {
    int n = blockIdx.x;
    int j = threadIdx.x;
    int dg = deg[n];
    int end = rowptr[n], start = end - dg;
    float a0 = 0.f, a1 = 0.f, a2 = 0.f;
    for (int e = start; e < end; e++) {
        int s = csr[e];
        a0 += X2[(size_t)s*256 + 0];
        a1 += X2[(size_t)s*256 + 1];
        a2 += X2[(size_t)s*256 + 2];
    }
    float inv = 1.0f / (float)max(dg, 1);
    a0 *= inv; a1 *= inv; a2 *= inv;
    float x0 = X2[(size_t)n*256 + 0], x1 = X2[(size_t)n*256 + 1], x2 = X2[(size_t)n*256 + 2];
    float acc = Wl1[3*j]*a0 + Wl1[3*j+1]*a1 + Wl1[3*j+2]*a2 + bl1[j]
              + Wr1[3*j]*x0 + Wr1[3*j+1]*x1 + Wr1[3*j+2]*x2;
    X2[(size_t)n*256 + 128 + j] = tanhf(acc);
}

// ---------------- agg2: mean of h1 over in-neighbors -> X2[n][0..127]
__global__ void agg2_k(float* __restrict__ X2, const int* __restrict__ rowptr,
                       const int* __restrict__ deg, const int* __restrict__ csr) {
    int lane = threadIdx.x & 63;
    int n = blockIdx.x * 4 + (threadIdx.x >> 6);
    int dg = deg[n];
    int end = rowptr[n], start = end - dg;
    float acc0 = 0.f, acc1 = 0.f;
    for (int e = start; e < end; e++) {
        int s = csr[e];
        float2 v = *(const float2*)&X2[(size_t)s*256 + 128 + lane*2];
        acc0 += v.x; acc1 += v.y;
    }
    float inv = 1.0f / (float)max(dg, 1);
    float2 o; o.x = acc0 * inv; o.y = acc1 * inv;
    *(float2*)&X2[(size_t)n*256 + lane*2] = o;
}

// ---------------- conv2 GEMM: h2 = tanh(X2[N x 256] @ W'[256 x 128] + bl2)
// W' rows 0..127 = Wl2^T, 128..255 = Wr2^T (transposed during LDS staging).
// Output written in-place into X2[n][0..127].
#define C2_MT 64
#define C2_KC 32
#define C2_AP (C2_MT + 4)   // 68
#define C2_WP (H + 4)       // 132
__global__ __launch_bounds__(256) void conv2_gemm_k(float* __restrict__ X2,
        const float* __restrict__ Wl2, const float* __restrict__ Wr2,
        const float* __restrict__ bl2) {
    __shared__ float At[C2_KC * C2_AP];
    __shared__ float Wt[C2_KC * C2_WP];
    int tid = threadIdx.x;
    int n0 = blockIdx.x * C2_MT;
    int mg = tid >> 4;   // 0..15 -> rows mg*4..mg*4+3
    int ng = tid & 15;   // 0..15 -> cols ng*8..ng*8+7
    float acc[4][8];
    #pragma unroll
    for (int r = 0; r < 4; r++)
        #pragma unroll
        for (int i = 0; i < 8; i++) acc[r][i] = 0.f;

    for (int kc = 0; kc < 256; kc += C2_KC) {
        #pragma unroll
        for (int l = 0; l < 2; l++) {           // A: 64x32 = 512 float4
            int idx = l*256 + tid;
            int m = idx >> 3, kq = idx & 7;
            int node = n0 + m;
            float4 v = make_float4(0.f,0.f,0.f,0.f);
            if (node < N_NODES) v = *(const float4*)&X2[(size_t)node*256 + kc + kq*4];
            int kk = kq * 4;
            At[(kk+0)*C2_AP + m] = v.x;
            At[(kk+1)*C2_AP + m] = v.y;
            At[(kk+2)*C2_AP + m] = v.z;
            At[(kk+3)*C2_AP + m] = v.w;
        }
        const float* Wsrc = (kc < 128) ? Wl2 : Wr2;
        int kbase = (kc < 128) ? kc : (kc - 128);
        #pragma unroll
        for (int l = 0; l < 4; l++) {           // W: 32x128 = 1024 float4
            int idx = l*256 + tid;
            int j = idx >> 3, kq = idx & 7;
            float4 v = *(const float4*)&Wsrc[j*H + kbase + kq*4];
            int kk = kq * 4;
            Wt[(kk+0)*C2_WP + j] = v.x;
            Wt[(kk+1)*C2_WP + j] = v.y;
            Wt[(kk+2)*C2_WP + j] = v.z;
            Wt[(kk+3)*C2_WP + j] = v.w;
        }
        __syncthreads();
        #pragma unroll
        for (int kk = 0; kk < C2_KC; kk++) {
            float a4[4], w8[8];
            *(float4*)a4     = *(const float4*)&At[kk*C2_AP + mg*4];
            *(float4*)w8     = *(const float4*)&Wt[kk*C2_WP + ng*8];
            *(float4*)(w8+4) = *(const float4*)&Wt[kk*C2_WP + ng*8 + 4];
            #pragma unroll
            for (int r = 0; r < 4; r++)
                #pragma unroll
                for (int i = 0; i < 8; i++) acc[r][i] += a4[r] * w8[i];
        }
        __syncthreads();
    }
    #pragma unroll
    for (int r = 0; r < 4; r++) {
        int node = n0 + mg*4 + r;
        if (node < N_NODES) {
            #pragma unroll
            for (int i = 0; i < 8; i++) {
                int j = ng*8 + i;
                X2[(size_t)node*256 + j] = tanhf(acc[r][i] + bl2[j]);
            }
        }
    }
}

// ---------------- fused MLP: t = tanh(h2@W1^T + b1); logits = t@W2^T + b2; softmax
#define ML_MT 32
#define ML_KC 32
#define ML_AP (ML_MT + 4)   // 36
#define ML_WP (LH + 4)      // 260
__global__ __launch_bounds__(256) void mlp_k(const float* __restrict__ X2,
        const float* __restrict__ W1, const float* __restrict__ b1,
        const float* __restrict__ W2, const float* __restrict__ b2,
        float* __restrict__ out) {
    __shared__ float At[ML_KC * ML_AP];     // 4608 B
    __shared__ float WT[ML_KC * ML_WP];     // 33280 B, reused as T[32][260]
    __shared__ float W2s[CDIM * ML_WP];     // 8320 B
    __shared__ float llog[ML_MT * CDIM];    // 1024 B
    int tid = threadIdx.x;
    int n0 = blockIdx.x * ML_MT;
    int mg = tid >> 5;   // 0..7  -> rows mg*4..+3
    int ng = tid & 31;   // 0..31 -> cols ng*8..+7
    // preload W2 (8x256) into LDS, padded stride
    #pragma unroll
    for (int l = 0; l < 8; l++) {
        int i = l*256 + tid;      // 0..2047
        W2s[(i >> 8) * ML_WP + (i & 255)] = W2[i];
    }
    float acc[4][8];
    #pragma unroll
    for (int r = 0; r < 4; r++)
        #pragma unroll
        for (int i = 0; i < 8; i++) acc[r][i] = 0.f;

    for (int kc = 0; kc < H; kc += ML_KC) {
        {   // A: 32x32 = 256 float4, 1/thread
            int m = tid >> 3, kq = tid & 7;
            int node = n0 + m;
            float4 v = make_float4(0.f,0.f,0.f,0.f);
            if (node < N_NODES) v = *(const float4*)&X2[(size_t)node*256 + kc + kq*4];
            int kk = kq * 4;
            At[(kk+0)*ML_AP + m] = v.x;
            At[(kk+1)*ML_AP + m] = v.y;
            At[(kk+2)*ML_AP + m] = v.z;
            At[(kk+3)*ML_AP + m] = v.w;
        }
        #pragma unroll
        for (int l = 0; l < 8; l++) {           // W1: 32x256 = 2048 float4
            int idx = l*256 + tid;
            int j = idx >> 3, kq = idx & 7;
            float4 v = *(const float4*)&W1[j*H + kc + kq*4];
            int kk = kq * 4;
            WT[(kk+0)*ML_WP + j] = v.x;
            WT[(kk+1)*ML_WP + j] = v.y;
            WT[(kk+2)*ML_WP + j] = v.z;
            WT[(kk+3)*ML_WP + j] = v.w;
        }
        __syncthreads();
        #pragma unroll
        for (int kk = 0; kk < ML_KC; kk++) {
            float a4[4], w8[8];
            *(float4*)a4     = *(const float4*)&At[kk*ML_AP + mg*4];
            *(float4*)w8     = *(const float4*)&WT[kk*ML_WP + ng*8];
            *(float4*)(w8+4) = *(const float4*)&WT[kk*ML_WP + ng*8 + 4];
            #pragma unroll
            for (int r = 0; r < 4; r++)
                #pragma unroll
                for (int i = 0; i < 8; i++) acc[r][i] += a4[r] * w8[i];
        }
        __syncthreads();
    }
    // tanh epilogue into T (reuse WT region)
    #pragma unroll
    for (int r = 0; r < 4; r++) {
        int m = mg*4 + r;
        #pragma unroll
        for (int i = 0; i < 8; i++) {
            int j = ng*8 + i;
            WT[m*ML_WP + j] = tanhf(acc[r][i] + b1[j]);
        }
    }
    __syncthreads();
    // logits: thread = (m, c)
    {
        int m = tid >> 3, c = tid & 7;
        float lg = b2[c];
        #pragma unroll 4
        for (int k = 0; k < LH; k += 4) {
            float4 t4 = *(const float4*)&WT[m*ML_WP + k];
            float4 w4 = *(const float4*)&W2s[c*ML_WP + k];
            lg += t4.x*w4.x + t4.y*w4.y + t4.z*w4.z + t4.w*w4.w;
        }
        llog[tid] = lg;
    }
    __syncthreads();
    if (tid < ML_MT) {
        int node = n0 + tid;
        if (node < N_NODES) {
            float mx = -INFINITY;
            #pragma unroll
            for (int q = 0; q < CDIM; q++) mx = fmaxf(mx, llog[tid*8 + q]);
            float ex[CDIM], ssum = 0.f;
            #pragma unroll
            for (int q = 0; q < CDIM; q++) { ex[q] = expf(llog[tid*8 + q] - mx); ssum += ex[q]; }
            float rs = 1.0f / ssum;
            #pragma unroll
            for (int q = 0; q < CDIM; q++) out[(size_t)node*CDIM + q] = ex[q] * rs;
        }
    }
}

extern "C" void kernel_launch(void* const* d_in, const int* in_sizes, int n_in,
                              void* d_out, int out_size, void* d_ws, size_t ws_size,
                              hipStream_t stream) {
    const float* x   = (const float*)d_in[0];
    const int*   ei  = (const int*)d_in[1];
    const float* Wl1 = (const float*)d_in[2];
    const float* bl1 = (const float*)d_in[3];
    const float* Wr1 = (const float*)d_in[4];
    const float* Wl2 = (const float*)d_in[5];
    const float* bl2 = (const float*)d_in[6];
    const float* Wr2 = (const float*)d_in[7];
    const float* W1  = (const float*)d_in[8];
    const float* b1  = (const float*)d_in[9];
    const float* W2  = (const float*)d_in[10];
    const float* b2  = (const float*)d_in[11];

    float* ws     = (float*)d_ws;
    float* part   = ws + OFF_PART;
    float* params = ws + OFF_PARAMS;
    int*   deg    = (int*)(ws + OFF_DEG);
    int*   rowptr = (int*)(ws + OFF_ROWPTR);
    int*   bsums  = (int*)(ws + OFF_BSUMS);
    float* X2     = ws + OFF_X2;
    int*   csr    = (int*)d_out;   // transient scratch; overwritten by mlp_k at the end

    hipMemsetAsync(deg, 0, (size_t)N_NODES * sizeof(int), stream);

    stats_partial_k<<<NB_STATS, 256, 0, stream>>>(x, part);
    stats_final_k<<<1, 64, 0, stream>>>(part, params);
    normalize_k<<<(N_NODES + 255) / 256, 256, 0, stream>>>(x, params, X2);

    deg_count_k<<<(N_EDGES + 255) / 256, 256, 0, stream>>>(ei, deg);
    const int nb_scan = (N_NODES + 1023) / 1024;   // 98
    scan1_k<<<nb_scan, 256, 0, stream>>>(deg, rowptr, bsums);
    scan2_k<<<1, 64, 0, stream>>>(bsums, nb_scan);
    scan3_k<<<nb_scan, 256, 0, stream>>>(rowptr, bsums);
    scatter_k<<<(N_EDGES + 255) / 256, 256, 0, stream>>>(ei, rowptr, csr);

    conv1_k<<<N_NODES, H, 0, stream>>>(X2, rowptr, deg, csr, Wl1, bl1, Wr1);
    agg2_k<<<N_NODES / 4, 256, 0, stream>>>(X2, rowptr, deg, csr);
    conv2_gemm_k<<<(N_NODES + C2_MT - 1) / C2_MT, 256, 0, stream>>>(X2, Wl2, Wr2, bl2);
    mlp_k<<<(N_NODES + ML_MT - 1) / ML_MT, 256, 0, stream>>>(X2, W1, b1, W2, b2, (float*)d_out);
}

// Round 3
// 412.520 us; speedup vs baseline: 3.9951x; 1.4437x over previous
//
#include <hip/hip_runtime.h>
#include <hip/hip_bf16.h>
#include <math.h>

#define N_NODES 100000
#define N_EDGES 600000
#define H 128
#define LH 256
#define CDIM 8
#define NB_STATS 64

typedef __attribute__((ext_vector_type(8))) short short8;
typedef __attribute__((ext_vector_type(4))) float floatx4;

// ------------- workspace layout (4-byte words) -------------
#define OFF_PART   0
#define OFF_PARAMS 704
#define OFF_DEG    712
#define OFF_ROWPTR (OFF_DEG + N_NODES)
#define OFF_BSUMS  (OFF_ROWPTR + N_NODES)
#define OFF_H0     (OFF_BSUMS + 128)            // N*4 fp32 (float4 rows)
#define OFF_CSR    (OFF_H0 + N_NODES*4)
#define OFF_WPK2   (OFF_CSR + N_EDGES)          // 32768 bf16 = 16384 words
#define OFF_WPK1   (OFF_WPK2 + 16384)           // 32768 bf16
#define OFF_W2PK   (OFF_WPK1 + 16384)           // 4096 bf16 = 2048 words
#define OFF_XB     (OFF_W2PK + 2048)            // N*256 bf16 = 12.8M words
// end = OFF_XB + 12,800,000 ~= 14.04M words = 56.2 MB (< 103 MB proven)

__device__ __forceinline__ float rot_c() { return cosf(1.57079632679489661923f); }
__device__ __forceinline__ float rot_s() { return sinf(1.57079632679489661923f); }
__device__ __forceinline__ float bfhi(unsigned v) { return __uint_as_float(v & 0xffff0000u); }
__device__ __forceinline__ float bflo(unsigned v) { return __uint_as_float(v << 16); }

// ---------------- stats ----------------
__global__ void stats_partial_k(const float* __restrict__ x, float* __restrict__ part) {
    const float c = rot_c(), sn = rot_s();
    float mn0 = INFINITY, mx0 = -INFINITY, mn1 = INFINITY, mx1 = -INFINITY;
    float s0 = 0.f, s1 = 0.f, sr0 = 0.f, sr1 = 0.f;
    float mxr0 = -INFINITY, mxr1 = -INFINITY, mxa = -INFINITY;
    for (int i = blockIdx.x * blockDim.x + threadIdx.x; i < N_NODES;
         i += gridDim.x * blockDim.x) {
        float x0 = x[3*i], x1 = x[3*i+1], a = x[3*i+2];
        float r0 = c*x0 - sn*x1;
        float r1 = sn*x0 + c*x1;
        mn0 = fminf(mn0, x0); mx0 = fmaxf(mx0, x0);
        mn1 = fminf(mn1, x1); mx1 = fmaxf(mx1, x1);
        s0 += x0; s1 += x1; sr0 += r0; sr1 += r1;
        mxr0 = fmaxf(mxr0, r0); mxr1 = fmaxf(mxr1, r1);
        mxa = fmaxf(mxa, a);
    }
    __shared__ float red[256];
    float vals[11] = {mn0, mx0, mn1, mx1, s0, s1, sr0, sr1, mxr0, mxr1, mxa};
    const int ops[11] = {0,1,0,1,2,2,2,2,1,1,1};
    for (int v = 0; v < 11; v++) {
        red[threadIdx.x] = vals[v];
        __syncthreads();
        for (int s = 128; s > 0; s >>= 1) {
            if ((int)threadIdx.x < s) {
                float a = red[threadIdx.x], b = red[threadIdx.x + s];
                red[threadIdx.x] = (ops[v]==0) ? fminf(a,b) : (ops[v]==1) ? fmaxf(a,b) : (a+b);
            }
            __syncthreads();
        }
        if (threadIdx.x == 0) part[blockIdx.x * 11 + v] = red[0];
        __syncthreads();
    }
}

__global__ void stats_final_k(const float* __restrict__ part, float* __restrict__ params) {
    __shared__ float red[64];
    __shared__ float res[11];
    const int ops[11] = {0,1,0,1,2,2,2,2,1,1,1};
    for (int v = 0; v < 11; v++) {
        red[threadIdx.x] = part[threadIdx.x * 11 + v];
        __syncthreads();
        for (int s = 32; s > 0; s >>= 1) {
            if ((int)threadIdx.x < s) {
                float a = red[threadIdx.x], b = red[threadIdx.x + s];
                red[threadIdx.x] = (ops[v]==0) ? fminf(a,b) : (ops[v]==1) ? fmaxf(a,b) : (a+b);
            }
            __syncthreads();
        }
        if (threadIdx.x == 0) res[v] = red[0];
        __syncthreads();
    }
    if (threadIdx.x == 0) {
        int rotate = (res[3] - res[2]) > (res[1] - res[0]);
        params[0] = (float)rotate;
        params[1] = (rotate ? res[6] : res[4]) / (float)N_NODES;
        params[2] = (rotate ? res[7] : res[5]) / (float)N_NODES;
        params[3] = rotate ? res[8] : res[1];
        params[4] = rotate ? res[9] : res[3];
        params[5] = res[10];
    }
}

__global__ void normalize_k(const float* __restrict__ x, const float* __restrict__ params,
                            float4* __restrict__ h0) {
    int i = blockIdx.x * blockDim.x + threadIdx.x;
    if (i >= N_NODES) return;
    const float c = rot_c(), sn = rot_s();
    float x0 = x[3*i], x1 = x[3*i+1], a = x[3*i+2];
    bool rot = params[0] != 0.f;
    float u0 = rot ? (c*x0 - sn*x1) : x0;
    float u1 = rot ? (sn*x0 + c*x1) : x1;
    h0[i] = make_float4((u0 - params[1]) / params[3],
                        (u1 - params[2]) / params[4],
                        a / params[5], 0.f);
}

// ---------------- weight pre-pack into MFMA B-fragment order ----------------
// B-frag (16x16x32): lane holds B[k=(lane>>4)*8+j][n=lane&15], j=0..7 contiguous.
__global__ void pack_k(const float* __restrict__ Wl2, const float* __restrict__ Wr2,
                       const float* __restrict__ W1, const float* __restrict__ W2,
                       __hip_bfloat16* __restrict__ Wpk2,
                       __hip_bfloat16* __restrict__ Wpk1,
                       __hip_bfloat16* __restrict__ W2pk) {
    int idx = blockIdx.x * blockDim.x + threadIdx.x;
    if (idx < 32768) {                       // Wpk2[ks8][nt8][lane64][j8], K=256,N=128
        int j = idx & 7, lane = (idx >> 3) & 63, nt = (idx >> 9) & 7, ks = idx >> 12;
        int k = ks*32 + (lane >> 4)*8 + j;
        int n = nt*16 + (lane & 15);
        float v = (k < 128) ? Wl2[n*H + k] : Wr2[n*H + (k - 128)];
        Wpk2[idx] = __float2bfloat16(v);
    } else if (idx < 65536) {                // Wpk1[ks4][nt16][lane64][j8], K=128,N=256
        int i2 = idx - 32768;
        int j = i2 & 7, lane = (i2 >> 3) & 63, nt = (i2 >> 9) & 15, ks = i2 >> 13;
        int k = ks*32 + (lane >> 4)*8 + j;
        int n = nt*16 + (lane & 15);
        Wpk1[i2] = __float2bfloat16(W1[n*H + k]);
    } else if (idx < 69632) {                // W2pk[ks8][lane64][j8], K=256,N=16(8 real)
        int i3 = idx - 65536;
        int j = i3 & 7, lane = (i3 >> 3) & 63, ks = i3 >> 9;
        int k = ks*32 + (lane >> 4)*8 + j;
        int n = lane & 15;
        W2pk[i3] = __float2bfloat16((n < CDIM) ? W2[n*LH + k] : 0.f);
    }
}

// ---------------- CSR build ----------------
__global__ void deg_count_k(const int* __restrict__ ei, int* __restrict__ deg) {
    int e = blockIdx.x * blockDim.x + threadIdx.x;
    if (e >= N_EDGES) return;
    atomicAdd(&deg[ei[N_EDGES + e]], 1);
}

__global__ void scan1_k(const int* __restrict__ deg, int* __restrict__ rowptr,
                        int* __restrict__ bsums) {
    __shared__ int s[256];
    int t = threadIdx.x;
    int base = blockIdx.x * 1024 + t * 4;
    int d0 = (base+0 < N_NODES) ? deg[base+0] : 0;
    int d1 = (base+1 < N_NODES) ? deg[base+1] : 0;
    int d2 = (base+2 < N_NODES) ? deg[base+2] : 0;
    int d3 = (base+3 < N_NODES) ? deg[base+3] : 0;
    int tsum = d0 + d1 + d2 + d3;
    s[t] = tsum;
    __syncthreads();
    for (int off = 1; off < 256; off <<= 1) {
        int v = (t >= off) ? s[t - off] : 0;
        __syncthreads();
        s[t] += v;
        __syncthreads();
    }
    int excl = s[t] - tsum;
    if (base+0 < N_NODES) rowptr[base+0] = excl;
    if (base+1 < N_NODES) rowptr[base+1] = excl + d0;
    if (base+2 < N_NODES) rowptr[base+2] = excl + d0 + d1;
    if (base+3 < N_NODES) rowptr[base+3] = excl + d0 + d1 + d2;
    if (t == 255) bsums[blockIdx.x] = s[255];
}

__global__ void scan2_k(int* __restrict__ bsums, int nb) {
    if (threadIdx.x == 0 && blockIdx.x == 0) {
        int run = 0;
        for (int b = 0; b < nb; b++) { int v = bsums[b]; bsums[b] = run; run += v; }
    }
}

__global__ void scan3_k(int* __restrict__ rowptr, const int* __restrict__ bsums) {
    int t = threadIdx.x;
    int base = blockIdx.x * 1024 + t * 4;
    int add = bsums[blockIdx.x];
    if (base+0 < N_NODES) rowptr[base+0] += add;
    if (base+1 < N_NODES) rowptr[base+1] += add;
    if (base+2 < N_NODES) rowptr[base+2] += add;
    if (base+3 < N_NODES) rowptr[base+3] += add;
}

__global__ void scatter_k(const int* __restrict__ ei, int* __restrict__ rowptr,
                          int* __restrict__ csr) {
    int e = blockIdx.x * blockDim.x + threadIdx.x;
    if (e >= N_EDGES) return;
    int d = ei[N_EDGES + e];
    int pos = atomicAdd(&rowptr[d], 1);
    csr[pos] = ei[e];
}

// ---------------- conv1: agg(h0) + dense 3->128, h1 (bf16) -> Xb[n][128..255]
__global__ void conv1_k(const float4* __restrict__ h0, const int* __restrict__ rowptr,
                        const int* __restrict__ deg, const int* __restrict__ csr,
                        const float* __restrict__ Wl1, const float* __restrict__ bl1,
                        const float* __restrict__ Wr1, __hip_bfloat16* __restrict__ Xb) {
    int n = blockIdx.x;
    int j = threadIdx.x;
    int dg = deg[n];
    int end = rowptr[n], start = end - dg;
    float a0 = 0.f, a1 = 0.f, a2 = 0.f;
    for (int e = start; e < end; e++) {
        int s = csr[e];
        float4 v = h0[s];
        a0 += v.x; a1 += v.y; a2 += v.z;
    }
    float inv = 1.0f / (float)max(dg, 1);
    a0 *= inv; a1 *= inv; a2 *= inv;
    float4 xv = h0[n];
    float acc = Wl1[3*j]*a0 + Wl1[3*j+1]*a1 + Wl1[3*j+2]*a2 + bl1[j]
              + Wr1[3*j]*xv.x + Wr1[3*j+1]*xv.y + Wr1[3*j+2]*xv.z;
    Xb[(size_t)n*256 + 128 + j] = __float2bfloat16(tanhf(acc));
}

// ---------------- agg2: mean of h1 (bf16) -> Xb[n][0..127] (bf16)
__global__ void agg2_k(__hip_bfloat16* __restrict__ Xb, const int* __restrict__ rowptr,
                       const int* __restrict__ deg, const int* __restrict__ csr) {
    int lane = threadIdx.x & 63;
    int n = blockIdx.x * 4 + (threadIdx.x >> 6);
    int dg = deg[n];
    int end = rowptr[n], start = end - dg;
    float a0 = 0.f, a1 = 0.f;
    for (int e = start; e < end; e++) {
        int s = csr[e];
        unsigned v = *(const unsigned*)&Xb[(size_t)s*256 + 128 + lane*2];
        a0 += bflo(v); a1 += bfhi(v);
    }
    float inv = 1.0f / (float)max(dg, 1);
    __hip_bfloat16 o0 = __float2bfloat16(a0 * inv);
    __hip_bfloat16 o1 = __float2bfloat16(a1 * inv);
    unsigned ov = ((unsigned)*(unsigned short*)&o1 << 16) | (unsigned)*(unsigned short*)&o0;
    *(unsigned*)&Xb[(size_t)n*256 + lane*2] = ov;
}

// ---------------- conv2 MFMA: h2 = tanh([agg2|h1] @ W' + bl2) -> Xb[n][0..127]
__global__ __launch_bounds__(256, 2) void conv2_mfma_k(__hip_bfloat16* __restrict__ Xb,
        const __hip_bfloat16* __restrict__ Wpk2, const float* __restrict__ bl2) {
    __shared__ short Ws[32768];   // 64 KB: [ks8][nt8][lane64][j8]
    int tid = threadIdx.x;
    {
        const float4* s = (const float4*)Wpk2;
        float4* d = (float4*)Ws;
        #pragma unroll
        for (int i = 0; i < 16; i++) d[tid + i*256] = s[tid + i*256];
    }
    __syncthreads();
    int lane = tid & 63, wave = tid >> 6;
    int quad = lane >> 4, m = lane & 15;
    int row = blockIdx.x * 64 + wave * 16 + m;
    int rowL = row < N_NODES ? row : N_NODES - 1;
    const short* Arow = (const short*)Xb + (size_t)rowL * 256;
    floatx4 acc[8];
    #pragma unroll
    for (int i = 0; i < 8; i++)
        #pragma unroll
        for (int r = 0; r < 4; r++) acc[i][r] = 0.f;
    #pragma unroll
    for (int ks = 0; ks < 8; ks++) {
        short8 a = *(const short8*)(Arow + ks*32 + quad*8);
        #pragma unroll
        for (int nt = 0; nt < 8; nt++) {
            short8 b = *(const short8*)&Ws[((ks*8 + nt)*64 + lane)*8];
            acc[nt] = __builtin_amdgcn_mfma_f32_16x16x32_bf16(a, b, acc[nt], 0, 0, 0);
        }
    }
    int c0 = lane & 15;
    int rbase = blockIdx.x * 64 + wave * 16 + quad * 4;
    #pragma unroll
    for (int nt = 0; nt < 8; nt++) {
        int col = nt*16 + c0;
        float bb = bl2[col];
        #pragma unroll
        for (int r = 0; r < 4; r++) {
            int rr = rbase + r;
            if (rr < N_NODES)
                Xb[(size_t)rr*256 + col] = __float2bfloat16(tanhf(acc[nt][r] + bb));
        }
    }
}

// ---------------- fused MLP MFMA: t=tanh(h2@W1^T+b1); logits=t@W2^T+b2; softmax
#define TP 264   // t-tile row stride (bf16 units)
__global__ __launch_bounds__(256, 2) void mlp_mfma_k(const __hip_bfloat16* __restrict__ Xb,
        const __hip_bfloat16* __restrict__ Wpk1, const float* __restrict__ b1,
        const __hip_bfloat16* __restrict__ W2pk, const float* __restrict__ b2,
        float* __restrict__ out) {
    __shared__ short Ws[32768];     // 64 KB: W1 frags, later reused as t-tile [64][TP]
    __shared__ short W2s[4096];     // 8 KB
    __shared__ float lg[4][16][16]; // 4 KB
    int tid = threadIdx.x;
    {
        const float4* s = (const float4*)Wpk1;
        float4* d = (float4*)Ws;
        #pragma unroll
        for (int i = 0; i < 16; i++) d[tid + i*256] = s[tid + i*256];
        const float4* s2 = (const float4*)W2pk;
        float4* d2 = (float4*)W2s;
        d2[tid] = s2[tid];
        d2[tid + 256] = s2[tid + 256];
    }
    __syncthreads();
    int lane = tid & 63, wave = tid >> 6;
    int quad = lane >> 4, m = lane & 15;
    int row = blockIdx.x * 64 + wave * 16 + m;
    int rowL = row < N_NODES ? row : N_NODES - 1;
    const short* Arow = (const short*)Xb + (size_t)rowL * 256;   // h2 in cols 0..127
    floatx4 acc[16];
    #pragma unroll
    for (int i = 0; i < 16; i++)
        #pragma unroll
        for (int r = 0; r < 4; r++) acc[i][r] = 0.f;
    #pragma unroll
    for (int ks = 0; ks < 4; ks++) {
        short8 a = *(const short8*)(Arow + ks*32 + quad*8);
        #pragma unroll
        for (int nt = 0; nt < 16; nt++) {
            short8 b = *(const short8*)&Ws[((ks*16 + nt)*64 + lane)*8];
            acc[nt] = __builtin_amdgcn_mfma_f32_16x16x32_bf16(a, b, acc[nt], 0, 0, 0);
        }
    }
    __syncthreads();   // all waves done reading Ws; reuse as t-tile
    short* T = Ws;
    int c0 = lane & 15;
    int mrow = wave * 16 + quad * 4;
    #pragma unroll
    for (int nt = 0; nt < 16; nt++) {
        int col = nt*16 + c0;
        float bb = b1[col];
        #pragma unroll
        for (int r = 0; r < 4; r++) {
            __hip_bfloat16 h = __float2bfloat16(tanhf(acc[nt][r] + bb));
            T[(mrow + r)*TP + col] = *(short*)&h;
        }
    }
    __syncthreads();
    // logits: K=256 MFMA vs zero-padded W2 (N=16, cols 0..7 real)
    floatx4 lacc;
    #pragma unroll
    for (int r = 0; r < 4; r++) lacc[r] = 0.f;
    const short* Trow = T + (size_t)(wave*16 + m) * TP;
    #pragma unroll
    for (int ks = 0; ks < 8; ks++) {
        short8 a = *(const short8*)(Trow + ks*32 + quad*8);
        short8 b = *(const short8*)&W2s[(ks*64 + lane)*8];
        lacc = __builtin_amdgcn_mfma_f32_16x16x32_bf16(a, b, lacc, 0, 0, 0);
    }
    #pragma unroll
    for (int r = 0; r < 4; r++) lg[wave][quad*4 + r][c0] = lacc[r];
    __syncthreads();
    if (lane < 16) {
        int rr = blockIdx.x * 64 + wave * 16 + lane;
        if (rr < N_NODES) {
            float v[CDIM];
            float mx = -INFINITY;
            #pragma unroll
            for (int q = 0; q < CDIM; q++) { v[q] = lg[wave][lane][q] + b2[q]; mx = fmaxf(mx, v[q]); }
            float ssum = 0.f;
            #pragma unroll
            for (int q = 0; q < CDIM; q++) { v[q] = expf(v[q] - mx); ssum += v[q]; }
            float rs = 1.0f / ssum;
            #pragma unroll
            for (int q = 0; q < CDIM; q++) v[q] *= rs;
            *(float4*)&out[(size_t)rr*CDIM]     = make_float4(v[0], v[1], v[2], v[3]);
            *(float4*)&out[(size_t)rr*CDIM + 4] = make_float4(v[4], v[5], v[6], v[7]);
        }
    }
}

extern "C" void kernel_launch(void* const* d_in, const int* in_sizes, int n_in,
                              void* d_out, int out_size, void* d_ws, size_t ws_size,
                              hipStream_t stream) {
    const float* x   = (const float*)d_in[0];
    const int*   ei  = (const int*)d_in[1];
    const float* Wl1 = (const float*)d_in[2];
    const float* bl1 = (const float*)d_in[3];
    const float* Wr1 = (const float*)d_in[4];
    const float* Wl2 = (const float*)d_in[5];
    const float* bl2 = (const float*)d_in[6];
    const float* Wr2 = (const float*)d_in[7];
    const float* W1  = (const float*)d_in[8];
    const float* b1  = (const float*)d_in[9];
    const float* W2  = (const float*)d_in[10];
    const float* b2  = (const float*)d_in[11];

    float* ws     = (float*)d_ws;
    float* part   = ws + OFF_PART;
    float* params = ws + OFF_PARAMS;
    int*   deg    = (int*)(ws + OFF_DEG);
    int*   rowptr = (int*)(ws + OFF_ROWPTR);
    int*   bsums  = (int*)(ws + OFF_BSUMS);
    float4* h0    = (float4*)(ws + OFF_H0);
    int*   csr    = (int*)(ws + OFF_CSR);
    __hip_bfloat16* Wpk2 = (__hip_bfloat16*)(ws + OFF_WPK2);
    __hip_bfloat16* Wpk1 = (__hip_bfloat16*)(ws + OFF_WPK1);
    __hip_bfloat16* W2pk = (__hip_bfloat16*)(ws + OFF_W2PK);
    __hip_bfloat16* Xb   = (__hip_bfloat16*)(ws + OFF_XB);

    hipMemsetAsync(deg, 0, (size_t)N_NODES * sizeof(int), stream);

    pack_k<<<(69632 + 255) / 256, 256, 0, stream>>>(Wl2, Wr2, W1, W2, Wpk2, Wpk1, W2pk);
    stats_partial_k<<<NB_STATS, 256, 0, stream>>>(x, part);
    stats_final_k<<<1, 64, 0, stream>>>(part, params);
    normalize_k<<<(N_NODES + 255) / 256, 256, 0, stream>>>(x, params, h0);

    deg_count_k<<<(N_EDGES + 255) / 256, 256, 0, stream>>>(ei, deg);
    const int nb_scan = (N_NODES + 1023) / 1024;
    scan1_k<<<nb_scan, 256, 0, stream>>>(deg, rowptr, bsums);
    scan2_k<<<1, 64, 0, stream>>>(bsums, nb_scan);
    scan3_k<<<nb_scan, 256, 0, stream>>>(rowptr, bsums);
    scatter_k<<<(N_EDGES + 255) / 256, 256, 0, stream>>>(ei, rowptr, csr);

    conv1_k<<<N_NODES, H, 0, stream>>>(h0, rowptr, deg, csr, Wl1, bl1, Wr1, Xb);
    agg2_k<<<N_NODES / 4, 256, 0, stream>>>(Xb, rowptr, deg, csr);
    const int gtiles = (N_NODES + 63) / 64;
    conv2_mfma_k<<<gtiles, 256, 0, stream>>>(Xb, Wpk2, bl2);
    mlp_mfma_k<<<gtiles, 256, 0, stream>>>(Xb, Wpk1, b1, W2pk, b2, (float*)d_out);
}

// Round 4
// 358.546 us; speedup vs baseline: 4.5965x; 1.1505x over previous
//
#include <hip/hip_runtime.h>
#include <hip/hip_bf16.h>
#include <math.h>

#define N_NODES 100000
#define N_EDGES 600000
#define H 128
#define LH 256
#define CDIM 8
#define NB_STATS 64

typedef __attribute__((ext_vector_type(8))) short short8;
typedef __attribute__((ext_vector_type(4))) float floatx4;

// ------------- workspace layout (4-byte words) -------------
#define OFF_PART   0
#define OFF_PARAMS 704
#define OFF_DEG    712
#define OFF_ROWPTR (OFF_DEG + N_NODES)
#define OFF_BSUMS  (OFF_ROWPTR + N_NODES)
#define OFF_H0     (OFF_BSUMS + 128)            // N*4 fp32 (float4 rows)
#define OFF_AGG1   (OFF_H0 + N_NODES*4)         // N*4 fp32
#define OFF_CSR    (OFF_AGG1 + N_NODES*4)
#define OFF_WPK2   (OFF_CSR + N_EDGES)          // 32768 bf16 = 16384 words
#define OFF_WPK1   (OFF_WPK2 + 16384)           // 32768 bf16
#define OFF_W2PK   (OFF_WPK1 + 16384)           // 4096 bf16 = 2048 words
#define OFF_XB     (OFF_W2PK + 2048)            // N*256 bf16 = 12.8M words
// end ~= 14.4M words = 57.8 MB (< 103 MB proven)

__device__ __forceinline__ float rot_c() { return cosf(1.57079632679489661923f); }
__device__ __forceinline__ float rot_s() { return sinf(1.57079632679489661923f); }
__device__ __forceinline__ float bfhi(unsigned v) { return __uint_as_float(v & 0xffff0000u); }
__device__ __forceinline__ float bflo(unsigned v) { return __uint_as_float(v << 16); }

// ---------------- stats ----------------
__global__ void stats_partial_k(const float* __restrict__ x, float* __restrict__ part) {
    const float c = rot_c(), sn = rot_s();
    float mn0 = INFINITY, mx0 = -INFINITY, mn1 = INFINITY, mx1 = -INFINITY;
    float s0 = 0.f, s1 = 0.f, sr0 = 0.f, sr1 = 0.f;
    float mxr0 = -INFINITY, mxr1 = -INFINITY, mxa = -INFINITY;
    for (int i = blockIdx.x * blockDim.x + threadIdx.x; i < N_NODES;
         i += gridDim.x * blockDim.x) {
        float x0 = x[3*i], x1 = x[3*i+1], a = x[3*i+2];
        float r0 = c*x0 - sn*x1;
        float r1 = sn*x0 + c*x1;
        mn0 = fminf(mn0, x0); mx0 = fmaxf(mx0, x0);
        mn1 = fminf(mn1, x1); mx1 = fmaxf(mx1, x1);
        s0 += x0; s1 += x1; sr0 += r0; sr1 += r1;
        mxr0 = fmaxf(mxr0, r0); mxr1 = fmaxf(mxr1, r1);
        mxa = fmaxf(mxa, a);
    }
    __shared__ float red[256];
    float vals[11] = {mn0, mx0, mn1, mx1, s0, s1, sr0, sr1, mxr0, mxr1, mxa};
    const int ops[11] = {0,1,0,1,2,2,2,2,1,1,1};
    for (int v = 0; v < 11; v++) {
        red[threadIdx.x] = vals[v];
        __syncthreads();
        for (int s = 128; s > 0; s >>= 1) {
            if ((int)threadIdx.x < s) {
                float a = red[threadIdx.x], b = red[threadIdx.x + s];
                red[threadIdx.x] = (ops[v]==0) ? fminf(a,b) : (ops[v]==1) ? fmaxf(a,b) : (a+b);
            }
            __syncthreads();
        }
        if (threadIdx.x == 0) part[blockIdx.x * 11 + v] = red[0];
        __syncthreads();
    }
}

__global__ void stats_final_k(const float* __restrict__ part, float* __restrict__ params) {
    __shared__ float red[64];
    __shared__ float res[11];
    const int ops[11] = {0,1,0,1,2,2,2,2,1,1,1};
    for (int v = 0; v < 11; v++) {
        red[threadIdx.x] = part[threadIdx.x * 11 + v];
        __syncthreads();
        for (int s = 32; s > 0; s >>= 1) {
            if ((int)threadIdx.x < s) {
                float a = red[threadIdx.x], b = red[threadIdx.x + s];
                red[threadIdx.x] = (ops[v]==0) ? fminf(a,b) : (ops[v]==1) ? fmaxf(a,b) : (a+b);
            }
            __syncthreads();
        }
        if (threadIdx.x == 0) res[v] = red[0];
        __syncthreads();
    }
    if (threadIdx.x == 0) {
        int rotate = (res[3] - res[2]) > (res[1] - res[0]);
        params[0] = (float)rotate;
        params[1] = (rotate ? res[6] : res[4]) / (float)N_NODES;
        params[2] = (rotate ? res[7] : res[5]) / (float)N_NODES;
        params[3] = rotate ? res[8] : res[1];
        params[4] = rotate ? res[9] : res[3];
        params[5] = res[10];
    }
}

__global__ void normalize_k(const float* __restrict__ x, const float* __restrict__ params,
                            float4* __restrict__ h0) {
    int i = blockIdx.x * blockDim.x + threadIdx.x;
    if (i >= N_NODES) return;
    const float c = rot_c(), sn = rot_s();
    float x0 = x[3*i], x1 = x[3*i+1], a = x[3*i+2];
    bool rot = params[0] != 0.f;
    float u0 = rot ? (c*x0 - sn*x1) : x0;
    float u1 = rot ? (sn*x0 + c*x1) : x1;
    h0[i] = make_float4((u0 - params[1]) / params[3],
                        (u1 - params[2]) / params[4],
                        a / params[5], 0.f);
}

// ---------------- weight pre-pack into MFMA B-fragment order ----------------
__global__ void pack_k(const float* __restrict__ Wl2, const float* __restrict__ Wr2,
                       const float* __restrict__ W1, const float* __restrict__ W2,
                       __hip_bfloat16* __restrict__ Wpk2,
                       __hip_bfloat16* __restrict__ Wpk1,
                       __hip_bfloat16* __restrict__ W2pk) {
    int idx = blockIdx.x * blockDim.x + threadIdx.x;
    if (idx < 32768) {                       // Wpk2[ks8][nt8][lane64][j8], K=256,N=128
        int j = idx & 7, lane = (idx >> 3) & 63, nt = (idx >> 9) & 7, ks = idx >> 12;
        int k = ks*32 + (lane >> 4)*8 + j;
        int n = nt*16 + (lane & 15);
        float v = (k < 128) ? Wl2[n*H + k] : Wr2[n*H + (k - 128)];
        Wpk2[idx] = __float2bfloat16(v);
    } else if (idx < 65536) {                // Wpk1[ks4][nt16][lane64][j8], K=128,N=256
        int i2 = idx - 32768;
        int j = i2 & 7, lane = (i2 >> 3) & 63, nt = (i2 >> 9) & 15, ks = i2 >> 13;
        int k = ks*32 + (lane >> 4)*8 + j;
        int n = nt*16 + (lane & 15);
        Wpk1[i2] = __float2bfloat16(W1[n*H + k]);
    } else if (idx < 69632) {                // W2pk[ks8][lane64][j8], K=256,N=16(8 real)
        int i3 = idx - 65536;
        int j = i3 & 7, lane = (i3 >> 3) & 63, ks = i3 >> 9;
        int k = ks*32 + (lane >> 4)*8 + j;
        int n = lane & 15;
        W2pk[i3] = __float2bfloat16((n < CDIM) ? W2[n*LH + k] : 0.f);
    }
}

// ---------------- CSR build ----------------
__global__ void deg_count_k(const int* __restrict__ ei, int* __restrict__ deg) {
    int e = blockIdx.x * blockDim.x + threadIdx.x;
    if (e >= N_EDGES) return;
    atomicAdd(&deg[ei[N_EDGES + e]], 1);
}

__global__ void scan1_k(const int* __restrict__ deg, int* __restrict__ rowptr,
                        int* __restrict__ bsums) {
    __shared__ int s[256];
    int t = threadIdx.x;
    int base = blockIdx.x * 1024 + t * 4;
    int d0 = (base+0 < N_NODES) ? deg[base+0] : 0;
    int d1 = (base+1 < N_NODES) ? deg[base+1] : 0;
    int d2 = (base+2 < N_NODES) ? deg[base+2] : 0;
    int d3 = (base+3 < N_NODES) ? deg[base+3] : 0;
    int tsum = d0 + d1 + d2 + d3;
    s[t] = tsum;
    __syncthreads();
    for (int off = 1; off < 256; off <<= 1) {
        int v = (t >= off) ? s[t - off] : 0;
        __syncthreads();
        s[t] += v;
        __syncthreads();
    }
    int excl = s[t] - tsum;
    if (base+0 < N_NODES) rowptr[base+0] = excl;
    if (base+1 < N_NODES) rowptr[base+1] = excl + d0;
    if (base+2 < N_NODES) rowptr[base+2] = excl + d0 + d1;
    if (base+3 < N_NODES) rowptr[base+3] = excl + d0 + d1 + d2;
    if (t == 255) bsums[blockIdx.x] = s[255];
}

__global__ void scan2_k(int* __restrict__ bsums, int nb) {
    if (threadIdx.x == 0 && blockIdx.x == 0) {
        int run = 0;
        for (int b = 0; b < nb; b++) { int v = bsums[b]; bsums[b] = run; run += v; }
    }
}

__global__ void scan3_k(int* __restrict__ rowptr, const int* __restrict__ bsums) {
    int t = threadIdx.x;
    int base = blockIdx.x * 1024 + t * 4;
    int add = bsums[blockIdx.x];
    if (base+0 < N_NODES) rowptr[base+0] += add;
    if (base+1 < N_NODES) rowptr[base+1] += add;
    if (base+2 < N_NODES) rowptr[base+2] += add;
    if (base+3 < N_NODES) rowptr[base+3] += add;
}

__global__ void scatter_k(const int* __restrict__ ei, int* __restrict__ rowptr,
                          int* __restrict__ csr) {
    int e = blockIdx.x * blockDim.x + threadIdx.x;
    if (e >= N_EDGES) return;
    int d = ei[N_EDGES + e];
    int pos = atomicAdd(&rowptr[d], 1);
    csr[pos] = ei[e];
}

// ---------------- agg1: mean of h0 over in-neighbors (1 thread / node) ----
__global__ void agg1_k(const float4* __restrict__ h0, const int* __restrict__ rowptr,
                       const int* __restrict__ deg, const int* __restrict__ csr,
                       float4* __restrict__ agg1) {
    int n = blockIdx.x * blockDim.x + threadIdx.x;
    if (n >= N_NODES) return;
    int dg = deg[n];
    int end = rowptr[n], start = end - dg;
    float a0 = 0.f, a1 = 0.f, a2 = 0.f;
    int e = start;
    for (; e + 1 < end; e += 2) {
        int s0 = csr[e], s1 = csr[e+1];
        float4 v0 = h0[s0];
        float4 v1 = h0[s1];
        a0 += v0.x + v1.x; a1 += v0.y + v1.y; a2 += v0.z + v1.z;
    }
    if (e < end) {
        float4 v = h0[csr[e]];
        a0 += v.x; a1 += v.y; a2 += v.z;
    }
    float inv = 1.0f / (float)max(dg, 1);
    agg1[n] = make_float4(a0 * inv, a1 * inv, a2 * inv, 0.f);
}

// ---------------- conv1 dense: h1 = tanh(agg1@Wl1^T + h0@Wr1^T + b) ----
__global__ __launch_bounds__(256) void conv1_dense_k(const float4* __restrict__ h0,
        const float4* __restrict__ agg1,
        const float* __restrict__ Wl1, const float* __restrict__ bl1,
        const float* __restrict__ Wr1, __hip_bfloat16* __restrict__ Xb) {
    __shared__ float wl[H*3], wr[H*3], bb[H];
    int tid = threadIdx.x;
    for (int i = tid; i < H*3; i += 256) { wl[i] = Wl1[i]; wr[i] = Wr1[i]; }
    if (tid < H) bb[tid] = bl1[tid];
    __syncthreads();
    int n = blockIdx.x * 2 + (tid >> 7);
    int j = tid & 127;
    float4 a = agg1[n];
    float4 xv = h0[n];
    float acc = wl[3*j]*a.x + wl[3*j+1]*a.y + wl[3*j+2]*a.z + bb[j]
              + wr[3*j]*xv.x + wr[3*j+1]*xv.y + wr[3*j+2]*xv.z;
    Xb[(size_t)n*256 + 128 + j] = __float2bfloat16(tanhf(acc));
}

// ---------------- agg2: mean of h1 (bf16) -> Xb[n][0..127], unroll x4 ----
__global__ void agg2_k(__hip_bfloat16* __restrict__ Xb, const int* __restrict__ rowptr,
                       const int* __restrict__ deg, const int* __restrict__ csr) {
    int lane = threadIdx.x & 63;
    int n = blockIdx.x * 4 + (threadIdx.x >> 6);
    int dg = deg[n];
    int end = rowptr[n], start = end - dg;
    float a0 = 0.f, a1 = 0.f;
    int e = start;
    for (; e + 3 < end; e += 4) {
        int s0 = csr[e], s1 = csr[e+1], s2 = csr[e+2], s3 = csr[e+3];
        unsigned v0 = *(const unsigned*)&Xb[(size_t)s0*256 + 128 + lane*2];
        unsigned v1 = *(const unsigned*)&Xb[(size_t)s1*256 + 128 + lane*2];
        unsigned v2 = *(const unsigned*)&Xb[(size_t)s2*256 + 128 + lane*2];
        unsigned v3 = *(const unsigned*)&Xb[(size_t)s3*256 + 128 + lane*2];
        a0 += (bflo(v0) + bflo(v1)) + (bflo(v2) + bflo(v3));
        a1 += (bfhi(v0) + bfhi(v1)) + (bfhi(v2) + bfhi(v3));
    }
    for (; e < end; e++) {
        unsigned v = *(const unsigned*)&Xb[(size_t)csr[e]*256 + 128 + lane*2];
        a0 += bflo(v); a1 += bfhi(v);
    }
    float inv = 1.0f / (float)max(dg, 1);
    __hip_bfloat16 o0 = __float2bfloat16(a0 * inv);
    __hip_bfloat16 o1 = __float2bfloat16(a1 * inv);
    unsigned ov = ((unsigned)*(unsigned short*)&o1 << 16) | (unsigned)*(unsigned short*)&o0;
    *(unsigned*)&Xb[(size_t)n*256 + lane*2] = ov;
}

// ---------------- conv2 MFMA: h2 = tanh([agg2|h1] @ W' + bl2) -> Xb[n][0..127]
__global__ __launch_bounds__(256, 2) void conv2_mfma_k(__hip_bfloat16* __restrict__ Xb,
        const __hip_bfloat16* __restrict__ Wpk2, const float* __restrict__ bl2) {
    __shared__ short Ws[32768];   // 64 KB: [ks8][nt8][lane64][j8]
    int tid = threadIdx.x;
    {
        const float4* s = (const float4*)Wpk2;
        float4* d = (float4*)Ws;
        #pragma unroll
        for (int i = 0; i < 16; i++) d[tid + i*256] = s[tid + i*256];
    }
    __syncthreads();
    int lane = tid & 63, wave = tid >> 6;
    int quad = lane >> 4, m = lane & 15;
    int row = blockIdx.x * 64 + wave * 16 + m;
    int rowL = row < N_NODES ? row : N_NODES - 1;
    const short* Arow = (const short*)Xb + (size_t)rowL * 256;
    floatx4 acc[8];
    #pragma unroll
    for (int i = 0; i < 8; i++)
        #pragma unroll
        for (int r = 0; r < 4; r++) acc[i][r] = 0.f;
    #pragma unroll
    for (int ks = 0; ks < 8; ks++) {
        short8 a = *(const short8*)(Arow + ks*32 + quad*8);
        #pragma unroll
        for (int nt = 0; nt < 8; nt++) {
            short8 b = *(const short8*)&Ws[((ks*8 + nt)*64 + lane)*8];
            acc[nt] = __builtin_amdgcn_mfma_f32_16x16x32_bf16(a, b, acc[nt], 0, 0, 0);
        }
    }
    int c0 = lane & 15;
    int rbase = blockIdx.x * 64 + wave * 16 + quad * 4;
    #pragma unroll
    for (int nt = 0; nt < 8; nt++) {
        int col = nt*16 + c0;
        float bb = bl2[col];
        #pragma unroll
        for (int r = 0; r < 4; r++) {
            int rr = rbase + r;
            if (rr < N_NODES)
                Xb[(size_t)rr*256 + col] = __float2bfloat16(tanhf(acc[nt][r] + bb));
        }
    }
}

// ---------------- fused MLP MFMA ----------------
#define TP 264
__global__ __launch_bounds__(256, 2) void mlp_mfma_k(const __hip_bfloat16* __restrict__ Xb,
        const __hip_bfloat16* __restrict__ Wpk1, const float* __restrict__ b1,
        const __hip_bfloat16* __restrict__ W2pk, const float* __restrict__ b2,
        float* __restrict__ out) {
    __shared__ short Ws[32768];
    __shared__ short W2s[4096];
    __shared__ float lg[4][16][16];
    int tid = threadIdx.x;
    {
        const float4* s = (const float4*)Wpk1;
        float4* d = (float4*)Ws;
        #pragma unroll
        for (int i = 0; i < 16; i++) d[tid + i*256] = s[tid + i*256];
        const float4* s2 = (const float4*)W2pk;
        float4* d2 = (float4*)W2s;
        d2[tid] = s2[tid];
        d2[tid + 256] = s2[tid + 256];
    }
    __syncthreads();
    int lane = tid & 63, wave = tid >> 6;
    int quad = lane >> 4, m = lane & 15;
    int row = blockIdx.x * 64 + wave * 16 + m;
    int rowL = row < N_NODES ? row : N_NODES - 1;
    const short* Arow = (const short*)Xb + (size_t)rowL * 256;
    floatx4 acc[16];
    #pragma unroll
    for (int i = 0; i < 16; i++)
        #pragma unroll
        for (int r = 0; r < 4; r++) acc[i][r] = 0.f;
    #pragma unroll
    for (int ks = 0; ks < 4; ks++) {
        short8 a = *(const short8*)(Arow + ks*32 + quad*8);
        #pragma unroll
        for (int nt = 0; nt < 16; nt++) {
            short8 b = *(const short8*)&Ws[((ks*16 + nt)*64 + lane)*8];
            acc[nt] = __builtin_amdgcn_mfma_f32_16x16x32_bf16(a, b, acc[nt], 0, 0, 0);
        }
    }
    __syncthreads();
    short* T = Ws;
    int c0 = lane & 15;
    int mrow = wave * 16 + quad * 4;
    #pragma unroll
    for (int nt = 0; nt < 16; nt++) {
        int col = nt*16 + c0;
        float bb = b1[col];
        #pragma unroll
        for (int r = 0; r < 4; r++) {
            __hip_bfloat16 h = __float2bfloat16(tanhf(acc[nt][r] + bb));
            T[(mrow + r)*TP + col] = *(short*)&h;
        }
    }
    __syncthreads();
    floatx4 lacc;
    #pragma unroll
    for (int r = 0; r < 4; r++) lacc[r] = 0.f;
    const short* Trow = T + (size_t)(wave*16 + m) * TP;
    #pragma unroll
    for (int ks = 0; ks < 8; ks++) {
        short8 a = *(const short8*)(Trow + ks*32 + quad*8);
        short8 b = *(const short8*)&W2s[(ks*64 + lane)*8];
        lacc = __builtin_amdgcn_mfma_f32_16x16x32_bf16(a, b, lacc, 0, 0, 0);
    }
    #pragma unroll
    for (int r = 0; r < 4; r++) lg[wave][quad*4 + r][c0] = lacc[r];
    __syncthreads();
    if (lane < 16) {
        int rr = blockIdx.x * 64 + wave * 16 + lane;
        if (rr < N_NODES) {
            float v[CDIM];
            float mx = -INFINITY;
            #pragma unroll
            for (int q = 0; q < CDIM; q++) { v[q] = lg[wave][lane][q] + b2[q]; mx = fmaxf(mx, v[q]); }
            float ssum = 0.f;
            #pragma unroll
            for (int q = 0; q < CDIM; q++) { v[q] = expf(v[q] - mx); ssum += v[q]; }
            float rs = 1.0f / ssum;
            #pragma unroll
            for (int q = 0; q < CDIM; q++) v[q] *= rs;
            *(float4*)&out[(size_t)rr*CDIM]     = make_float4(v[0], v[1], v[2], v[3]);
            *(float4*)&out[(size_t)rr*CDIM + 4] = make_float4(v[4], v[5], v[6], v[7]);
        }
    }
}

extern "C" void kernel_launch(void* const* d_in, const int* in_sizes, int n_in,
                              void* d_out, int out_size, void* d_ws, size_t ws_size,
                              hipStream_t stream) {
    const float* x   = (const float*)d_in[0];
    const int*   ei  = (const int*)d_in[1];
    const float* Wl1 = (const float*)d_in[2];
    const float* bl1 = (const float*)d_in[3];
    const float* Wr1 = (const float*)d_in[4];
    const float* Wl2 = (const float*)d_in[5];
    const float* bl2 = (const float*)d_in[6];
    const float* Wr2 = (const float*)d_in[7];
    const float* W1  = (const float*)d_in[8];
    const float* b1  = (const float*)d_in[9];
    const float* W2  = (const float*)d_in[10];
    const float* b2  = (const float*)d_in[11];

    float* ws     = (float*)d_ws;
    float* part   = ws + OFF_PART;
    float* params = ws + OFF_PARAMS;
    int*   deg    = (int*)(ws + OFF_DEG);
    int*   rowptr = (int*)(ws + OFF_ROWPTR);
    int*   bsums  = (int*)(ws + OFF_BSUMS);
    float4* h0    = (float4*)(ws + OFF_H0);
    float4* agg1  = (float4*)(ws + OFF_AGG1);
    int*   csr    = (int*)(ws + OFF_CSR);
    __hip_bfloat16* Wpk2 = (__hip_bfloat16*)(ws + OFF_WPK2);
    __hip_bfloat16* Wpk1 = (__hip_bfloat16*)(ws + OFF_WPK1);
    __hip_bfloat16* W2pk = (__hip_bfloat16*)(ws + OFF_W2PK);
    __hip_bfloat16* Xb   = (__hip_bfloat16*)(ws + OFF_XB);

    hipMemsetAsync(deg, 0, (size_t)N_NODES * sizeof(int), stream);

    pack_k<<<(69632 + 255) / 256, 256, 0, stream>>>(Wl2, Wr2, W1, W2, Wpk2, Wpk1, W2pk);
    stats_partial_k<<<NB_STATS, 256, 0, stream>>>(x, part);
    stats_final_k<<<1, 64, 0, stream>>>(part, params);
    normalize_k<<<(N_NODES + 255) / 256, 256, 0, stream>>>(x, params, h0);

    deg_count_k<<<(N_EDGES + 255) / 256, 256, 0, stream>>>(ei, deg);
    const int nb_scan = (N_NODES + 1023) / 1024;
    scan1_k<<<nb_scan, 256, 0, stream>>>(deg, rowptr, bsums);
    scan2_k<<<1, 64, 0, stream>>>(bsums, nb_scan);
    scan3_k<<<nb_scan, 256, 0, stream>>>(rowptr, bsums);
    scatter_k<<<(N_EDGES + 255) / 256, 256, 0, stream>>>(ei, rowptr, csr);

    agg1_k<<<(N_NODES + 255) / 256, 256, 0, stream>>>(h0, rowptr, deg, csr, agg1);
    conv1_dense_k<<<N_NODES / 2, 256, 0, stream>>>(h0, agg1, Wl1, bl1, Wr1, Xb);
    agg2_k<<<N_NODES / 4, 256, 0, stream>>>(Xb, rowptr, deg, csr);
    const int gtiles = (N_NODES + 63) / 64;
    conv2_mfma_k<<<gtiles, 256, 0, stream>>>(Xb, Wpk2, bl2);
    mlp_mfma_k<<<gtiles, 256, 0, stream>>>(Xb, Wpk1, b1, W2pk, b2, (float*)d_out);
}

// Round 6
// 325.110 us; speedup vs baseline: 5.0692x; 1.1028x over previous
//
#include <hip/hip_runtime.h>
#include <hip/hip_bf16.h>
#include <math.h>

#define N_NODES 100000
#define N_EDGES 600000
#define H 128
#define LH 256
#define CDIM 8
#define NB_STATS 64
#define NTILES ((N_NODES + 63) / 64)   // 1563

typedef __attribute__((ext_vector_type(8))) short short8;
typedef __attribute__((ext_vector_type(4))) float floatx4;

// ------------- workspace layout (4-byte words) -------------
#define OFF_PART   0
#define OFF_PARAMS 704
#define OFF_DEG    712
#define OFF_ROWPTR (OFF_DEG + N_NODES)
#define OFF_BSUMS  (OFF_ROWPTR + N_NODES)
#define OFF_H0     (OFF_BSUMS + 128)            // N*4 fp32 (float4 rows)
#define OFF_AGG1   (OFF_H0 + N_NODES*4)         // N*4 fp32
#define OFF_CSR    (OFF_AGG1 + N_NODES*4)
#define OFF_WPK2   (OFF_CSR + N_EDGES)          // 32768 bf16 = 16384 words
#define OFF_WPK1   (OFF_WPK2 + 16384)           // 32768 bf16
#define OFF_W2PK   (OFF_WPK1 + 16384)           // 4096 bf16 = 2048 words
#define OFF_XB     (OFF_W2PK + 2048)            // N*256 bf16 = 12.8M words

__device__ __forceinline__ float rot_c() { return cosf(1.57079632679489661923f); }
__device__ __forceinline__ float rot_s() { return sinf(1.57079632679489661923f); }
__device__ __forceinline__ float bfhi(unsigned v) { return __uint_as_float(v & 0xffff0000u); }
__device__ __forceinline__ float bflo(unsigned v) { return __uint_as_float(v << 16); }
__device__ __forceinline__ unsigned short bfu(float f) {
    __hip_bfloat16 h = __float2bfloat16(f);
    return *(unsigned short*)&h;
}

// ---------------- stats partial (also zeroes deg) ----------------
__global__ void stats_partial_k(const float* __restrict__ x, float* __restrict__ part,
                                int* __restrict__ deg) {
    const float c = rot_c(), sn = rot_s();
    float mn0 = INFINITY, mx0 = -INFINITY, mn1 = INFINITY, mx1 = -INFINITY;
    float s0 = 0.f, s1 = 0.f, sr0 = 0.f, sr1 = 0.f;
    float mxr0 = -INFINITY, mxr1 = -INFINITY, mxa = -INFINITY;
    for (int i = blockIdx.x * blockDim.x + threadIdx.x; i < N_NODES;
         i += gridDim.x * blockDim.x) {
        deg[i] = 0;
        float x0 = x[3*i], x1 = x[3*i+1], a = x[3*i+2];
        float r0 = c*x0 - sn*x1;
        float r1 = sn*x0 + c*x1;
        mn0 = fminf(mn0, x0); mx0 = fmaxf(mx0, x0);
        mn1 = fminf(mn1, x1); mx1 = fmaxf(mx1, x1);
        s0 += x0; s1 += x1; sr0 += r0; sr1 += r1;
        mxr0 = fmaxf(mxr0, r0); mxr1 = fmaxf(mxr1, r1);
        mxa = fmaxf(mxa, a);
    }
    __shared__ float red[256];
    float vals[11] = {mn0, mx0, mn1, mx1, s0, s1, sr0, sr1, mxr0, mxr1, mxa};
    const int ops[11] = {0,1,0,1,2,2,2,2,1,1,1};
    for (int v = 0; v < 11; v++) {
        red[threadIdx.x] = vals[v];
        __syncthreads();
        for (int s = 128; s > 0; s >>= 1) {
            if ((int)threadIdx.x < s) {
                float a = red[threadIdx.x], b = red[threadIdx.x + s];
                red[threadIdx.x] = (ops[v]==0) ? fminf(a,b) : (ops[v]==1) ? fmaxf(a,b) : (a+b);
            }
            __syncthreads();
        }
        if (threadIdx.x == 0) part[blockIdx.x * 11 + v] = red[0];
        __syncthreads();
    }
}

// ---------------- normalize (+ final stats reduce + weight pre-pack) ------
__global__ __launch_bounds__(256) void normalize_k(const float* __restrict__ x,
        const float* __restrict__ part, float4* __restrict__ h0,
        const float* __restrict__ Wl2, const float* __restrict__ Wr2,
        const float* __restrict__ W1, const float* __restrict__ W2,
        __hip_bfloat16* __restrict__ Wpk2, __hip_bfloat16* __restrict__ Wpk1,
        __hip_bfloat16* __restrict__ W2pk) {
    __shared__ float res[11];
    int tid = threadIdx.x;
    if (tid < 64) {
        const int ops[11] = {0,1,0,1,2,2,2,2,1,1,1};
        for (int v = 0; v < 11; v++) {
            float val = part[tid * 11 + v];
            #pragma unroll
            for (int off = 32; off > 0; off >>= 1) {
                float o = __shfl_down(val, off);
                val = (ops[v]==0) ? fminf(val,o) : (ops[v]==1) ? fmaxf(val,o) : (val+o);
            }
            if (tid == 0) res[v] = val;
        }
    }
    __syncthreads();
    int rotate = (res[3] - res[2]) > (res[1] - res[0]);
    float mean0 = (rotate ? res[6] : res[4]) / (float)N_NODES;
    float mean1 = (rotate ? res[7] : res[5]) / (float)N_NODES;
    float imx0  = 1.0f / (rotate ? res[8] : res[1]);
    float imx1  = 1.0f / (rotate ? res[9] : res[3]);
    float imxa  = 1.0f / res[10];

    int i = blockIdx.x * blockDim.x + tid;
    if (i < N_NODES) {
        const float c = rot_c(), sn = rot_s();
        float x0 = x[3*i], x1 = x[3*i+1], a = x[3*i+2];
        float u0 = rotate ? (c*x0 - sn*x1) : x0;
        float u1 = rotate ? (sn*x0 + c*x1) : x1;
        h0[i] = make_float4((u0 - mean0) * imx0, (u1 - mean1) * imx1, a * imxa, 0.f);
    }
    // weight pre-pack into MFMA B-fragment order (blocks 0..271 cover idx<69632)
    int idx = i;
    if (idx < 32768) {                       // Wpk2[ks8][nt8][lane64][j8], K=256,N=128
        int j = idx & 7, lane = (idx >> 3) & 63, nt = (idx >> 9) & 7, ks = idx >> 12;
        int k = ks*32 + (lane >> 4)*8 + j;
        int n = nt*16 + (lane & 15);
        float v = (k < 128) ? Wl2[n*H + k] : Wr2[n*H + (k - 128)];
        Wpk2[idx] = __float2bfloat16(v);
    } else if (idx < 65536) {                // Wpk1[ks4][nt16][lane64][j8], K=128,N=256
        int i2 = idx - 32768;
        int j = i2 & 7, lane = (i2 >> 3) & 63, nt = (i2 >> 9) & 15, ks = i2 >> 13;
        int k = ks*32 + (lane >> 4)*8 + j;
        int n = nt*16 + (lane & 15);
        Wpk1[i2] = __float2bfloat16(W1[n*H + k]);
    } else if (idx < 69632) {                // W2pk[ks8][lane64][j8], K=256,N=16(8 real)
        int i3 = idx - 65536;
        int j = i3 & 7, lane = (i3 >> 3) & 63, ks = i3 >> 9;
        int k = ks*32 + (lane >> 4)*8 + j;
        int n = lane & 15;
        W2pk[i3] = __float2bfloat16((n < CDIM) ? W2[n*LH + k] : 0.f);
    }
}

// ---------------- CSR build ----------------
__global__ void deg_count_k(const int* __restrict__ ei, int* __restrict__ deg) {
    int e = blockIdx.x * blockDim.x + threadIdx.x;
    if (e >= N_EDGES) return;
    atomicAdd(&deg[ei[N_EDGES + e]], 1);
}

__global__ void scan1_k(const int* __restrict__ deg, int* __restrict__ rowptr,
                        int* __restrict__ bsums) {
    __shared__ int s[256];
    int t = threadIdx.x;
    int base = blockIdx.x * 1024 + t * 4;
    int d0 = (base+0 < N_NODES) ? deg[base+0] : 0;
    int d1 = (base+1 < N_NODES) ? deg[base+1] : 0;
    int d2 = (base+2 < N_NODES) ? deg[base+2] : 0;
    int d3 = (base+3 < N_NODES) ? deg[base+3] : 0;
    int tsum = d0 + d1 + d2 + d3;
    s[t] = tsum;
    __syncthreads();
    for (int off = 1; off < 256; off <<= 1) {
        int v = (t >= off) ? s[t - off] : 0;
        __syncthreads();
        s[t] += v;
        __syncthreads();
    }
    int excl = s[t] - tsum;
    if (base+0 < N_NODES) rowptr[base+0] = excl;
    if (base+1 < N_NODES) rowptr[base+1] = excl + d0;
    if (base+2 < N_NODES) rowptr[base+2] = excl + d0 + d1;
    if (base+3 < N_NODES) rowptr[base+3] = excl + d0 + d1 + d2;
    if (t == 255) bsums[blockIdx.x] = s[255];
}

// scan3 with folded scan2: add = sum of bsums[0..blockIdx-1]
__global__ void scan3_k(int* __restrict__ rowptr, const int* __restrict__ bsums, int nb) {
    __shared__ int sb[256];
    int t = threadIdx.x;
    sb[t] = (t < (int)blockIdx.x && t < nb) ? bsums[t] : 0;
    __syncthreads();
    for (int s = 128; s > 0; s >>= 1) {
        if (t < s) sb[t] += sb[t + s];
        __syncthreads();
    }
    int add = sb[0];
    int base = blockIdx.x * 1024 + t * 4;
    if (base+0 < N_NODES) rowptr[base+0] += add;
    if (base+1 < N_NODES) rowptr[base+1] += add;
    if (base+2 < N_NODES) rowptr[base+2] += add;
    if (base+3 < N_NODES) rowptr[base+3] += add;
}

__global__ void scatter_k(const int* __restrict__ ei, int* __restrict__ rowptr,
                          int* __restrict__ csr) {
    int e = blockIdx.x * blockDim.x + threadIdx.x;
    if (e >= N_EDGES) return;
    int d = ei[N_EDGES + e];
    int pos = atomicAdd(&rowptr[d], 1);
    csr[pos] = ei[e];
}

// ---------------- agg1: mean of h0 over in-neighbors (1 thread / node) ----
__global__ void agg1_k(const float4* __restrict__ h0, const int* __restrict__ rowptr,
                       const int* __restrict__ deg, const int* __restrict__ csr,
                       float4* __restrict__ agg1) {
    int n = blockIdx.x * blockDim.x + threadIdx.x;
    if (n >= N_NODES) return;
    int dg = deg[n];
    int end = rowptr[n], start = end - dg;
    float a0 = 0.f, a1 = 0.f, a2 = 0.f;
    int e = start;
    for (; e + 3 < end; e += 4) {
        int s0 = csr[e], s1 = csr[e+1], s2 = csr[e+2], s3 = csr[e+3];
        float4 v0 = h0[s0];
        float4 v1 = h0[s1];
        float4 v2 = h0[s2];
        float4 v3 = h0[s3];
        a0 += (v0.x + v1.x) + (v2.x + v3.x);
        a1 += (v0.y + v1.y) + (v2.y + v3.y);
        a2 += (v0.z + v1.z) + (v2.z + v3.z);
    }
    for (; e < end; e++) {
        float4 v = h0[csr[e]];
        a0 += v.x; a1 += v.y; a2 += v.z;
    }
    float inv = 1.0f / (float)max(dg, 1);
    agg1[n] = make_float4(a0 * inv, a1 * inv, a2 * inv, 0.f);
}

// ---------------- conv1 dense: grid-stride, weights staged once ----------
__global__ __launch_bounds__(256) void conv1_dense_k(const float4* __restrict__ h0,
        const float4* __restrict__ agg1,
        const float* __restrict__ Wl1, const float* __restrict__ bl1,
        const float* __restrict__ Wr1, __hip_bfloat16* __restrict__ Xb) {
    __shared__ float wl[H*3], wr[H*3], bb[H];
    int tid = threadIdx.x;
    for (int i = tid; i < H*3; i += 256) { wl[i] = Wl1[i]; wr[i] = Wr1[i]; }
    if (tid < H) bb[tid] = bl1[tid];
    __syncthreads();
    int sub = tid >> 6;            // 4 nodes per iteration
    int j2 = (tid & 63) * 2;       // column pair
    int stride = gridDim.x * 4;
    for (int base = blockIdx.x * 4; base < N_NODES; base += stride) {
        int n = base + sub;        // N_NODES % 4 == 0 -> always valid
        float4 a = agg1[n];
        float4 xv = h0[n];
        float o0 = wl[3*j2+0]*a.x + wl[3*j2+1]*a.y + wl[3*j2+2]*a.z + bb[j2]
                 + wr[3*j2+0]*xv.x + wr[3*j2+1]*xv.y + wr[3*j2+2]*xv.z;
        float o1 = wl[3*j2+3]*a.x + wl[3*j2+4]*a.y + wl[3*j2+5]*a.z + bb[j2+1]
                 + wr[3*j2+3]*xv.x + wr[3*j2+4]*xv.y + wr[3*j2+5]*xv.z;
        unsigned pv = ((unsigned)bfu(tanhf(o1)) << 16) | (unsigned)bfu(tanhf(o0));
        *(unsigned*)&Xb[(size_t)n*256 + 128 + j2] = pv;
    }
}

// ---------------- agg2: mean of h1 (bf16) -> Xb[n][0..127]
// half-wave (32 lanes) per node, 4 cols/lane: 32*4 = exactly 128 cols.
__global__ void agg2_k(__hip_bfloat16* __restrict__ Xb, const int* __restrict__ rowptr,
                       const int* __restrict__ deg, const int* __restrict__ csr) {
    int lane = threadIdx.x & 31;
    int n = blockIdx.x * 8 + (threadIdx.x >> 5);
    int dg = deg[n];
    int end = rowptr[n], start = end - dg;
    float a0 = 0.f, a1 = 0.f, a2 = 0.f, a3 = 0.f;
    int e = start;
    for (; e + 3 < end; e += 4) {
        int s0 = csr[e], s1 = csr[e+1], s2 = csr[e+2], s3 = csr[e+3];
        uint2 v0 = *(const uint2*)&Xb[(size_t)s0*256 + 128 + lane*4];
        uint2 v1 = *(const uint2*)&Xb[(size_t)s1*256 + 128 + lane*4];
        uint2 v2 = *(const uint2*)&Xb[(size_t)s2*256 + 128 + lane*4];
        uint2 v3 = *(const uint2*)&Xb[(size_t)s3*256 + 128 + lane*4];
        a0 += (bflo(v0.x) + bflo(v1.x)) + (bflo(v2.x) + bflo(v3.x));
        a1 += (bfhi(v0.x) + bfhi(v1.x)) + (bfhi(v2.x) + bfhi(v3.x));
        a2 += (bflo(v0.y) + bflo(v1.y)) + (bflo(v2.y) + bflo(v3.y));
        a3 += (bfhi(v0.y) + bfhi(v1.y)) + (bfhi(v2.y) + bfhi(v3.y));
    }
    for (; e < end; e++) {
        uint2 v = *(const uint2*)&Xb[(size_t)csr[e]*256 + 128 + lane*4];
        a0 += bflo(v.x); a1 += bfhi(v.x); a2 += bflo(v.y); a3 += bfhi(v.y);
    }
    float inv = 1.0f / (float)max(dg, 1);
    uint2 o;
    o.x = ((unsigned)bfu(a1*inv) << 16) | (unsigned)bfu(a0*inv);
    o.y = ((unsigned)bfu(a3*inv) << 16) | (unsigned)bfu(a2*inv);
    *(uint2*)&Xb[(size_t)n*256 + lane*4] = o;
}

// ---------------- conv2 MFMA: grid-stride, weights persistent in LDS ------
__global__ __launch_bounds__(256, 2) void conv2_mfma_k(__hip_bfloat16* __restrict__ Xb,
        const __hip_bfloat16* __restrict__ Wpk2, const float* __restrict__ bl2) {
    __shared__ short Ws[32768];   // 64 KB: [ks8][nt8][lane64][j8]
    int tid = threadIdx.x;
    {
        const float4* s = (const float4*)Wpk2;
        float4* d = (float4*)Ws;
        #pragma unroll
        for (int i = 0; i < 16; i++) d[tid + i*256] = s[tid + i*256];
    }
    __syncthreads();
    int lane = tid & 63, wave = tid >> 6;
    int quad = lane >> 4, m = lane & 15, c0 = lane & 15;
    for (int tile = blockIdx.x; tile < NTILES; tile += gridDim.x) {
        int row = tile * 64 + wave * 16 + m;
        int rowL = row < N_NODES ? row : N_NODES - 1;
        const short* Arow = (const short*)Xb + (size_t)rowL * 256;
        floatx4 acc[8];
        #pragma unroll
        for (int i = 0; i < 8; i++)
            #pragma unroll
            for (int r = 0; r < 4; r++) acc[i][r] = 0.f;
        #pragma unroll
        for (int ks = 0; ks < 8; ks++) {
            short8 a = *(const short8*)(Arow + ks*32 + quad*8);
            #pragma unroll
            for (int nt = 0; nt < 8; nt++) {
                short8 b = *(const short8*)&Ws[((ks*8 + nt)*64 + lane)*8];
                acc[nt] = __builtin_amdgcn_mfma_f32_16x16x32_bf16(a, b, acc[nt], 0, 0, 0);
            }
        }
        int rbase = tile * 64 + wave * 16 + quad * 4;
        #pragma unroll
        for (int nt = 0; nt < 8; nt++) {
            int col = nt*16 + c0;
            float bb = bl2[col];
            #pragma unroll
            for (int r = 0; r < 4; r++) {
                int rr = rbase + r;
                if (rr < N_NODES)
                    Xb[(size_t)rr*256 + col] = __float2bfloat16(tanhf(acc[nt][r] + bb));
            }
        }
    }
}

// ---------------- fused MLP MFMA: grid-stride, weights persistent ---------
#define TP 264
__global__ __launch_bounds__(256, 1) void mlp_mfma_k(const __hip_bfloat16* __restrict__ Xb,
        const __hip_bfloat16* __restrict__ Wpk1, const float* __restrict__ b1,
        const __hip_bfloat16* __restrict__ W2pk, const float* __restrict__ b2,
        float* __restrict__ out) {
    __shared__ short Ws[32768];     // 64 KB W1 frags (persistent)
    __shared__ short T[64 * TP];    // 33 KB t-tile
    __shared__ short W2s[4096];     // 8 KB
    __shared__ float lg[4][16][16]; // 4 KB
    int tid = threadIdx.x;
    {
        const float4* s = (const float4*)Wpk1;
        float4* d = (float4*)Ws;
        #pragma unroll
        for (int i = 0; i < 16; i++) d[tid + i*256] = s[tid + i*256];
        const float4* s2 = (const float4*)W2pk;
        float4* d2 = (float4*)W2s;
        d2[tid] = s2[tid];
        d2[tid + 256] = s2[tid + 256];
    }
    __syncthreads();
    int lane = tid & 63, wave = tid >> 6;
    int quad = lane >> 4, m = lane & 15, c0 = lane & 15;
    for (int tile = blockIdx.x; tile < NTILES; tile += gridDim.x) {
        int row = tile * 64 + wave * 16 + m;
        int rowL = row < N_NODES ? row : N_NODES - 1;
        const short* Arow = (const short*)Xb + (size_t)rowL * 256;   // h2 cols 0..127
        floatx4 acc[16];
        #pragma unroll
        for (int i = 0; i < 16; i++)
            #pragma unroll
            for (int r = 0; r < 4; r++) acc[i][r] = 0.f;
        #pragma unroll
        for (int ks = 0; ks < 4; ks++) {
            short8 a = *(const short8*)(Arow + ks*32 + quad*8);
            #pragma unroll
            for (int nt = 0; nt < 16; nt++) {
                short8 b = *(const short8*)&Ws[((ks*16 + nt)*64 + lane)*8];
                acc[nt] = __builtin_amdgcn_mfma_f32_16x16x32_bf16(a, b, acc[nt], 0, 0, 0);
            }
        }
        int mrow = wave * 16 + quad * 4;
        #pragma unroll
        for (int nt = 0; nt < 16; nt++) {
            int col = nt*16 + c0;
            float bb = b1[col];
            #pragma unroll
            for (int r = 0; r < 4; r++) {
                __hip_bfloat16 h = __float2bfloat16(tanhf(acc[nt][r] + bb));
                T[(mrow + r)*TP + col] = *(short*)&h;
            }
        }
        __syncthreads();
        floatx4 lacc;
        #pragma unroll
        for (int r = 0; r < 4; r++) lacc[r] = 0.f;
        const short* Trow = T + (size_t)(wave*16 + m) * TP;
        #pragma unroll
        for (int ks = 0; ks < 8; ks++) {
            short8 a = *(const short8*)(Trow + ks*32 + quad*8);
            short8 b = *(const short8*)&W2s[(ks*64 + lane)*8];
            lacc = __builtin_amdgcn_mfma_f32_16x16x32_bf16(a, b, lacc, 0, 0, 0);
        }
        #pragma unroll
        for (int r = 0; r < 4; r++) lg[wave][quad*4 + r][c0] = lacc[r];
        __syncthreads();
        if (lane < 16) {
            int rr = tile * 64 + wave * 16 + lane;
            if (rr < N_NODES) {
                float v[CDIM];
                float mx = -INFINITY;
                #pragma unroll
                for (int q = 0; q < CDIM; q++) { v[q] = lg[wave][lane][q] + b2[q]; mx = fmaxf(mx, v[q]); }
                float ssum = 0.f;
                #pragma unroll
                for (int q = 0; q < CDIM; q++) { v[q] = expf(v[q] - mx); ssum += v[q]; }
                float rs = 1.0f / ssum;
                #pragma unroll
                for (int q = 0; q < CDIM; q++) v[q] *= rs;
                *(float4*)&out[(size_t)rr*CDIM]     = make_float4(v[0], v[1], v[2], v[3]);
                *(float4*)&out[(size_t)rr*CDIM + 4] = make_float4(v[4], v[5], v[6], v[7]);
            }
        }
    }
}

extern "C" void kernel_launch(void* const* d_in, const int* in_sizes, int n_in,
                              void* d_out, int out_size, void* d_ws, size_t ws_size,
                              hipStream_t stream) {
    const float* x   = (const float*)d_in[0];
    const int*   ei  = (const int*)d_in[1];
    const float* Wl1 = (const float*)d_in[2];
    const float* bl1 = (const float*)d_in[3];
    const float* Wr1 = (const float*)d_in[4];
    const float* Wl2 = (const float*)d_in[5];
    const float* bl2 = (const float*)d_in[6];
    const float* Wr2 = (const float*)d_in[7];
    const float* W1  = (const float*)d_in[8];
    const float* b1  = (const float*)d_in[9];
    const float* W2  = (const float*)d_in[10];
    const float* b2  = (const float*)d_in[11];

    float* ws     = (float*)d_ws;
    float* part   = ws + OFF_PART;
    int*   deg    = (int*)(ws + OFF_DEG);
    int*   rowptr = (int*)(ws + OFF_ROWPTR);
    int*   bsums  = (int*)(ws + OFF_BSUMS);
    float4* h0    = (float4*)(ws + OFF_H0);
    float4* agg1  = (float4*)(ws + OFF_AGG1);
    int*   csr    = (int*)(ws + OFF_CSR);
    __hip_bfloat16* Wpk2 = (__hip_bfloat16*)(ws + OFF_WPK2);
    __hip_bfloat16* Wpk1 = (__hip_bfloat16*)(ws + OFF_WPK1);
    __hip_bfloat16* W2pk = (__hip_bfloat16*)(ws + OFF_W2PK);
    __hip_bfloat16* Xb   = (__hip_bfloat16*)(ws + OFF_XB);

    const int nb_scan = (N_NODES + 1023) / 1024;   // 98

    stats_partial_k<<<NB_STATS, 256, 0, stream>>>(x, part, deg);
    normalize_k<<<(N_NODES + 255) / 256, 256, 0, stream>>>(x, part, h0,
            Wl2, Wr2, W1, W2, Wpk2, Wpk1, W2pk);
    deg_count_k<<<(N_EDGES + 255) / 256, 256, 0, stream>>>(ei, deg);
    scan1_k<<<nb_scan, 256, 0, stream>>>(deg, rowptr, bsums);
    scan3_k<<<nb_scan, 256, 0, stream>>>(rowptr, bsums, nb_scan);
    scatter_k<<<(N_EDGES + 255) / 256, 256, 0, stream>>>(ei, rowptr, csr);

    agg1_k<<<(N_NODES + 255) / 256, 256, 0, stream>>>(h0, rowptr, deg, csr, agg1);
    conv1_dense_k<<<1024, 256, 0, stream>>>(h0, agg1, Wl1, bl1, Wr1, Xb);
    agg2_k<<<N_NODES / 8, 256, 0, stream>>>(Xb, rowptr, deg, csr);
    conv2_mfma_k<<<512, 256, 0, stream>>>(Xb, Wpk2, bl2);
    mlp_mfma_k<<<256, 256, 0, stream>>>(Xb, Wpk1, b1, W2pk, b2, (float*)d_out);
}

// Round 7
// 316.209 us; speedup vs baseline: 5.2119x; 1.0281x over previous
//
#include <hip/hip_runtime.h>
#include <hip/hip_bf16.h>
#include <math.h>

#define N_NODES 100000
#define N_EDGES 600000
#define H 128
#define LH 256
#define CDIM 8
#define NB_STATS 64
#define NTILES ((N_NODES + 63) / 64)     // 1563 (64-row tiles, mlp)
#define NT2    ((N_NODES + 127) / 128)   // 782  (128-row tiles, conv2)

typedef __attribute__((ext_vector_type(8))) short short8;
typedef __attribute__((ext_vector_type(4))) float floatx4;

// ------------- workspace layout (4-byte words) -------------
#define OFF_PART   0
#define OFF_PARAMS 704
#define OFF_DEG    712
#define OFF_ROWPTR (OFF_DEG + N_NODES)
#define OFF_BSUMS  (OFF_ROWPTR + N_NODES)
#define OFF_H0     (OFF_BSUMS + 128)            // N*4 fp32 (float4 rows)
#define OFF_AGG1   (OFF_H0 + N_NODES*4)         // (unused now, kept for layout)
#define OFF_CSR    (OFF_AGG1 + N_NODES*4)
#define OFF_WPK2   (OFF_CSR + N_EDGES)          // 32768 bf16 = 16384 words
#define OFF_WPK1   (OFF_WPK2 + 16384)           // 32768 bf16
#define OFF_W2PK   (OFF_WPK1 + 16384)           // 4096 bf16 = 2048 words
#define OFF_XB     (OFF_W2PK + 2048)            // N*256 bf16 = 12.8M words

__device__ __forceinline__ float rot_c() { return cosf(1.57079632679489661923f); }
__device__ __forceinline__ float rot_s() { return sinf(1.57079632679489661923f); }
__device__ __forceinline__ float bfhi(unsigned v) { return __uint_as_float(v & 0xffff0000u); }
__device__ __forceinline__ float bflo(unsigned v) { return __uint_as_float(v << 16); }
__device__ __forceinline__ unsigned short bfu(float f) {
    __hip_bfloat16 h = __float2bfloat16(f);
    return *(unsigned short*)&h;
}

// ---------------- stats partial (also zeroes deg) ----------------
__global__ void stats_partial_k(const float* __restrict__ x, float* __restrict__ part,
                                int* __restrict__ deg) {
    const float c = rot_c(), sn = rot_s();
    float mn0 = INFINITY, mx0 = -INFINITY, mn1 = INFINITY, mx1 = -INFINITY;
    float s0 = 0.f, s1 = 0.f, sr0 = 0.f, sr1 = 0.f;
    float mxr0 = -INFINITY, mxr1 = -INFINITY, mxa = -INFINITY;
    for (int i = blockIdx.x * blockDim.x + threadIdx.x; i < N_NODES;
         i += gridDim.x * blockDim.x) {
        deg[i] = 0;
        float x0 = x[3*i], x1 = x[3*i+1], a = x[3*i+2];
        float r0 = c*x0 - sn*x1;
        float r1 = sn*x0 + c*x1;
        mn0 = fminf(mn0, x0); mx0 = fmaxf(mx0, x0);
        mn1 = fminf(mn1, x1); mx1 = fmaxf(mx1, x1);
        s0 += x0; s1 += x1; sr0 += r0; sr1 += r1;
        mxr0 = fmaxf(mxr0, r0); mxr1 = fmaxf(mxr1, r1);
        mxa = fmaxf(mxa, a);
    }
    __shared__ float red[256];
    float vals[11] = {mn0, mx0, mn1, mx1, s0, s1, sr0, sr1, mxr0, mxr1, mxa};
    const int ops[11] = {0,1,0,1,2,2,2,2,1,1,1};
    for (int v = 0; v < 11; v++) {
        red[threadIdx.x] = vals[v];
        __syncthreads();
        for (int s = 128; s > 0; s >>= 1) {
            if ((int)threadIdx.x < s) {
                float a = red[threadIdx.x], b = red[threadIdx.x + s];
                red[threadIdx.x] = (ops[v]==0) ? fminf(a,b) : (ops[v]==1) ? fmaxf(a,b) : (a+b);
            }
            __syncthreads();
        }
        if (threadIdx.x == 0) part[blockIdx.x * 11 + v] = red[0];
        __syncthreads();
    }
}

// ---------------- normalize (+ final stats reduce + weight pre-pack) ------
__global__ __launch_bounds__(256) void normalize_k(const float* __restrict__ x,
        const float* __restrict__ part, float4* __restrict__ h0,
        const float* __restrict__ Wl2, const float* __restrict__ Wr2,
        const float* __restrict__ W1, const float* __restrict__ W2,
        __hip_bfloat16* __restrict__ Wpk2, __hip_bfloat16* __restrict__ Wpk1,
        __hip_bfloat16* __restrict__ W2pk) {
    __shared__ float res[11];
    int tid = threadIdx.x;
    if (tid < 64) {
        const int ops[11] = {0,1,0,1,2,2,2,2,1,1,1};
        for (int v = 0; v < 11; v++) {
            float val = part[tid * 11 + v];
            #pragma unroll
            for (int off = 32; off > 0; off >>= 1) {
                float o = __shfl_down(val, off);
                val = (ops[v]==0) ? fminf(val,o) : (ops[v]==1) ? fmaxf(val,o) : (val+o);
            }
            if (tid == 0) res[v] = val;
        }
    }
    __syncthreads();
    int rotate = (res[3] - res[2]) > (res[1] - res[0]);
    float mean0 = (rotate ? res[6] : res[4]) / (float)N_NODES;
    float mean1 = (rotate ? res[7] : res[5]) / (float)N_NODES;
    float imx0  = 1.0f / (rotate ? res[8] : res[1]);
    float imx1  = 1.0f / (rotate ? res[9] : res[3]);
    float imxa  = 1.0f / res[10];

    int i = blockIdx.x * blockDim.x + tid;
    if (i < N_NODES) {
        const float c = rot_c(), sn = rot_s();
        float x0 = x[3*i], x1 = x[3*i+1], a = x[3*i+2];
        float u0 = rotate ? (c*x0 - sn*x1) : x0;
        float u1 = rotate ? (sn*x0 + c*x1) : x1;
        h0[i] = make_float4((u0 - mean0) * imx0, (u1 - mean1) * imx1, a * imxa, 0.f);
    }
    int idx = i;
    if (idx < 32768) {                       // Wpk2[ks8][nt8][lane64][j8], K=256,N=128
        int j = idx & 7, lane = (idx >> 3) & 63, nt = (idx >> 9) & 7, ks = idx >> 12;
        int k = ks*32 + (lane >> 4)*8 + j;
        int n = nt*16 + (lane & 15);
        float v = (k < 128) ? Wl2[n*H + k] : Wr2[n*H + (k - 128)];
        Wpk2[idx] = __float2bfloat16(v);
    } else if (idx < 65536) {                // Wpk1[ks4][nt16][lane64][j8], K=128,N=256
        int i2 = idx - 32768;
        int j = i2 & 7, lane = (i2 >> 3) & 63, nt = (i2 >> 9) & 15, ks = i2 >> 13;
        int k = ks*32 + (lane >> 4)*8 + j;
        int n = nt*16 + (lane & 15);
        Wpk1[i2] = __float2bfloat16(W1[n*H + k]);
    } else if (idx < 69632) {                // W2pk[ks8][lane64][j8], K=256,N=16(8 real)
        int i3 = idx - 65536;
        int j = i3 & 7, lane = (i3 >> 3) & 63, ks = i3 >> 9;
        int k = ks*32 + (lane >> 4)*8 + j;
        int n = lane & 15;
        W2pk[i3] = __float2bfloat16((n < CDIM) ? W2[n*LH + k] : 0.f);
    }
}

// ---------------- CSR build ----------------
__global__ void deg_count_k(const int* __restrict__ ei, int* __restrict__ deg) {
    int e = blockIdx.x * blockDim.x + threadIdx.x;
    if (e >= N_EDGES) return;
    atomicAdd(&deg[ei[N_EDGES + e]], 1);
}

__global__ void scan1_k(const int* __restrict__ deg, int* __restrict__ rowptr,
                        int* __restrict__ bsums) {
    __shared__ int s[256];
    int t = threadIdx.x;
    int base = blockIdx.x * 1024 + t * 4;
    int d0 = (base+0 < N_NODES) ? deg[base+0] : 0;
    int d1 = (base+1 < N_NODES) ? deg[base+1] : 0;
    int d2 = (base+2 < N_NODES) ? deg[base+2] : 0;
    int d3 = (base+3 < N_NODES) ? deg[base+3] : 0;
    int tsum = d0 + d1 + d2 + d3;
    s[t] = tsum;
    __syncthreads();
    for (int off = 1; off < 256; off <<= 1) {
        int v = (t >= off) ? s[t - off] : 0;
        __syncthreads();
        s[t] += v;
        __syncthreads();
    }
    int excl = s[t] - tsum;
    if (base+0 < N_NODES) rowptr[base+0] = excl;
    if (base+1 < N_NODES) rowptr[base+1] = excl + d0;
    if (base+2 < N_NODES) rowptr[base+2] = excl + d0 + d1;
    if (base+3 < N_NODES) rowptr[base+3] = excl + d0 + d1 + d2;
    if (t == 255) bsums[blockIdx.x] = s[255];
}

// scan3 with folded scan2: add = sum of bsums[0..blockIdx-1]
__global__ void scan3_k(int* __restrict__ rowptr, const int* __restrict__ bsums, int nb) {
    __shared__ int sb[256];
    int t = threadIdx.x;
    sb[t] = (t < (int)blockIdx.x && t < nb) ? bsums[t] : 0;
    __syncthreads();
    for (int s = 128; s > 0; s >>= 1) {
        if (t < s) sb[t] += sb[t + s];
        __syncthreads();
    }
    int add = sb[0];
    int base = blockIdx.x * 1024 + t * 4;
    if (base+0 < N_NODES) rowptr[base+0] += add;
    if (base+1 < N_NODES) rowptr[base+1] += add;
    if (base+2 < N_NODES) rowptr[base+2] += add;
    if (base+3 < N_NODES) rowptr[base+3] += add;
}

__global__ void scatter_k(const int* __restrict__ ei, int* __restrict__ rowptr,
                          int* __restrict__ csr) {
    int e = blockIdx.x * blockDim.x + threadIdx.x;
    if (e >= N_EDGES) return;
    int d = ei[N_EDGES + e];
    int pos = atomicAdd(&rowptr[d], 1);
    csr[pos] = ei[e];
}

// ---------------- fused agg1 + conv1 dense ----------------
// phase1: thread-per-node mean-gather of h0 -> LDS; phase2: dense 3->128 + tanh
__global__ __launch_bounds__(256) void agg1conv1_k(const float4* __restrict__ h0,
        const int* __restrict__ rowptr, const int* __restrict__ deg,
        const int* __restrict__ csr,
        const float* __restrict__ Wl1, const float* __restrict__ bl1,
        const float* __restrict__ Wr1, __hip_bfloat16* __restrict__ Xb) {
    __shared__ float wl[H*3], wr[H*3], bb[H];
    __shared__ float4 sa[256];
    int tid = threadIdx.x;
    for (int i = tid; i < H*3; i += 256) { wl[i] = Wl1[i]; wr[i] = Wr1[i]; }
    if (tid < H) bb[tid] = bl1[tid];
    int base = blockIdx.x * 256;
    int n = base + tid;
    float4 av = make_float4(0.f, 0.f, 0.f, 0.f);
    if (n < N_NODES) {
        int dg = deg[n];
        int end = rowptr[n], start = end - dg;
        float a0 = 0.f, a1 = 0.f, a2 = 0.f;
        int e = start;
        for (; e + 3 < end; e += 4) {
            int s0 = csr[e], s1 = csr[e+1], s2 = csr[e+2], s3 = csr[e+3];
            float4 v0 = h0[s0];
            float4 v1 = h0[s1];
            float4 v2 = h0[s2];
            float4 v3 = h0[s3];
            a0 += (v0.x + v1.x) + (v2.x + v3.x);
            a1 += (v0.y + v1.y) + (v2.y + v3.y);
            a2 += (v0.z + v1.z) + (v2.z + v3.z);
        }
        for (; e < end; e++) {
            float4 v = h0[csr[e]];
            a0 += v.x; a1 += v.y; a2 += v.z;
        }
        float inv = 1.0f / (float)max(dg, 1);
        av = make_float4(a0 * inv, a1 * inv, a2 * inv, 0.f);
    }
    sa[tid] = av;
    __syncthreads();
    int sub = tid >> 6;
    int j2 = (tid & 63) * 2;
    for (int i = 0; i < 64; i++) {
        int loc = i * 4 + sub;
        int nn = base + loc;
        if (nn >= N_NODES) break;
        float4 a = sa[loc];
        float4 xv = h0[nn];
        float o0 = wl[3*j2+0]*a.x + wl[3*j2+1]*a.y + wl[3*j2+2]*a.z + bb[j2]
                 + wr[3*j2+0]*xv.x + wr[3*j2+1]*xv.y + wr[3*j2+2]*xv.z;
        float o1 = wl[3*j2+3]*a.x + wl[3*j2+4]*a.y + wl[3*j2+5]*a.z + bb[j2+1]
                 + wr[3*j2+3]*xv.x + wr[3*j2+4]*xv.y + wr[3*j2+5]*xv.z;
        unsigned pv = ((unsigned)bfu(tanhf(o1)) << 16) | (unsigned)bfu(tanhf(o0));
        *(unsigned*)&Xb[(size_t)nn*256 + 128 + j2] = pv;
    }
}

// ---------------- agg2: mean of h1 (bf16) -> Xb[n][0..127]
// half-wave (32 lanes) per node, 4 cols/lane: 32*4 = exactly 128 cols.
__global__ void agg2_k(__hip_bfloat16* __restrict__ Xb, const int* __restrict__ rowptr,
                       const int* __restrict__ deg, const int* __restrict__ csr) {
    int lane = threadIdx.x & 31;
    int n = blockIdx.x * 8 + (threadIdx.x >> 5);
    int dg = deg[n];
    int end = rowptr[n], start = end - dg;
    float a0 = 0.f, a1 = 0.f, a2 = 0.f, a3 = 0.f;
    int e = start;
    for (; e + 3 < end; e += 4) {
        int s0 = csr[e], s1 = csr[e+1], s2 = csr[e+2], s3 = csr[e+3];
        uint2 v0 = *(const uint2*)&Xb[(size_t)s0*256 + 128 + lane*4];
        uint2 v1 = *(const uint2*)&Xb[(size_t)s1*256 + 128 + lane*4];
        uint2 v2 = *(const uint2*)&Xb[(size_t)s2*256 + 128 + lane*4];
        uint2 v3 = *(const uint2*)&Xb[(size_t)s3*256 + 128 + lane*4];
        a0 += (bflo(v0.x) + bflo(v1.x)) + (bflo(v2.x) + bflo(v3.x));
        a1 += (bfhi(v0.x) + bfhi(v1.x)) + (bfhi(v2.x) + bfhi(v3.x));
        a2 += (bflo(v0.y) + bflo(v1.y)) + (bflo(v2.y) + bflo(v3.y));
        a3 += (bfhi(v0.y) + bfhi(v1.y)) + (bfhi(v2.y) + bfhi(v3.y));
    }
    for (; e < end; e++) {
        uint2 v = *(const uint2*)&Xb[(size_t)csr[e]*256 + 128 + lane*4];
        a0 += bflo(v.x); a1 += bfhi(v.x); a2 += bflo(v.y); a3 += bfhi(v.y);
    }
    float inv = 1.0f / (float)max(dg, 1);
    uint2 o;
    o.x = ((unsigned)bfu(a1*inv) << 16) | (unsigned)bfu(a0*inv);
    o.y = ((unsigned)bfu(a3*inv) << 16) | (unsigned)bfu(a2*inv);
    *(uint2*)&Xb[(size_t)n*256 + lane*4] = o;
}

// ---------------- conv2 MFMA: 8 waves, per-wave C staging, coalesced WB ----
// LDS: Ws 64KB + Cs 34KB + bl2 0.5KB = ~98.5KB -> 1 block/CU, 8 waves/CU.
// No barriers in the tile loop (Ws read-only, Cs slices wave-private).
#define CSTR 136   // shorts per staged row (128 + 8 pad; 272B = 17x16B)
__global__ __launch_bounds__(512, 2) void conv2_mfma_k(__hip_bfloat16* __restrict__ Xb,
        const __hip_bfloat16* __restrict__ Wpk2, const float* __restrict__ bl2) {
    __shared__ short Ws[32768];          // [ks8][nt8][lane64][j8]
    __shared__ short Cs[8 * 16 * CSTR];  // per-wave 16x136 slices
    __shared__ float bs2[H];
    int tid = threadIdx.x;
    {
        const float4* s = (const float4*)Wpk2;
        float4* d = (float4*)Ws;
        #pragma unroll
        for (int i = 0; i < 8; i++) d[tid + i*512] = s[tid + i*512];
        if (tid < H) bs2[tid] = bl2[tid];
    }
    __syncthreads();
    int lane = tid & 63, wave = tid >> 6;
    int quad = lane >> 4, m = lane & 15, c0 = lane & 15;
    short* Tw = &Cs[wave * (16 * CSTR)];
    int lrow = lane >> 2;                 // writeback row within wave-slice
    int lseg = lane & 3;
    for (int tile = blockIdx.x; tile < NT2; tile += gridDim.x) {
        int row = tile*128 + wave*16 + m;
        int rowL = row < N_NODES ? row : N_NODES - 1;
        const short* Arow = (const short*)Xb + (size_t)rowL * 256;
        floatx4 acc[8];
        #pragma unroll
        for (int i = 0; i < 8; i++)
            #pragma unroll
            for (int r = 0; r < 4; r++) acc[i][r] = 0.f;
        #pragma unroll
        for (int ks = 0; ks < 8; ks++) {
            short8 a = *(const short8*)(Arow + ks*32 + quad*8);
            #pragma unroll
            for (int nt = 0; nt < 8; nt++) {
                short8 b = *(const short8*)&Ws[((ks*8 + nt)*64 + lane)*8];
                acc[nt] = __builtin_amdgcn_mfma_f32_16x16x32_bf16(a, b, acc[nt], 0, 0, 0);
            }
        }
        // stage tanh(acc+b) into wave-private LDS slice
        #pragma unroll
        for (int nt = 0; nt < 8; nt++) {
            int col = nt*16 + c0;
            float bb = bs2[col];
            #pragma unroll
            for (int r = 0; r < 4; r++)
                Tw[(quad*4 + r)*CSTR + col] = (short)bfu(tanhf(acc[nt][r] + bb));
        }
        // coalesced writeback: 4 lanes x 16B = full 64B lines
        int rowg = tile*128 + wave*16 + lrow;
        if (rowg < N_NODES) {
            short* dst = (short*)Xb + (size_t)rowg * 256;
            const short* srcr = &Tw[lrow * CSTR];
            #pragma unroll
            for (int s = 0; s < 4; s++) {
                int cseg = lseg + 4*s;
                *(short8*)&dst[cseg*8] = *(const short8*)&srcr[cseg*8];
            }
        }
    }
}

// ---------------- fused MLP MFMA: W2 in regs, chunked wave-private T ------
// LDS: Ws 64KB + Ts 9KB + b1 1KB = ~74KB -> 2 blocks/CU, 8 waves/CU.
// No barriers in the tile loop.
#define TSTR 72    // shorts per T row (64 + 8 pad; 144B = 9x16B)
__global__ __launch_bounds__(256, 2) void mlp_mfma_k(const __hip_bfloat16* __restrict__ Xb,
        const __hip_bfloat16* __restrict__ Wpk1, const float* __restrict__ b1,
        const __hip_bfloat16* __restrict__ W2pk, const float* __restrict__ b2,
        float* __restrict__ out) {
    __shared__ short Ws[32768];          // W1 frags (persistent)
    __shared__ short Ts[4 * 16 * TSTR];  // per-wave 16x72 T chunk
    __shared__ float b1s[LH];
    int tid = threadIdx.x;
    int lane = tid & 63, wave = tid >> 6;
    int quad = lane >> 4, m = lane & 15, c0 = lane & 15;
    {
        const float4* s = (const float4*)Wpk1;
        float4* d = (float4*)Ws;
        #pragma unroll
        for (int i = 0; i < 16; i++) d[tid + i*256] = s[tid + i*256];
        b1s[tid] = b1[tid];
    }
    // W2 fragments -> registers (persistent)
    short8 w2f[8];
    #pragma unroll
    for (int ks = 0; ks < 8; ks++)
        w2f[ks] = *(const short8*)&W2pk[(ks*64 + lane)*8];
    float b2v = (c0 < CDIM) ? b2[c0] : 0.f;
    __syncthreads();
    short* Tw = &Ts[wave * (16 * TSTR)];
    for (int tile = blockIdx.x; tile < NTILES; tile += gridDim.x) {
        int row = tile*64 + wave*16 + m;
        int rowL = row < N_NODES ? row : N_NODES - 1;
        const short* Arow = (const short*)Xb + (size_t)rowL * 256;   // h2 cols 0..127
        floatx4 acc[16];
        #pragma unroll
        for (int i = 0; i < 16; i++)
            #pragma unroll
            for (int r = 0; r < 4; r++) acc[i][r] = 0.f;
        #pragma unroll
        for (int ks = 0; ks < 4; ks++) {
            short8 a = *(const short8*)(Arow + ks*32 + quad*8);
            #pragma unroll
            for (int nt = 0; nt < 16; nt++) {
                short8 b = *(const short8*)&Ws[((ks*16 + nt)*64 + lane)*8];
                acc[nt] = __builtin_amdgcn_mfma_f32_16x16x32_bf16(a, b, acc[nt], 0, 0, 0);
            }
        }
        // GEMM2 in 4 K-chunks through the wave-private T slice
        floatx4 lacc;
        #pragma unroll
        for (int r = 0; r < 4; r++) lacc[r] = 0.f;
        #pragma unroll
        for (int ch = 0; ch < 4; ch++) {
            #pragma unroll
            for (int ntl = 0; ntl < 4; ntl++) {
                int nt = ch*4 + ntl;
                int col = nt*16 + c0;
                float bb = b1s[col];
                #pragma unroll
                for (int r = 0; r < 4; r++)
                    Tw[(quad*4 + r)*TSTR + ntl*16 + c0] =
                        (short)bfu(tanhf(acc[nt][r] + bb));
            }
            #pragma unroll
            for (int k2 = 0; k2 < 2; k2++) {
                short8 a = *(const short8*)&Tw[m*TSTR + k2*32 + quad*8];
                lacc = __builtin_amdgcn_mfma_f32_16x16x32_bf16(a, w2f[ch*2 + k2], lacc, 0, 0, 0);
            }
        }
        // softmax across the 8 class lanes (xor butterfly within c0 groups)
        int rbase = tile*64 + wave*16 + quad*4;
        #pragma unroll
        for (int r = 0; r < 4; r++) {
            float v = lacc[r] + b2v;
            float mval = (c0 < CDIM) ? v : -INFINITY;
            #pragma unroll
            for (int off = 1; off < 8; off <<= 1)
                mval = fmaxf(mval, __shfl_xor(mval, off));
            float e = (c0 < CDIM) ? expf(v - mval) : 0.f;
            float ssum = e;
            #pragma unroll
            for (int off = 1; off < 8; off <<= 1)
                ssum += __shfl_xor(ssum, off);
            int rowg = rbase + r;
            if (c0 < CDIM && rowg < N_NODES)
                out[(size_t)rowg*CDIM + c0] = e / ssum;
        }
    }
}

extern "C" void kernel_launch(void* const* d_in, const int* in_sizes, int n_in,
                              void* d_out, int out_size, void* d_ws, size_t ws_size,
                              hipStream_t stream) {
    const float* x   = (const float*)d_in[0];
    const int*   ei  = (const int*)d_in[1];
    const float* Wl1 = (const float*)d_in[2];
    const float* bl1 = (const float*)d_in[3];
    const float* Wr1 = (const float*)d_in[4];
    const float* Wl2 = (const float*)d_in[5];
    const float* bl2 = (const float*)d_in[6];
    const float* Wr2 = (const float*)d_in[7];
    const float* W1  = (const float*)d_in[8];
    const float* b1  = (const float*)d_in[9];
    const float* W2  = (const float*)d_in[10];
    const float* b2  = (const float*)d_in[11];

    float* ws     = (float*)d_ws;
    float* part   = ws + OFF_PART;
    int*   deg    = (int*)(ws + OFF_DEG);
    int*   rowptr = (int*)(ws + OFF_ROWPTR);
    int*   bsums  = (int*)(ws + OFF_BSUMS);
    float4* h0    = (float4*)(ws + OFF_H0);
    int*   csr    = (int*)(ws + OFF_CSR);
    __hip_bfloat16* Wpk2 = (__hip_bfloat16*)(ws + OFF_WPK2);
    __hip_bfloat16* Wpk1 = (__hip_bfloat16*)(ws + OFF_WPK1);
    __hip_bfloat16* W2pk = (__hip_bfloat16*)(ws + OFF_W2PK);
    __hip_bfloat16* Xb   = (__hip_bfloat16*)(ws + OFF_XB);

    const int nb_scan = (N_NODES + 1023) / 1024;   // 98

    stats_partial_k<<<NB_STATS, 256, 0, stream>>>(x, part, deg);
    normalize_k<<<(N_NODES + 255) / 256, 256, 0, stream>>>(x, part, h0,
            Wl2, Wr2, W1, W2, Wpk2, Wpk1, W2pk);
    deg_count_k<<<(N_EDGES + 255) / 256, 256, 0, stream>>>(ei, deg);
    scan1_k<<<nb_scan, 256, 0, stream>>>(deg, rowptr, bsums);
    scan3_k<<<nb_scan, 256, 0, stream>>>(rowptr, bsums, nb_scan);
    scatter_k<<<(N_EDGES + 255) / 256, 256, 0, stream>>>(ei, rowptr, csr);

    agg1conv1_k<<<(N_NODES + 255) / 256, 256, 0, stream>>>(h0, rowptr, deg, csr,
            Wl1, bl1, Wr1, Xb);
    agg2_k<<<N_NODES / 8, 256, 0, stream>>>(Xb, rowptr, deg, csr);
    conv2_mfma_k<<<256, 512, 0, stream>>>(Xb, Wpk2, bl2);
    mlp_mfma_k<<<512, 256, 0, stream>>>(Xb, Wpk1, b1, W2pk, b2, (float*)d_out);
}

// Round 8
// 301.473 us; speedup vs baseline: 5.4667x; 1.0489x over previous
//
#include <hip/hip_runtime.h>
#include <hip/hip_bf16.h>
#include <math.h>

#define N_NODES 100000
#define N_EDGES 600000
#define H 128
#define LH 256
#define CDIM 8
#define NB_STATS 64
#define NTILES ((N_NODES + 63) / 64)     // 1563 (64-row tiles)

typedef __attribute__((ext_vector_type(8))) short short8;
typedef __attribute__((ext_vector_type(4))) float floatx4;

// ------------- workspace layout (4-byte words) -------------
#define OFF_PART   0
#define OFF_PARAMS 704
#define OFF_DEG    712
#define OFF_ROWPTR (OFF_DEG + N_NODES)
#define OFF_BSUMS  (OFF_ROWPTR + N_NODES)
#define OFF_H0     (OFF_BSUMS + 128)            // N*4 fp32 (float4 rows)
#define OFF_AGG1   (OFF_H0 + N_NODES*4)         // (unused, kept for layout)
#define OFF_CSR    (OFF_AGG1 + N_NODES*4)
#define OFF_WPK2   (OFF_CSR + N_EDGES)          // 32768 bf16 = 16384 words
#define OFF_WPK1   (OFF_WPK2 + 16384)           // 32768 bf16
#define OFF_W2PK   (OFF_WPK1 + 16384)           // 4096 bf16 = 2048 words
#define OFF_XB     (OFF_W2PK + 2048)            // N*256 bf16 = 12.8M words

__device__ __forceinline__ float rot_c() { return cosf(1.57079632679489661923f); }
__device__ __forceinline__ float rot_s() { return sinf(1.57079632679489661923f); }
__device__ __forceinline__ float bfhi(unsigned v) { return __uint_as_float(v & 0xffff0000u); }
__device__ __forceinline__ float bflo(unsigned v) { return __uint_as_float(v << 16); }
__device__ __forceinline__ unsigned short bfu(float f) {
    __hip_bfloat16 h = __float2bfloat16(f);
    return *(unsigned short*)&h;
}

// ---------------- stats partial (also zeroes deg) ----------------
__global__ void stats_partial_k(const float* __restrict__ x, float* __restrict__ part,
                                int* __restrict__ deg) {
    const float c = rot_c(), sn = rot_s();
    float mn0 = INFINITY, mx0 = -INFINITY, mn1 = INFINITY, mx1 = -INFINITY;
    float s0 = 0.f, s1 = 0.f, sr0 = 0.f, sr1 = 0.f;
    float mxr0 = -INFINITY, mxr1 = -INFINITY, mxa = -INFINITY;
    for (int i = blockIdx.x * blockDim.x + threadIdx.x; i < N_NODES;
         i += gridDim.x * blockDim.x) {
        deg[i] = 0;
        float x0 = x[3*i], x1 = x[3*i+1], a = x[3*i+2];
        float r0 = c*x0 - sn*x1;
        float r1 = sn*x0 + c*x1;
        mn0 = fminf(mn0, x0); mx0 = fmaxf(mx0, x0);
        mn1 = fminf(mn1, x1); mx1 = fmaxf(mx1, x1);
        s0 += x0; s1 += x1; sr0 += r0; sr1 += r1;
        mxr0 = fmaxf(mxr0, r0); mxr1 = fmaxf(mxr1, r1);
        mxa = fmaxf(mxa, a);
    }
    __shared__ float red[256];
    float vals[11] = {mn0, mx0, mn1, mx1, s0, s1, sr0, sr1, mxr0, mxr1, mxa};
    const int ops[11] = {0,1,0,1,2,2,2,2,1,1,1};
    for (int v = 0; v < 11; v++) {
        red[threadIdx.x] = vals[v];
        __syncthreads();
        for (int s = 128; s > 0; s >>= 1) {
            if ((int)threadIdx.x < s) {
                float a = red[threadIdx.x], b = red[threadIdx.x + s];
                red[threadIdx.x] = (ops[v]==0) ? fminf(a,b) : (ops[v]==1) ? fmaxf(a,b) : (a+b);
            }
            __syncthreads();
        }
        if (threadIdx.x == 0) part[blockIdx.x * 11 + v] = red[0];
        __syncthreads();
    }
}

// ---------------- normalize (+ final stats reduce + weight pre-pack) ------
__global__ __launch_bounds__(256) void normalize_k(const float* __restrict__ x,
        const float* __restrict__ part, float4* __restrict__ h0,
        const float* __restrict__ Wl2, const float* __restrict__ Wr2,
        const float* __restrict__ W1, const float* __restrict__ W2,
        __hip_bfloat16* __restrict__ Wpk2, __hip_bfloat16* __restrict__ Wpk1,
        __hip_bfloat16* __restrict__ W2pk) {
    __shared__ float res[11];
    int tid = threadIdx.x;
    if (tid < 64) {
        const int ops[11] = {0,1,0,1,2,2,2,2,1,1,1};
        for (int v = 0; v < 11; v++) {
            float val = part[tid * 11 + v];
            #pragma unroll
            for (int off = 32; off > 0; off >>= 1) {
                float o = __shfl_down(val, off);
                val = (ops[v]==0) ? fminf(val,o) : (ops[v]==1) ? fmaxf(val,o) : (val+o);
            }
            if (tid == 0) res[v] = val;
        }
    }
    __syncthreads();
    int rotate = (res[3] - res[2]) > (res[1] - res[0]);
    float mean0 = (rotate ? res[6] : res[4]) / (float)N_NODES;
    float mean1 = (rotate ? res[7] : res[5]) / (float)N_NODES;
    float imx0  = 1.0f / (rotate ? res[8] : res[1]);
    float imx1  = 1.0f / (rotate ? res[9] : res[3]);
    float imxa  = 1.0f / res[10];

    int i = blockIdx.x * blockDim.x + tid;
    if (i < N_NODES) {
        const float c = rot_c(), sn = rot_s();
        float x0 = x[3*i], x1 = x[3*i+1], a = x[3*i+2];
        float u0 = rotate ? (c*x0 - sn*x1) : x0;
        float u1 = rotate ? (sn*x0 + c*x1) : x1;
        h0[i] = make_float4((u0 - mean0) * imx0, (u1 - mean1) * imx1, a * imxa, 0.f);
    }
    int idx = i;
    if (idx < 32768) {                       // Wpk2[ks8][nt8][lane64][j8], K=256,N=128
        int j = idx & 7, lane = (idx >> 3) & 63, nt = (idx >> 9) & 7, ks = idx >> 12;
        int k = ks*32 + (lane >> 4)*8 + j;
        int n = nt*16 + (lane & 15);
        float v = (k < 128) ? Wl2[n*H + k] : Wr2[n*H + (k - 128)];
        Wpk2[idx] = __float2bfloat16(v);
    } else if (idx < 65536) {                // Wpk1[ks4][nt16][lane64][j8], K=128,N=256
        int i2 = idx - 32768;
        int j = i2 & 7, lane = (i2 >> 3) & 63, nt = (i2 >> 9) & 15, ks = i2 >> 13;
        int k = ks*32 + (lane >> 4)*8 + j;
        int n = nt*16 + (lane & 15);
        Wpk1[i2] = __float2bfloat16(W1[n*H + k]);
    } else if (idx < 69632) {                // W2pk[ks8][lane64][j8], K=256,N=16(8 real)
        int i3 = idx - 65536;
        int j = i3 & 7, lane = (i3 >> 3) & 63, ks = i3 >> 9;
        int k = ks*32 + (lane >> 4)*8 + j;
        int n = lane & 15;
        W2pk[i3] = __float2bfloat16((n < CDIM) ? W2[n*LH + k] : 0.f);
    }
}

// ---------------- CSR build ----------------
__global__ void deg_count_k(const int* __restrict__ ei, int* __restrict__ deg) {
    int e = blockIdx.x * blockDim.x + threadIdx.x;
    if (e >= N_EDGES) return;
    atomicAdd(&deg[ei[N_EDGES + e]], 1);
}

__global__ void scan1_k(const int* __restrict__ deg, int* __restrict__ rowptr,
                        int* __restrict__ bsums) {
    __shared__ int s[256];
    int t = threadIdx.x;
    int base = blockIdx.x * 1024 + t * 4;
    int d0 = (base+0 < N_NODES) ? deg[base+0] : 0;
    int d1 = (base+1 < N_NODES) ? deg[base+1] : 0;
    int d2 = (base+2 < N_NODES) ? deg[base+2] : 0;
    int d3 = (base+3 < N_NODES) ? deg[base+3] : 0;
    int tsum = d0 + d1 + d2 + d3;
    s[t] = tsum;
    __syncthreads();
    for (int off = 1; off < 256; off <<= 1) {
        int v = (t >= off) ? s[t - off] : 0;
        __syncthreads();
        s[t] += v;
        __syncthreads();
    }
    int excl = s[t] - tsum;
    if (base+0 < N_NODES) rowptr[base+0] = excl;
    if (base+1 < N_NODES) rowptr[base+1] = excl + d0;
    if (base+2 < N_NODES) rowptr[base+2] = excl + d0 + d1;
    if (base+3 < N_NODES) rowptr[base+3] = excl + d0 + d1 + d2;
    if (t == 255) bsums[blockIdx.x] = s[255];
}

// scan3 with folded scan2: add = sum of bsums[0..blockIdx-1]
__global__ void scan3_k(int* __restrict__ rowptr, const int* __restrict__ bsums, int nb) {
    __shared__ int sb[256];
    int t = threadIdx.x;
    sb[t] = (t < (int)blockIdx.x && t < nb) ? bsums[t] : 0;
    __syncthreads();
    for (int s = 128; s > 0; s >>= 1) {
        if (t < s) sb[t] += sb[t + s];
        __syncthreads();
    }
    int add = sb[0];
    int base = blockIdx.x * 1024 + t * 4;
    if (base+0 < N_NODES) rowptr[base+0] += add;
    if (base+1 < N_NODES) rowptr[base+1] += add;
    if (base+2 < N_NODES) rowptr[base+2] += add;
    if (base+3 < N_NODES) rowptr[base+3] += add;
}

__global__ void scatter_k(const int* __restrict__ ei, int* __restrict__ rowptr,
                          int* __restrict__ csr) {
    int e = blockIdx.x * blockDim.x + threadIdx.x;
    if (e >= N_EDGES) return;
    int d = ei[N_EDGES + e];
    int pos = atomicAdd(&rowptr[d], 1);
    csr[pos] = ei[e];
}

// ---------------- fused agg1 + conv1 dense ----------------
__global__ __launch_bounds__(256) void agg1conv1_k(const float4* __restrict__ h0,
        const int* __restrict__ rowptr, const int* __restrict__ deg,
        const int* __restrict__ csr,
        const float* __restrict__ Wl1, const float* __restrict__ bl1,
        const float* __restrict__ Wr1, __hip_bfloat16* __restrict__ Xb) {
    __shared__ float wl[H*3], wr[H*3], bb[H];
    __shared__ float4 sa[256];
    int tid = threadIdx.x;
    for (int i = tid; i < H*3; i += 256) { wl[i] = Wl1[i]; wr[i] = Wr1[i]; }
    if (tid < H) bb[tid] = bl1[tid];
    int base = blockIdx.x * 256;
    int n = base + tid;
    float4 av = make_float4(0.f, 0.f, 0.f, 0.f);
    if (n < N_NODES) {
        int dg = deg[n];
        int end = rowptr[n], start = end - dg;
        float a0 = 0.f, a1 = 0.f, a2 = 0.f;
        int e = start;
        for (; e + 3 < end; e += 4) {
            int s0 = csr[e], s1 = csr[e+1], s2 = csr[e+2], s3 = csr[e+3];
            float4 v0 = h0[s0];
            float4 v1 = h0[s1];
            float4 v2 = h0[s2];
            float4 v3 = h0[s3];
            a0 += (v0.x + v1.x) + (v2.x + v3.x);
            a1 += (v0.y + v1.y) + (v2.y + v3.y);
            a2 += (v0.z + v1.z) + (v2.z + v3.z);
        }
        for (; e < end; e++) {
            float4 v = h0[csr[e]];
            a0 += v.x; a1 += v.y; a2 += v.z;
        }
        float inv = 1.0f / (float)max(dg, 1);
        av = make_float4(a0 * inv, a1 * inv, a2 * inv, 0.f);
    }
    sa[tid] = av;
    __syncthreads();
    int sub = tid >> 6;
    int j2 = (tid & 63) * 2;
    for (int i = 0; i < 64; i++) {
        int loc = i * 4 + sub;
        int nn = base + loc;
        if (nn >= N_NODES) break;
        float4 a = sa[loc];
        float4 xv = h0[nn];
        float o0 = wl[3*j2+0]*a.x + wl[3*j2+1]*a.y + wl[3*j2+2]*a.z + bb[j2]
                 + wr[3*j2+0]*xv.x + wr[3*j2+1]*xv.y + wr[3*j2+2]*xv.z;
        float o1 = wl[3*j2+3]*a.x + wl[3*j2+4]*a.y + wl[3*j2+5]*a.z + bb[j2+1]
                 + wr[3*j2+3]*xv.x + wr[3*j2+4]*xv.y + wr[3*j2+5]*xv.z;
        unsigned pv = ((unsigned)bfu(tanhf(o1)) << 16) | (unsigned)bfu(tanhf(o0));
        *(unsigned*)&Xb[(size_t)nn*256 + 128 + j2] = pv;
    }
}

// ---------------- agg2: mean of h1 (bf16) -> Xb[n][0..127]
// half-wave (32 lanes) per node, 4 cols/lane: 32*4 = exactly 128 cols.
__global__ void agg2_k(__hip_bfloat16* __restrict__ Xb, const int* __restrict__ rowptr,
                       const int* __restrict__ deg, const int* __restrict__ csr) {
    int lane = threadIdx.x & 31;
    int n = blockIdx.x * 8 + (threadIdx.x >> 5);
    int dg = deg[n];
    int end = rowptr[n], start = end - dg;
    float a0 = 0.f, a1 = 0.f, a2 = 0.f, a3 = 0.f;
    int e = start;
    for (; e + 3 < end; e += 4) {
        int s0 = csr[e], s1 = csr[e+1], s2 = csr[e+2], s3 = csr[e+3];
        uint2 v0 = *(const uint2*)&Xb[(size_t)s0*256 + 128 + lane*4];
        uint2 v1 = *(const uint2*)&Xb[(size_t)s1*256 + 128 + lane*4];
        uint2 v2 = *(const uint2*)&Xb[(size_t)s2*256 + 128 + lane*4];
        uint2 v3 = *(const uint2*)&Xb[(size_t)s3*256 + 128 + lane*4];
        a0 += (bflo(v0.x) + bflo(v1.x)) + (bflo(v2.x) + bflo(v3.x));
        a1 += (bfhi(v0.x) + bfhi(v1.x)) + (bfhi(v2.x) + bfhi(v3.x));
        a2 += (bflo(v0.y) + bflo(v1.y)) + (bflo(v2.y) + bflo(v3.y));
        a3 += (bfhi(v0.y) + bfhi(v1.y)) + (bfhi(v2.y) + bfhi(v3.y));
    }
    for (; e < end; e++) {
        uint2 v = *(const uint2*)&Xb[(size_t)csr[e]*256 + 128 + lane*4];
        a0 += bflo(v.x); a1 += bfhi(v.x); a2 += bflo(v.y); a3 += bfhi(v.y);
    }
    float inv = 1.0f / (float)max(dg, 1);
    uint2 o;
    o.x = ((unsigned)bfu(a1*inv) << 16) | (unsigned)bfu(a0*inv);
    o.y = ((unsigned)bfu(a3*inv) << 16) | (unsigned)bfu(a2*inv);
    *(uint2*)&Xb[(size_t)n*256 + lane*4] = o;
}

// ---------------- FUSED conv2 + MLP + softmax ----------------
// Per 64-row tile, per wave (16 rows):
//   conv2: [agg2|h1] @ W' -> h2 (C-layout) -> tanh -> wave-private LDS slice
//   GEMM1: re-read slice as A-frags, x W1^T -> t (C-layout)
//   GEMM2: chunked tanh(t) through same slice vs W2-frags in regs -> logits
//   softmax via 8-lane shuffle. h2 NEVER touches HBM.
// LDS: Ws2 64K + Ws1 64K + Cs 17K = 145 KB -> 1 block/CU, 4 waves.
// Next-tile A prefetched into registers to cover HBM latency (1 wave/SIMD).
#define CSTR 136   // shorts per staged row (128 + 8 pad)
__global__ __launch_bounds__(256, 1) void conv2mlp_k(const __hip_bfloat16* __restrict__ Xb,
        const __hip_bfloat16* __restrict__ Wpk2, const float* __restrict__ bl2,
        const __hip_bfloat16* __restrict__ Wpk1, const float* __restrict__ b1,
        const __hip_bfloat16* __restrict__ W2pk, const float* __restrict__ b2,
        float* __restrict__ out) {
    __shared__ short Ws2[32768];         // conv2 weights [ks8][nt8][lane64][j8]
    __shared__ short Ws1[32768];         // W1 weights [ks4][nt16][lane64][j8]
    __shared__ short Cs[4 * 16 * CSTR];  // per-wave 16x136 staging
    int tid = threadIdx.x;
    int lane = tid & 63, wave = tid >> 6;
    int quad = lane >> 4, m = lane & 15, c0 = lane & 15;
    {
        const float4* s2 = (const float4*)Wpk2;
        const float4* s1 = (const float4*)Wpk1;
        float4* d2 = (float4*)Ws2;
        float4* d1 = (float4*)Ws1;
        #pragma unroll
        for (int i = 0; i < 16; i++) {
            d2[tid + i*256] = s2[tid + i*256];
            d1[tid + i*256] = s1[tid + i*256];
        }
    }
    // W2 fragments + biases -> registers (persistent)
    short8 w2f[8];
    #pragma unroll
    for (int ks = 0; ks < 8; ks++)
        w2f[ks] = *(const short8*)&W2pk[(ks*64 + lane)*8];
    float bl2r[8], b1r[16];
    #pragma unroll
    for (int nt = 0; nt < 8; nt++) bl2r[nt] = bl2[nt*16 + c0];
    #pragma unroll
    for (int nt = 0; nt < 16; nt++) b1r[nt] = b1[nt*16 + c0];
    float b2v = (c0 < CDIM) ? b2[c0] : 0.f;
    __syncthreads();
    short* Tw = &Cs[wave * (16 * CSTR)];

    int tile = blockIdx.x;
    short8 areg[8];
    {
        int row = tile*64 + wave*16 + m;
        int rowL = row < N_NODES ? row : N_NODES - 1;
        const short* Arow = (const short*)Xb + (size_t)rowL * 256;
        #pragma unroll
        for (int ks = 0; ks < 8; ks++)
            areg[ks] = *(const short8*)(Arow + ks*32 + quad*8);
    }
    for (; tile < NTILES; tile += gridDim.x) {
        // prefetch next tile's A fragments
        short8 anext[8];
        {
            int tnext = tile + gridDim.x;
            int rown = (tnext < NTILES) ? (tnext*64 + wave*16 + m) : 0;
            int rowNL = rown < N_NODES ? rown : N_NODES - 1;
            const short* ArowN = (const short*)Xb + (size_t)rowNL * 256;
            #pragma unroll
            for (int ks = 0; ks < 8; ks++)
                anext[ks] = *(const short8*)(ArowN + ks*32 + quad*8);
        }
        // ---- conv2: h2 = tanh([agg2|h1] @ W' + bl2)
        floatx4 acc2[8];
        #pragma unroll
        for (int i = 0; i < 8; i++)
            #pragma unroll
            for (int r = 0; r < 4; r++) acc2[i][r] = 0.f;
        #pragma unroll
        for (int ks = 0; ks < 8; ks++) {
            #pragma unroll
            for (int nt = 0; nt < 8; nt++) {
                short8 b = *(const short8*)&Ws2[((ks*8 + nt)*64 + lane)*8];
                acc2[nt] = __builtin_amdgcn_mfma_f32_16x16x32_bf16(areg[ks], b, acc2[nt], 0, 0, 0);
            }
        }
        #pragma unroll
        for (int nt = 0; nt < 8; nt++) {
            #pragma unroll
            for (int r = 0; r < 4; r++)
                Tw[(quad*4 + r)*CSTR + nt*16 + c0] = (short)bfu(tanhf(acc2[nt][r] + bl2r[nt]));
        }
        // ---- GEMM1: t_pre = h2 @ W1^T  (A from the slice just written)
        floatx4 acc1[16];
        #pragma unroll
        for (int i = 0; i < 16; i++)
            #pragma unroll
            for (int r = 0; r < 4; r++) acc1[i][r] = 0.f;
        #pragma unroll
        for (int ks = 0; ks < 4; ks++) {
            short8 a = *(const short8*)&Tw[m*CSTR + ks*32 + quad*8];
            #pragma unroll
            for (int nt = 0; nt < 16; nt++) {
                short8 b = *(const short8*)&Ws1[((ks*16 + nt)*64 + lane)*8];
                acc1[nt] = __builtin_amdgcn_mfma_f32_16x16x32_bf16(a, b, acc1[nt], 0, 0, 0);
            }
        }
        // ---- GEMM2 in 4 K-chunks through the (now dead) slice
        floatx4 lacc;
        #pragma unroll
        for (int r = 0; r < 4; r++) lacc[r] = 0.f;
        #pragma unroll
        for (int ch = 0; ch < 4; ch++) {
            #pragma unroll
            for (int ntl = 0; ntl < 4; ntl++) {
                int nt = ch*4 + ntl;
                #pragma unroll
                for (int r = 0; r < 4; r++)
                    Tw[(quad*4 + r)*CSTR + ntl*16 + c0] =
                        (short)bfu(tanhf(acc1[nt][r] + b1r[nt]));
            }
            #pragma unroll
            for (int k2 = 0; k2 < 2; k2++) {
                short8 a = *(const short8*)&Tw[m*CSTR + k2*32 + quad*8];
                lacc = __builtin_amdgcn_mfma_f32_16x16x32_bf16(a, w2f[ch*2 + k2], lacc, 0, 0, 0);
            }
        }
        // ---- softmax across the 8 class lanes
        int rbase = tile*64 + wave*16 + quad*4;
        #pragma unroll
        for (int r = 0; r < 4; r++) {
            float v = lacc[r] + b2v;
            float mval = (c0 < CDIM) ? v : -INFINITY;
            #pragma unroll
            for (int off = 1; off < 8; off <<= 1)
                mval = fmaxf(mval, __shfl_xor(mval, off));
            float e = (c0 < CDIM) ? expf(v - mval) : 0.f;
            float ssum = e;
            #pragma unroll
            for (int off = 1; off < 8; off <<= 1)
                ssum += __shfl_xor(ssum, off);
            int rowg = rbase + r;
            if (c0 < CDIM && rowg < N_NODES)
                out[(size_t)rowg*CDIM + c0] = e / ssum;
        }
        #pragma unroll
        for (int ks = 0; ks < 8; ks++) areg[ks] = anext[ks];
    }
}

extern "C" void kernel_launch(void* const* d_in, const int* in_sizes, int n_in,
                              void* d_out, int out_size, void* d_ws, size_t ws_size,
                              hipStream_t stream) {
    const float* x   = (const float*)d_in[0];
    const int*   ei  = (const int*)d_in[1];
    const float* Wl1 = (const float*)d_in[2];
    const float* bl1 = (const float*)d_in[3];
    const float* Wr1 = (const float*)d_in[4];
    const float* Wl2 = (const float*)d_in[5];
    const float* bl2 = (const float*)d_in[6];
    const float* Wr2 = (const float*)d_in[7];
    const float* W1  = (const float*)d_in[8];
    const float* b1  = (const float*)d_in[9];
    const float* W2  = (const float*)d_in[10];
    const float* b2  = (const float*)d_in[11];

    float* ws     = (float*)d_ws;
    float* part   = ws + OFF_PART;
    int*   deg    = (int*)(ws + OFF_DEG);
    int*   rowptr = (int*)(ws + OFF_ROWPTR);
    int*   bsums  = (int*)(ws + OFF_BSUMS);
    float4* h0    = (float4*)(ws + OFF_H0);
    int*   csr    = (int*)(ws + OFF_CSR);
    __hip_bfloat16* Wpk2 = (__hip_bfloat16*)(ws + OFF_WPK2);
    __hip_bfloat16* Wpk1 = (__hip_bfloat16*)(ws + OFF_WPK1);
    __hip_bfloat16* W2pk = (__hip_bfloat16*)(ws + OFF_W2PK);
    __hip_bfloat16* Xb   = (__hip_bfloat16*)(ws + OFF_XB);

    const int nb_scan = (N_NODES + 1023) / 1024;   // 98

    stats_partial_k<<<NB_STATS, 256, 0, stream>>>(x, part, deg);
    normalize_k<<<(N_NODES + 255) / 256, 256, 0, stream>>>(x, part, h0,
            Wl2, Wr2, W1, W2, Wpk2, Wpk1, W2pk);
    deg_count_k<<<(N_EDGES + 255) / 256, 256, 0, stream>>>(ei, deg);
    scan1_k<<<nb_scan, 256, 0, stream>>>(deg, rowptr, bsums);
    scan3_k<<<nb_scan, 256, 0, stream>>>(rowptr, bsums, nb_scan);
    scatter_k<<<(N_EDGES + 255) / 256, 256, 0, stream>>>(ei, rowptr, csr);

    agg1conv1_k<<<(N_NODES + 255) / 256, 256, 0, stream>>>(h0, rowptr, deg, csr,
            Wl1, bl1, Wr1, Xb);
    agg2_k<<<N_NODES / 8, 256, 0, stream>>>(Xb, rowptr, deg, csr);
    conv2mlp_k<<<256, 256, 0, stream>>>(Xb, Wpk2, bl2, Wpk1, b1, W2pk, b2,
            (float*)d_out);
}

// Round 10
// 277.864 us; speedup vs baseline: 5.9312x; 1.0850x over previous
//
#include <hip/hip_runtime.h>
#include <hip/hip_bf16.h>
#include <math.h>

#define N_NODES 100000
#define N_EDGES 600000
#define H 128
#define LH 256
#define CDIM 8
#define NB_STATS 64
#define NT128 ((N_NODES + 127) / 128)   // 782 (128-row tiles, fused kernel)

typedef __attribute__((ext_vector_type(8))) short short8;
typedef __attribute__((ext_vector_type(4))) float floatx4;

// ------------- workspace layout (4-byte words) -------------
#define OFF_PART   0
#define OFF_PARAMS 704
#define OFF_DEG    712
#define OFF_ROWPTR (OFF_DEG + N_NODES)
#define OFF_BSUMS  (OFF_ROWPTR + N_NODES)
#define OFF_H0     (OFF_BSUMS + 128)            // N*4 fp32 (float4 rows)
#define OFF_AGG1   (OFF_H0 + N_NODES*4)         // (unused, kept for layout)
#define OFF_CSR    (OFF_AGG1 + N_NODES*4)
#define OFF_WPK2   (OFF_CSR + N_EDGES)          // 32768 bf16 = 16384 words
#define OFF_WPK1   (OFF_WPK2 + 16384)           // 32768 bf16
#define OFF_W2PK   (OFF_WPK1 + 16384)           // 4096 bf16 = 2048 words
#define OFF_XB     (OFF_W2PK + 2048)            // N*256 bf16 = 12.8M words

__device__ __forceinline__ float rot_c() { return cosf(1.57079632679489661923f); }
__device__ __forceinline__ float rot_s() { return sinf(1.57079632679489661923f); }
__device__ __forceinline__ float bfhi(unsigned v) { return __uint_as_float(v & 0xffff0000u); }
__device__ __forceinline__ float bflo(unsigned v) { return __uint_as_float(v << 16); }
__device__ __forceinline__ unsigned short bfu(float f) {
    __hip_bfloat16 h = __float2bfloat16(f);
    return *(unsigned short*)&h;
}

// ---------------- stats partial (also zeroes deg) ----------------
__global__ void stats_partial_k(const float* __restrict__ x, float* __restrict__ part,
                                int* __restrict__ deg) {
    const float c = rot_c(), sn = rot_s();
    float mn0 = INFINITY, mx0 = -INFINITY, mn1 = INFINITY, mx1 = -INFINITY;
    float s0 = 0.f, s1 = 0.f, sr0 = 0.f, sr1 = 0.f;
    float mxr0 = -INFINITY, mxr1 = -INFINITY, mxa = -INFINITY;
    for (int i = blockIdx.x * blockDim.x + threadIdx.x; i < N_NODES;
         i += gridDim.x * blockDim.x) {
        deg[i] = 0;
        float x0 = x[3*i], x1 = x[3*i+1], a = x[3*i+2];
        float r0 = c*x0 - sn*x1;
        float r1 = sn*x0 + c*x1;
        mn0 = fminf(mn0, x0); mx0 = fmaxf(mx0, x0);
        mn1 = fminf(mn1, x1); mx1 = fmaxf(mx1, x1);
        s0 += x0; s1 += x1; sr0 += r0; sr1 += r1;
        mxr0 = fmaxf(mxr0, r0); mxr1 = fmaxf(mxr1, r1);
        mxa = fmaxf(mxa, a);
    }
    __shared__ float red[256];
    float vals[11] = {mn0, mx0, mn1, mx1, s0, s1, sr0, sr1, mxr0, mxr1, mxa};
    const int ops[11] = {0,1,0,1,2,2,2,2,1,1,1};
    for (int v = 0; v < 11; v++) {
        red[threadIdx.x] = vals[v];
        __syncthreads();
        for (int s = 128; s > 0; s >>= 1) {
            if ((int)threadIdx.x < s) {
                float a = red[threadIdx.x], b = red[threadIdx.x + s];
                red[threadIdx.x] = (ops[v]==0) ? fminf(a,b) : (ops[v]==1) ? fmaxf(a,b) : (a+b);
            }
            __syncthreads();
        }
        if (threadIdx.x == 0) part[blockIdx.x * 11 + v] = red[0];
        __syncthreads();
    }
}

// ---------------- normalize (+ final stats reduce + weight pre-pack) ------
__global__ __launch_bounds__(256) void normalize_k(const float* __restrict__ x,
        const float* __restrict__ part, float4* __restrict__ h0,
        const float* __restrict__ Wl2, const float* __restrict__ Wr2,
        const float* __restrict__ W1, const float* __restrict__ W2,
        __hip_bfloat16* __restrict__ Wpk2, __hip_bfloat16* __restrict__ Wpk1,
        __hip_bfloat16* __restrict__ W2pk) {
    __shared__ float res[11];
    int tid = threadIdx.x;
    if (tid < 64) {
        const int ops[11] = {0,1,0,1,2,2,2,2,1,1,1};
        for (int v = 0; v < 11; v++) {
            float val = part[tid * 11 + v];
            #pragma unroll
            for (int off = 32; off > 0; off >>= 1) {
                float o = __shfl_down(val, off);
                val = (ops[v]==0) ? fminf(val,o) : (ops[v]==1) ? fmaxf(val,o) : (val+o);
            }
            if (tid == 0) res[v] = val;
        }
    }
    __syncthreads();
    int rotate = (res[3] - res[2]) > (res[1] - res[0]);
    float mean0 = (rotate ? res[6] : res[4]) / (float)N_NODES;
    float mean1 = (rotate ? res[7] : res[5]) / (float)N_NODES;
    float imx0  = 1.0f / (rotate ? res[8] : res[1]);
    float imx1  = 1.0f / (rotate ? res[9] : res[3]);
    float imxa  = 1.0f / res[10];

    int i = blockIdx.x * blockDim.x + tid;
    if (i < N_NODES) {
        const float c = rot_c(), sn = rot_s();
        float x0 = x[3*i], x1 = x[3*i+1], a = x[3*i+2];
        float u0 = rotate ? (c*x0 - sn*x1) : x0;
        float u1 = rotate ? (sn*x0 + c*x1) : x1;
        h0[i] = make_float4((u0 - mean0) * imx0, (u1 - mean1) * imx1, a * imxa, 0.f);
    }
    int idx = i;
    if (idx < 32768) {                       // Wpk2[ks8][nt8][lane64][j8], K=256,N=128
        int j = idx & 7, lane = (idx >> 3) & 63, nt = (idx >> 9) & 7, ks = idx >> 12;
        int k = ks*32 + (lane >> 4)*8 + j;
        int n = nt*16 + (lane & 15);
        float v = (k < 128) ? Wl2[n*H + k] : Wr2[n*H + (k - 128)];
        Wpk2[idx] = __float2bfloat16(v);
    } else if (idx < 65536) {                // Wpk1[ks4][nt16][lane64][j8], K=128,N=256
        int i2 = idx - 32768;
        int j = i2 & 7, lane = (i2 >> 3) & 63, nt = (i2 >> 9) & 15, ks = i2 >> 13;
        int k = ks*32 + (lane >> 4)*8 + j;
        int n = nt*16 + (lane & 15);
        Wpk1[i2] = __float2bfloat16(W1[n*H + k]);
    } else if (idx < 69632) {                // W2pk[ks8][lane64][j8], K=256,N=16(8 real)
        int i3 = idx - 65536;
        int j = i3 & 7, lane = (i3 >> 3) & 63, ks = i3 >> 9;
        int k = ks*32 + (lane >> 4)*8 + j;
        int n = lane & 15;
        W2pk[i3] = __float2bfloat16((n < CDIM) ? W2[n*LH + k] : 0.f);
    }
}

// ---------------- CSR build ----------------
__global__ void deg_count_k(const int* __restrict__ ei, int* __restrict__ deg) {
    int e = blockIdx.x * blockDim.x + threadIdx.x;
    if (e >= N_EDGES) return;
    atomicAdd(&deg[ei[N_EDGES + e]], 1);
}

__global__ void scan1_k(const int* __restrict__ deg, int* __restrict__ rowptr,
                        int* __restrict__ bsums) {
    __shared__ int s[256];
    int t = threadIdx.x;
    int base = blockIdx.x * 1024 + t * 4;
    int d0 = (base+0 < N_NODES) ? deg[base+0] : 0;
    int d1 = (base+1 < N_NODES) ? deg[base+1] : 0;
    int d2 = (base+2 < N_NODES) ? deg[base+2] : 0;
    int d3 = (base+3 < N_NODES) ? deg[base+3] : 0;
    int tsum = d0 + d1 + d2 + d3;
    s[t] = tsum;
    __syncthreads();
    for (int off = 1; off < 256; off <<= 1) {
        int v = (t >= off) ? s[t - off] : 0;
        __syncthreads();
        s[t] += v;
        __syncthreads();
    }
    int excl = s[t] - tsum;
    if (base+0 < N_NODES) rowptr[base+0] = excl;
    if (base+1 < N_NODES) rowptr[base+1] = excl + d0;
    if (base+2 < N_NODES) rowptr[base+2] = excl + d0 + d1;
    if (base+3 < N_NODES) rowptr[base+3] = excl + d0 + d1 + d2;
    if (t == 255) bsums[blockIdx.x] = s[255];
}

// scan3 with folded scan2: add = sum of bsums[0..blockIdx-1]
__global__ void scan3_k(int* __restrict__ rowptr, const int* __restrict__ bsums, int nb) {
    __shared__ int sb[256];
    int t = threadIdx.x;
    sb[t] = (t < (int)blockIdx.x && t < nb) ? bsums[t] : 0;
    __syncthreads();
    for (int s = 128; s > 0; s >>= 1) {
        if (t < s) sb[t] += sb[t + s];
        __syncthreads();
    }
    int add = sb[0];
    int base = blockIdx.x * 1024 + t * 4;
    if (base+0 < N_NODES) rowptr[base+0] += add;
    if (base+1 < N_NODES) rowptr[base+1] += add;
    if (base+2 < N_NODES) rowptr[base+2] += add;
    if (base+3 < N_NODES) rowptr[base+3] += add;
}

__global__ void scatter_k(const int* __restrict__ ei, int* __restrict__ rowptr,
                          int* __restrict__ csr) {
    int e = blockIdx.x * blockDim.x + threadIdx.x;
    if (e >= N_EDGES) return;
    int d = ei[N_EDGES + e];
    int pos = atomicAdd(&rowptr[d], 1);
    csr[pos] = ei[e];
}

// ---------------- fused agg1 + conv1 dense ----------------
__global__ __launch_bounds__(256) void agg1conv1_k(const float4* __restrict__ h0,
        const int* __restrict__ rowptr, const int* __restrict__ deg,
        const int* __restrict__ csr,
        const float* __restrict__ Wl1, const float* __restrict__ bl1,
        const float* __restrict__ Wr1, __hip_bfloat16* __restrict__ Xb) {
    __shared__ float wl[H*3], wr[H*3], bb[H];
    __shared__ float4 sa[256];
    int tid = threadIdx.x;
    for (int i = tid; i < H*3; i += 256) { wl[i] = Wl1[i]; wr[i] = Wr1[i]; }
    if (tid < H) bb[tid] = bl1[tid];
    int base = blockIdx.x * 256;
    int n = base + tid;
    float4 av = make_float4(0.f, 0.f, 0.f, 0.f);
    if (n < N_NODES) {
        int dg = deg[n];
        int end = rowptr[n], start = end - dg;
        float a0 = 0.f, a1 = 0.f, a2 = 0.f;
        int e = start;
        for (; e + 3 < end; e += 4) {
            int s0 = csr[e], s1 = csr[e+1], s2 = csr[e+2], s3 = csr[e+3];
            float4 v0 = h0[s0];
            float4 v1 = h0[s1];
            float4 v2 = h0[s2];
            float4 v3 = h0[s3];
            a0 += (v0.x + v1.x) + (v2.x + v3.x);
            a1 += (v0.y + v1.y) + (v2.y + v3.y);
            a2 += (v0.z + v1.z) + (v2.z + v3.z);
        }
        for (; e < end; e++) {
            float4 v = h0[csr[e]];
            a0 += v.x; a1 += v.y; a2 += v.z;
        }
        float inv = 1.0f / (float)max(dg, 1);
        av = make_float4(a0 * inv, a1 * inv, a2 * inv, 0.f);
    }
    sa[tid] = av;
    __syncthreads();
    int sub = tid >> 6;
    int j2 = (tid & 63) * 2;
    for (int i = 0; i < 64; i++) {
        int loc = i * 4 + sub;
        int nn = base + loc;
        if (nn >= N_NODES) break;
        float4 a = sa[loc];
        float4 xv = h0[nn];
        float o0 = wl[3*j2+0]*a.x + wl[3*j2+1]*a.y + wl[3*j2+2]*a.z + bb[j2]
                 + wr[3*j2+0]*xv.x + wr[3*j2+1]*xv.y + wr[3*j2+2]*xv.z;
        float o1 = wl[3*j2+3]*a.x + wl[3*j2+4]*a.y + wl[3*j2+5]*a.z + bb[j2+1]
                 + wr[3*j2+3]*xv.x + wr[3*j2+4]*xv.y + wr[3*j2+5]*xv.z;
        unsigned pv = ((unsigned)bfu(tanhf(o1)) << 16) | (unsigned)bfu(tanhf(o0));
        *(unsigned*)&Xb[(size_t)nn*256 + 128 + j2] = pv;
    }
}

// ---------------- agg2: mean of h1 (bf16) -> Xb[n][0..127]
// half-wave (32 lanes) per node, 4 cols/lane: 32*4 = exactly 128 cols.
__global__ void agg2_k(__hip_bfloat16* __restrict__ Xb, const int* __restrict__ rowptr,
                       const int* __restrict__ deg, const int* __restrict__ csr) {
    int lane = threadIdx.x & 31;
    int n = blockIdx.x * 8 + (threadIdx.x >> 5);
    int dg = deg[n];
    int end = rowptr[n], start = end - dg;
    float a0 = 0.f, a1 = 0.f, a2 = 0.f, a3 = 0.f;
    int e = start;
    for (; e + 3 < end; e += 4) {
        int s0 = csr[e], s1 = csr[e+1], s2 = csr[e+2], s3 = csr[e+3];
        uint2 v0 = *(const uint2*)&Xb[(size_t)s0*256 + 128 + lane*4];
        uint2 v1 = *(const uint2*)&Xb[(size_t)s1*256 + 128 + lane*4];
        uint2 v2 = *(const uint2*)&Xb[(size_t)s2*256 + 128 + lane*4];
        uint2 v3 = *(const uint2*)&Xb[(size_t)s3*256 + 128 + lane*4];
        a0 += (bflo(v0.x) + bflo(v1.x)) + (bflo(v2.x) + bflo(v3.x));
        a1 += (bfhi(v0.x) + bfhi(v1.x)) + (bfhi(v2.x) + bfhi(v3.x));
        a2 += (bflo(v0.y) + bflo(v1.y)) + (bflo(v2.y) + bflo(v3.y));
        a3 += (bfhi(v0.y) + bfhi(v1.y)) + (bfhi(v2.y) + bfhi(v3.y));
    }
    for (; e < end; e++) {
        uint2 v = *(const uint2*)&Xb[(size_t)csr[e]*256 + 128 + lane*4];
        a0 += bflo(v.x); a1 += bfhi(v.x); a2 += bflo(v.y); a3 += bfhi(v.y);
    }
    float inv = 1.0f / (float)max(dg, 1);
    uint2 o;
    o.x = ((unsigned)bfu(a1*inv) << 16) | (unsigned)bfu(a0*inv);
    o.y = ((unsigned)bfu(a3*inv) << 16) | (unsigned)bfu(a2*inv);
    *(uint2*)&Xb[(size_t)n*256 + lane*4] = o;
}

// ---------------- FUSED conv2 + MLP + softmax (8 waves, 2/SIMD) ----------
// 512 threads share Ws2+Ws1 (128 KB); per-wave 16x128 staging slice with XOR
// swizzle (group' = group ^ row at 16B granularity) -> no padding, 32 KB.
// Total LDS = 160 KB = 1 block/CU = 8 waves/CU = 2 waves/SIMD.
// Cs index (shorts): row*128 + ((colgrp ^ row)<<3) + (col&7), colgrp = col>>3.
__global__ __launch_bounds__(512, 1) void conv2mlp_k(const __hip_bfloat16* __restrict__ Xb,
        const __hip_bfloat16* __restrict__ Wpk2, const float* __restrict__ bl2,
        const __hip_bfloat16* __restrict__ Wpk1, const float* __restrict__ b1,
        const __hip_bfloat16* __restrict__ W2pk, const float* __restrict__ b2,
        float* __restrict__ out) {
    __shared__ short Ws2[32768];         // conv2 weights [ks8][nt8][lane64][j8]
    __shared__ short Ws1[32768];         // W1 weights [ks4][nt16][lane64][j8]
    __shared__ short Cs[8 * 16 * 128];   // per-wave 16x128 swizzled staging
    int tid = threadIdx.x;
    int lane = tid & 63, wave = tid >> 6;
    int quad = lane >> 4, m = lane & 15, c0 = lane & 15;
    {
        // 512 threads x 8 iters x 16 B = exactly 64 KB per array (r9 bug: was 16)
        const float4* s2 = (const float4*)Wpk2;
        const float4* s1 = (const float4*)Wpk1;
        float4* d2 = (float4*)Ws2;
        float4* d1 = (float4*)Ws1;
        #pragma unroll
        for (int i = 0; i < 8; i++) {
            d2[tid + i*512] = s2[tid + i*512];
            d1[tid + i*512] = s1[tid + i*512];
        }
    }
    // W2 fragments + biases -> registers (persistent)
    short8 w2f[8];
    #pragma unroll
    for (int ks = 0; ks < 8; ks++)
        w2f[ks] = *(const short8*)&W2pk[(ks*64 + lane)*8];
    float bl2r[8], b1r[16];
    #pragma unroll
    for (int nt = 0; nt < 8; nt++) bl2r[nt] = bl2[nt*16 + c0];
    #pragma unroll
    for (int nt = 0; nt < 16; nt++) b1r[nt] = b1[nt*16 + c0];
    float b2v = (c0 < CDIM) ? b2[c0] : 0.f;
    __syncthreads();
    short* Tw = &Cs[wave * (16 * 128)];

    int tile = blockIdx.x;
    short8 areg[8];
    {
        int row = tile*128 + wave*16 + m;
        int rowL = row < N_NODES ? row : N_NODES - 1;
        const short* Arow = (const short*)Xb + (size_t)rowL * 256;
        #pragma unroll
        for (int ks = 0; ks < 8; ks++)
            areg[ks] = *(const short8*)(Arow + ks*32 + quad*8);
    }
    for (; tile < NT128; tile += gridDim.x) {
        // prefetch next tile's A fragments
        short8 anext[8];
        {
            int tnext = tile + gridDim.x;
            int rown = (tnext < NT128) ? (tnext*128 + wave*16 + m) : 0;
            int rowNL = rown < N_NODES ? rown : N_NODES - 1;
            const short* ArowN = (const short*)Xb + (size_t)rowNL * 256;
            #pragma unroll
            for (int ks = 0; ks < 8; ks++)
                anext[ks] = *(const short8*)(ArowN + ks*32 + quad*8);
        }
        // ---- conv2: h2 = tanh([agg2|h1] @ W' + bl2)
        floatx4 acc2[8];
        #pragma unroll
        for (int i = 0; i < 8; i++)
            #pragma unroll
            for (int r = 0; r < 4; r++) acc2[i][r] = 0.f;
        #pragma unroll
        for (int ks = 0; ks < 8; ks++) {
            #pragma unroll
            for (int nt = 0; nt < 8; nt++) {
                short8 b = *(const short8*)&Ws2[((ks*8 + nt)*64 + lane)*8];
                acc2[nt] = __builtin_amdgcn_mfma_f32_16x16x32_bf16(areg[ks], b, acc2[nt], 0, 0, 0);
            }
        }
        #pragma unroll
        for (int nt = 0; nt < 8; nt++) {
            int cg = nt*2 + (c0 >> 3);
            #pragma unroll
            for (int r = 0; r < 4; r++) {
                int row = quad*4 + r;
                Tw[row*128 + ((cg ^ row) << 3) + (c0 & 7)] =
                    (short)bfu(tanhf(acc2[nt][r] + bl2r[nt]));
            }
        }
        // ---- GEMM1: t_pre = h2 @ W1^T  (A from the slice just written)
        floatx4 acc1[16];
        #pragma unroll
        for (int i = 0; i < 16; i++)
            #pragma unroll
            for (int r = 0; r < 4; r++) acc1[i][r] = 0.f;
        #pragma unroll
        for (int ks = 0; ks < 4; ks++) {
            short8 a = *(const short8*)&Tw[m*128 + (((ks*4 + quad) ^ m) << 3)];
            #pragma unroll
            for (int nt = 0; nt < 16; nt++) {
                short8 b = *(const short8*)&Ws1[((ks*16 + nt)*64 + lane)*8];
                acc1[nt] = __builtin_amdgcn_mfma_f32_16x16x32_bf16(a, b, acc1[nt], 0, 0, 0);
            }
        }
        // ---- GEMM2 in 4 K-chunks through the (now dead) slice
        floatx4 lacc;
        #pragma unroll
        for (int r = 0; r < 4; r++) lacc[r] = 0.f;
        #pragma unroll
        for (int ch = 0; ch < 4; ch++) {
            #pragma unroll
            for (int ntl = 0; ntl < 4; ntl++) {
                int nt = ch*4 + ntl;
                int cg = ntl*2 + (c0 >> 3);
                #pragma unroll
                for (int r = 0; r < 4; r++) {
                    int row = quad*4 + r;
                    Tw[row*128 + ((cg ^ row) << 3) + (c0 & 7)] =
                        (short)bfu(tanhf(acc1[nt][r] + b1r[nt]));
                }
            }
            #pragma unroll
            for (int k2 = 0; k2 < 2; k2++) {
                short8 a = *(const short8*)&Tw[m*128 + (((k2*4 + quad) ^ m) << 3)];
                lacc = __builtin_amdgcn_mfma_f32_16x16x32_bf16(a, w2f[ch*2 + k2], lacc, 0, 0, 0);
            }
        }
        // ---- softmax across the 8 class lanes
        int rbase = tile*128 + wave*16 + quad*4;
        #pragma unroll
        for (int r = 0; r < 4; r++) {
            float v = lacc[r] + b2v;
            float mval = (c0 < CDIM) ? v : -INFINITY;
            #pragma unroll
            for (int off = 1; off < 8; off <<= 1)
                mval = fmaxf(mval, __shfl_xor(mval, off));
            float e = (c0 < CDIM) ? expf(v - mval) : 0.f;
            float ssum = e;
            #pragma unroll
            for (int off = 1; off < 8; off <<= 1)
                ssum += __shfl_xor(ssum, off);
            int rowg = rbase + r;
            if (c0 < CDIM && rowg < N_NODES)
                out[(size_t)rowg*CDIM + c0] = e / ssum;
        }
        #pragma unroll
        for (int ks = 0; ks < 8; ks++) areg[ks] = anext[ks];
    }
}

extern "C" void kernel_launch(void* const* d_in, const int* in_sizes, int n_in,
                              void* d_out, int out_size, void* d_ws, size_t ws_size,
                              hipStream_t stream) {
    const float* x   = (const float*)d_in[0];
    const int*   ei  = (const int*)d_in[1];
    const float* Wl1 = (const float*)d_in[2];
    const float* bl1 = (const float*)d_in[3];
    const float* Wr1 = (const float*)d_in[4];
    const float* Wl2 = (const float*)d_in[5];
    const float* bl2 = (const float*)d_in[6];
    const float* Wr2 = (const float*)d_in[7];
    const float* W1  = (const float*)d_in[8];
    const float* b1  = (const float*)d_in[9];
    const float* W2  = (const float*)d_in[10];
    const float* b2  = (const float*)d_in[11];

    float* ws     = (float*)d_ws;
    float* part   = ws + OFF_PART;
    int*   deg    = (int*)(ws + OFF_DEG);
    int*   rowptr = (int*)(ws + OFF_ROWPTR);
    int*   bsums  = (int*)(ws + OFF_BSUMS);
    float4* h0    = (float4*)(ws + OFF_H0);
    int*   csr    = (int*)(ws + OFF_CSR);
    __hip_bfloat16* Wpk2 = (__hip_bfloat16*)(ws + OFF_WPK2);
    __hip_bfloat16* Wpk1 = (__hip_bfloat16*)(ws + OFF_WPK1);
    __hip_bfloat16* W2pk = (__hip_bfloat16*)(ws + OFF_W2PK);
    __hip_bfloat16* Xb   = (__hip_bfloat16*)(ws + OFF_XB);

    const int nb_scan = (N_NODES + 1023) / 1024;   // 98

    stats_partial_k<<<NB_STATS, 256, 0, stream>>>(x, part, deg);
    normalize_k<<<(N_NODES + 255) / 256, 256, 0, stream>>>(x, part, h0,
            Wl2, Wr2, W1, W2, Wpk2, Wpk1, W2pk);
    deg_count_k<<<(N_EDGES + 255) / 256, 256, 0, stream>>>(ei, deg);
    scan1_k<<<nb_scan, 256, 0, stream>>>(deg, rowptr, bsums);
    scan3_k<<<nb_scan, 256, 0, stream>>>(rowptr, bsums, nb_scan);
    scatter_k<<<(N_EDGES + 255) / 256, 256, 0, stream>>>(ei, rowptr, csr);

    agg1conv1_k<<<(N_NODES + 255) / 256, 256, 0, stream>>>(h0, rowptr, deg, csr,
            Wl1, bl1, Wr1, Xb);
    agg2_k<<<N_NODES / 8, 256, 0, stream>>>(Xb, rowptr, deg, csr);
    conv2mlp_k<<<256, 512, 0, stream>>>(Xb, Wpk2, bl2, Wpk1, b1, W2pk, b2,
            (float*)d_out);
}

// Round 11
// 270.305 us; speedup vs baseline: 6.0970x; 1.0280x over previous
//
#include <hip/hip_runtime.h>
#include <hip/hip_bf16.h>
#include <math.h>

#define N_NODES 100000
#define N_EDGES 600000
#define H 128
#define LH 256
#define CDIM 8
#define NB_STATS 64
#define NT128 ((N_NODES + 127) / 128)   // 782 (128-row tiles, fused kernel)

typedef __attribute__((ext_vector_type(8))) short short8;
typedef __attribute__((ext_vector_type(4))) float floatx4;

// ------------- workspace layout (4-byte words) -------------
#define OFF_PART   0
#define OFF_PARAMS 704
#define OFF_DEG    712
#define OFF_ROWPTR (OFF_DEG + N_NODES)
#define OFF_BSUMS  (OFF_ROWPTR + N_NODES)
#define OFF_H0     (OFF_BSUMS + 128)            // N*4 fp32 (float4 rows)
#define OFF_AGG1   (OFF_H0 + N_NODES*4)         // (unused, kept for layout)
#define OFF_CSR    (OFF_AGG1 + N_NODES*4)
#define OFF_WPK2   (OFF_CSR + N_EDGES)          // 32768 bf16 = 16384 words
#define OFF_WPK1   (OFF_WPK2 + 16384)           // 32768 bf16
#define OFF_W2PK   (OFF_WPK1 + 16384)           // 4096 bf16 = 2048 words
#define OFF_XB     (OFF_W2PK + 2048)            // N*256 bf16 = 12.8M words

__device__ __forceinline__ float rot_c() { return cosf(1.57079632679489661923f); }
__device__ __forceinline__ float rot_s() { return sinf(1.57079632679489661923f); }
__device__ __forceinline__ float bfhi(unsigned v) { return __uint_as_float(v & 0xffff0000u); }
__device__ __forceinline__ float bflo(unsigned v) { return __uint_as_float(v << 16); }
__device__ __forceinline__ unsigned short bfu(float f) {
    __hip_bfloat16 h = __float2bfloat16(f);
    return *(unsigned short*)&h;
}
// fast tanh: 1 - 2/(e^{2x}+1). Exact at +-inf (rcp(inf)=0), rel err ~1e-6,
// far below bf16 quantization (~4e-3). ~5 VALU ops vs ~40 for libm tanhf.
__device__ __forceinline__ float ftanh(float x) {
    float e = __expf(2.0f * x);
    return 1.0f - 2.0f * __builtin_amdgcn_rcpf(e + 1.0f);
}

// ---------------- stats partial (also zeroes deg) ----------------
__global__ void stats_partial_k(const float* __restrict__ x, float* __restrict__ part,
                                int* __restrict__ deg) {
    const float c = rot_c(), sn = rot_s();
    float mn0 = INFINITY, mx0 = -INFINITY, mn1 = INFINITY, mx1 = -INFINITY;
    float s0 = 0.f, s1 = 0.f, sr0 = 0.f, sr1 = 0.f;
    float mxr0 = -INFINITY, mxr1 = -INFINITY, mxa = -INFINITY;
    for (int i = blockIdx.x * blockDim.x + threadIdx.x; i < N_NODES;
         i += gridDim.x * blockDim.x) {
        deg[i] = 0;
        float x0 = x[3*i], x1 = x[3*i+1], a = x[3*i+2];
        float r0 = c*x0 - sn*x1;
        float r1 = sn*x0 + c*x1;
        mn0 = fminf(mn0, x0); mx0 = fmaxf(mx0, x0);
        mn1 = fminf(mn1, x1); mx1 = fmaxf(mx1, x1);
        s0 += x0; s1 += x1; sr0 += r0; sr1 += r1;
        mxr0 = fmaxf(mxr0, r0); mxr1 = fmaxf(mxr1, r1);
        mxa = fmaxf(mxa, a);
    }
    __shared__ float red[256];
    float vals[11] = {mn0, mx0, mn1, mx1, s0, s1, sr0, sr1, mxr0, mxr1, mxa};
    const int ops[11] = {0,1,0,1,2,2,2,2,1,1,1};
    for (int v = 0; v < 11; v++) {
        red[threadIdx.x] = vals[v];
        __syncthreads();
        for (int s = 128; s > 0; s >>= 1) {
            if ((int)threadIdx.x < s) {
                float a = red[threadIdx.x], b = red[threadIdx.x + s];
                red[threadIdx.x] = (ops[v]==0) ? fminf(a,b) : (ops[v]==1) ? fmaxf(a,b) : (a+b);
            }
            __syncthreads();
        }
        if (threadIdx.x == 0) part[blockIdx.x * 11 + v] = red[0];
        __syncthreads();
    }
}

// ---------------- normalize (+ final stats reduce + weight pre-pack) ------
__global__ __launch_bounds__(256) void normalize_k(const float* __restrict__ x,
        const float* __restrict__ part, float4* __restrict__ h0,
        const float* __restrict__ Wl2, const float* __restrict__ Wr2,
        const float* __restrict__ W1, const float* __restrict__ W2,
        __hip_bfloat16* __restrict__ Wpk2, __hip_bfloat16* __restrict__ Wpk1,
        __hip_bfloat16* __restrict__ W2pk) {
    __shared__ float res[11];
    int tid = threadIdx.x;
    if (tid < 64) {
        const int ops[11] = {0,1,0,1,2,2,2,2,1,1,1};
        for (int v = 0; v < 11; v++) {
            float val = part[tid * 11 + v];
            #pragma unroll
            for (int off = 32; off > 0; off >>= 1) {
                float o = __shfl_down(val, off);
                val = (ops[v]==0) ? fminf(val,o) : (ops[v]==1) ? fmaxf(val,o) : (val+o);
            }
            if (tid == 0) res[v] = val;
        }
    }
    __syncthreads();
    int rotate = (res[3] - res[2]) > (res[1] - res[0]);
    float mean0 = (rotate ? res[6] : res[4]) / (float)N_NODES;
    float mean1 = (rotate ? res[7] : res[5]) / (float)N_NODES;
    float imx0  = 1.0f / (rotate ? res[8] : res[1]);
    float imx1  = 1.0f / (rotate ? res[9] : res[3]);
    float imxa  = 1.0f / res[10];

    int i = blockIdx.x * blockDim.x + tid;
    if (i < N_NODES) {
        const float c = rot_c(), sn = rot_s();
        float x0 = x[3*i], x1 = x[3*i+1], a = x[3*i+2];
        float u0 = rotate ? (c*x0 - sn*x1) : x0;
        float u1 = rotate ? (sn*x0 + c*x1) : x1;
        h0[i] = make_float4((u0 - mean0) * imx0, (u1 - mean1) * imx1, a * imxa, 0.f);
    }
    int idx = i;
    if (idx < 32768) {                       // Wpk2[ks8][nt8][lane64][j8], K=256,N=128
        int j = idx & 7, lane = (idx >> 3) & 63, nt = (idx >> 9) & 7, ks = idx >> 12;
        int k = ks*32 + (lane >> 4)*8 + j;
        int n = nt*16 + (lane & 15);
        float v = (k < 128) ? Wl2[n*H + k] : Wr2[n*H + (k - 128)];
        Wpk2[idx] = __float2bfloat16(v);
    } else if (idx < 65536) {                // Wpk1[ks4][nt16][lane64][j8], K=128,N=256
        int i2 = idx - 32768;
        int j = i2 & 7, lane = (i2 >> 3) & 63, nt = (i2 >> 9) & 15, ks = i2 >> 13;
        int k = ks*32 + (lane >> 4)*8 + j;
        int n = nt*16 + (lane & 15);
        Wpk1[i2] = __float2bfloat16(W1[n*H + k]);
    } else if (idx < 69632) {                // W2pk[ks8][lane64][j8], K=256,N=16(8 real)
        int i3 = idx - 65536;
        int j = i3 & 7, lane = (i3 >> 3) & 63, ks = i3 >> 9;
        int k = ks*32 + (lane >> 4)*8 + j;
        int n = lane & 15;
        W2pk[i3] = __float2bfloat16((n < CDIM) ? W2[n*LH + k] : 0.f);
    }
}

// ---------------- CSR build ----------------
__global__ void deg_count_k(const int* __restrict__ ei, int* __restrict__ deg) {
    int e = blockIdx.x * blockDim.x + threadIdx.x;
    if (e >= N_EDGES) return;
    atomicAdd(&deg[ei[N_EDGES + e]], 1);
}

__global__ void scan1_k(const int* __restrict__ deg, int* __restrict__ rowptr,
                        int* __restrict__ bsums) {
    __shared__ int s[256];
    int t = threadIdx.x;
    int base = blockIdx.x * 1024 + t * 4;
    int d0 = (base+0 < N_NODES) ? deg[base+0] : 0;
    int d1 = (base+1 < N_NODES) ? deg[base+1] : 0;
    int d2 = (base+2 < N_NODES) ? deg[base+2] : 0;
    int d3 = (base+3 < N_NODES) ? deg[base+3] : 0;
    int tsum = d0 + d1 + d2 + d3;
    s[t] = tsum;
    __syncthreads();
    for (int off = 1; off < 256; off <<= 1) {
        int v = (t >= off) ? s[t - off] : 0;
        __syncthreads();
        s[t] += v;
        __syncthreads();
    }
    int excl = s[t] - tsum;
    if (base+0 < N_NODES) rowptr[base+0] = excl;
    if (base+1 < N_NODES) rowptr[base+1] = excl + d0;
    if (base+2 < N_NODES) rowptr[base+2] = excl + d0 + d1;
    if (base+3 < N_NODES) rowptr[base+3] = excl + d0 + d1 + d2;
    if (t == 255) bsums[blockIdx.x] = s[255];
}

// scan3 with folded scan2: add = sum of bsums[0..blockIdx-1]
__global__ void scan3_k(int* __restrict__ rowptr, const int* __restrict__ bsums, int nb) {
    __shared__ int sb[256];
    int t = threadIdx.x;
    sb[t] = (t < (int)blockIdx.x && t < nb) ? bsums[t] : 0;
    __syncthreads();
    for (int s = 128; s > 0; s >>= 1) {
        if (t < s) sb[t] += sb[t + s];
        __syncthreads();
    }
    int add = sb[0];
    int base = blockIdx.x * 1024 + t * 4;
    if (base+0 < N_NODES) rowptr[base+0] += add;
    if (base+1 < N_NODES) rowptr[base+1] += add;
    if (base+2 < N_NODES) rowptr[base+2] += add;
    if (base+3 < N_NODES) rowptr[base+3] += add;
}

__global__ void scatter_k(const int* __restrict__ ei, int* __restrict__ rowptr,
                          int* __restrict__ csr) {
    int e = blockIdx.x * blockDim.x + threadIdx.x;
    if (e >= N_EDGES) return;
    int d = ei[N_EDGES + e];
    int pos = atomicAdd(&rowptr[d], 1);
    csr[pos] = ei[e];
}

// ---------------- fused agg1 + conv1 dense ----------------
__global__ __launch_bounds__(256) void agg1conv1_k(const float4* __restrict__ h0,
        const int* __restrict__ rowptr, const int* __restrict__ deg,
        const int* __restrict__ csr,
        const float* __restrict__ Wl1, const float* __restrict__ bl1,
        const float* __restrict__ Wr1, __hip_bfloat16* __restrict__ Xb) {
    __shared__ float wl[H*3], wr[H*3], bb[H];
    __shared__ float4 sa[256];
    int tid = threadIdx.x;
    for (int i = tid; i < H*3; i += 256) { wl[i] = Wl1[i]; wr[i] = Wr1[i]; }
    if (tid < H) bb[tid] = bl1[tid];
    int base = blockIdx.x * 256;
    int n = base + tid;
    float4 av = make_float4(0.f, 0.f, 0.f, 0.f);
    if (n < N_NODES) {
        int dg = deg[n];
        int end = rowptr[n], start = end - dg;
        float a0 = 0.f, a1 = 0.f, a2 = 0.f;
        int e = start;
        for (; e + 3 < end; e += 4) {
            int s0 = csr[e], s1 = csr[e+1], s2 = csr[e+2], s3 = csr[e+3];
            float4 v0 = h0[s0];
            float4 v1 = h0[s1];
            float4 v2 = h0[s2];
            float4 v3 = h0[s3];
            a0 += (v0.x + v1.x) + (v2.x + v3.x);
            a1 += (v0.y + v1.y) + (v2.y + v3.y);
            a2 += (v0.z + v1.z) + (v2.z + v3.z);
        }
        for (; e < end; e++) {
            float4 v = h0[csr[e]];
            a0 += v.x; a1 += v.y; a2 += v.z;
        }
        float inv = 1.0f / (float)max(dg, 1);
        av = make_float4(a0 * inv, a1 * inv, a2 * inv, 0.f);
    }
    sa[tid] = av;
    __syncthreads();
    int sub = tid >> 6;
    int j2 = (tid & 63) * 2;
    for (int i = 0; i < 64; i++) {
        int loc = i * 4 + sub;
        int nn = base + loc;
        if (nn >= N_NODES) break;
        float4 a = sa[loc];
        float4 xv = h0[nn];
        float o0 = wl[3*j2+0]*a.x + wl[3*j2+1]*a.y + wl[3*j2+2]*a.z + bb[j2]
                 + wr[3*j2+0]*xv.x + wr[3*j2+1]*xv.y + wr[3*j2+2]*xv.z;
        float o1 = wl[3*j2+3]*a.x + wl[3*j2+4]*a.y + wl[3*j2+5]*a.z + bb[j2+1]
                 + wr[3*j2+3]*xv.x + wr[3*j2+4]*xv.y + wr[3*j2+5]*xv.z;
        unsigned pv = ((unsigned)bfu(ftanh(o1)) << 16) | (unsigned)bfu(ftanh(o0));
        *(unsigned*)&Xb[(size_t)nn*256 + 128 + j2] = pv;
    }
}

// ---------------- agg2: mean of h1 (bf16) -> Xb[n][0..127]
// half-wave (32 lanes) per node, 4 cols/lane: 32*4 = exactly 128 cols.
__global__ void agg2_k(__hip_bfloat16* __restrict__ Xb, const int* __restrict__ rowptr,
                       const int* __restrict__ deg, const int* __restrict__ csr) {
    int lane = threadIdx.x & 31;
    int n = blockIdx.x * 8 + (threadIdx.x >> 5);
    int dg = deg[n];
    int end = rowptr[n], start = end - dg;
    float a0 = 0.f, a1 = 0.f, a2 = 0.f, a3 = 0.f;
    int e = start;
    for (; e + 3 < end; e += 4) {
        int s0 = csr[e], s1 = csr[e+1], s2 = csr[e+2], s3 = csr[e+3];
        uint2 v0 = *(const uint2*)&Xb[(size_t)s0*256 + 128 + lane*4];
        uint2 v1 = *(const uint2*)&Xb[(size_t)s1*256 + 128 + lane*4];
        uint2 v2 = *(const uint2*)&Xb[(size_t)s2*256 + 128 + lane*4];
        uint2 v3 = *(const uint2*)&Xb[(size_t)s3*256 + 128 + lane*4];
        a0 += (bflo(v0.x) + bflo(v1.x)) + (bflo(v2.x) + bflo(v3.x));
        a1 += (bfhi(v0.x) + bfhi(v1.x)) + (bfhi(v2.x) + bfhi(v3.x));
        a2 += (bflo(v0.y) + bflo(v1.y)) + (bflo(v2.y) + bflo(v3.y));
        a3 += (bfhi(v0.y) + bfhi(v1.y)) + (bfhi(v2.y) + bfhi(v3.y));
    }
    for (; e < end; e++) {
        uint2 v = *(const uint2*)&Xb[(size_t)csr[e]*256 + 128 + lane*4];
        a0 += bflo(v.x); a1 += bfhi(v.x); a2 += bflo(v.y); a3 += bfhi(v.y);
    }
    float inv = 1.0f / (float)max(dg, 1);
    uint2 o;
    o.x = ((unsigned)bfu(a1*inv) << 16) | (unsigned)bfu(a0*inv);
    o.y = ((unsigned)bfu(a3*inv) << 16) | (unsigned)bfu(a2*inv);
    *(uint2*)&Xb[(size_t)n*256 + lane*4] = o;
}

// ---------------- FUSED conv2 + MLP + softmax (8 waves, 2/SIMD) ----------
// 512 threads share Ws2+Ws1 (128 KB); per-wave 16x128 staging slice with XOR
// swizzle (group' = group ^ row at 16B granularity) -> no padding, 32 KB.
// Total LDS = 160 KB = 1 block/CU = 8 waves/CU = 2 waves/SIMD.
// Cs index (shorts): row*128 + ((colgrp ^ row)<<3) + (col&7), colgrp = col>>3.
__global__ __launch_bounds__(512, 1) void conv2mlp_k(const __hip_bfloat16* __restrict__ Xb,
        const __hip_bfloat16* __restrict__ Wpk2, const float* __restrict__ bl2,
        const __hip_bfloat16* __restrict__ Wpk1, const float* __restrict__ b1,
        const __hip_bfloat16* __restrict__ W2pk, const float* __restrict__ b2,
        float* __restrict__ out) {
    __shared__ short Ws2[32768];         // conv2 weights [ks8][nt8][lane64][j8]
    __shared__ short Ws1[32768];         // W1 weights [ks4][nt16][lane64][j8]
    __shared__ short Cs[8 * 16 * 128];   // per-wave 16x128 swizzled staging
    int tid = threadIdx.x;
    int lane = tid & 63, wave = tid >> 6;
    int quad = lane >> 4, m = lane & 15, c0 = lane & 15;
    {
        // 512 threads x 8 iters x 16 B = exactly 64 KB per array
        const float4* s2 = (const float4*)Wpk2;
        const float4* s1 = (const float4*)Wpk1;
        float4* d2 = (float4*)Ws2;
        float4* d1 = (float4*)Ws1;
        #pragma unroll
        for (int i = 0; i < 8; i++) {
            d2[tid + i*512] = s2[tid + i*512];
            d1[tid + i*512] = s1[tid + i*512];
        }
    }
    // W2 fragments + biases -> registers (persistent)
    short8 w2f[8];
    #pragma unroll
    for (int ks = 0; ks < 8; ks++)
        w2f[ks] = *(const short8*)&W2pk[(ks*64 + lane)*8];
    float bl2r[8], b1r[16];
    #pragma unroll
    for (int nt = 0; nt < 8; nt++) bl2r[nt] = bl2[nt*16 + c0];
    #pragma unroll
    for (int nt = 0; nt < 16; nt++) b1r[nt] = b1[nt*16 + c0];
    float b2v = (c0 < CDIM) ? b2[c0] : 0.f;
    __syncthreads();
    short* Tw = &Cs[wave * (16 * 128)];

    int tile = blockIdx.x;
    short8 areg[8];
    {
        int row = tile*128 + wave*16 + m;
        int rowL = row < N_NODES ? row : N_NODES - 1;
        const short* Arow = (const short*)Xb + (size_t)rowL * 256;
        #pragma unroll
        for (int ks = 0; ks < 8; ks++)
            areg[ks] = *(const short8*)(Arow + ks*32 + quad*8);
    }
    for (; tile < NT128; tile += gridDim.x) {
        // prefetch next tile's A fragments
        short8 anext[8];
        {
            int tnext = tile + gridDim.x;
            int rown = (tnext < NT128) ? (tnext*128 + wave*16 + m) : 0;
            int rowNL = rown < N_NODES ? rown : N_NODES - 1;
            const short* ArowN = (const short*)Xb + (size_t)rowNL * 256;
            #pragma unroll
            for (int ks = 0; ks < 8; ks++)
                anext[ks] = *(const short8*)(ArowN + ks*32 + quad*8);
        }
        // ---- conv2: h2 = tanh([agg2|h1] @ W' + bl2)
        floatx4 acc2[8];
        #pragma unroll
        for (int i = 0; i < 8; i++)
            #pragma unroll
            for (int r = 0; r < 4; r++) acc2[i][r] = 0.f;
        #pragma unroll
        for (int ks = 0; ks < 8; ks++) {
            #pragma unroll
            for (int nt = 0; nt < 8; nt++) {
                short8 b = *(const short8*)&Ws2[((ks*8 + nt)*64 + lane)*8];
                acc2[nt] = __builtin_amdgcn_mfma_f32_16x16x32_bf16(areg[ks], b, acc2[nt], 0, 0, 0);
            }
        }
        #pragma unroll
        for (int nt = 0; nt < 8; nt++) {
            int cg = nt*2 + (c0 >> 3);
            #pragma unroll
            for (int r = 0; r < 4; r++) {
                int row = quad*4 + r;
                Tw[row*128 + ((cg ^ row) << 3) + (c0 & 7)] =
                    (short)bfu(ftanh(acc2[nt][r] + bl2r[nt]));
            }
        }
        // ---- GEMM1: t_pre = h2 @ W1^T  (A from the slice just written)
        floatx4 acc1[16];
        #pragma unroll
        for (int i = 0; i < 16; i++)
            #pragma unroll
            for (int r = 0; r < 4; r++) acc1[i][r] = 0.f;
        #pragma unroll
        for (int ks = 0; ks < 4; ks++) {
            short8 a = *(const short8*)&Tw[m*128 + (((ks*4 + quad) ^ m) << 3)];
            #pragma unroll
            for (int nt = 0; nt < 16; nt++) {
                short8 b = *(const short8*)&Ws1[((ks*16 + nt)*64 + lane)*8];
                acc1[nt] = __builtin_amdgcn_mfma_f32_16x16x32_bf16(a, b, acc1[nt], 0, 0, 0);
            }
        }
        // ---- GEMM2 in 4 K-chunks through the (now dead) slice
        floatx4 lacc;
        #pragma unroll
        for (int r = 0; r < 4; r++) lacc[r] = 0.f;
        #pragma unroll
        for (int ch = 0; ch < 4; ch++) {
            #pragma unroll
            for (int ntl = 0; ntl < 4; ntl++) {
                int nt = ch*4 + ntl;
                int cg = ntl*2 + (c0 >> 3);
                #pragma unroll
                for (int r = 0; r < 4; r++) {
                    int row = quad*4 + r;
                    Tw[row*128 + ((cg ^ row) << 3) + (c0 & 7)] =
                        (short)bfu(ftanh(acc1[nt][r] + b1r[nt]));
                }
            }
            #pragma unroll
            for (int k2 = 0; k2 < 2; k2++) {
                short8 a = *(const short8*)&Tw[m*128 + (((k2*4 + quad) ^ m) << 3)];
                lacc = __builtin_amdgcn_mfma_f32_16x16x32_bf16(a, w2f[ch*2 + k2], lacc, 0, 0, 0);
            }
        }
        // ---- softmax across the 8 class lanes
        int rbase = tile*128 + wave*16 + quad*4;
        #pragma unroll
        for (int r = 0; r < 4; r++) {
            float v = lacc[r] + b2v;
            float mval = (c0 < CDIM) ? v : -INFINITY;
            #pragma unroll
            for (int off = 1; off < 8; off <<= 1)
                mval = fmaxf(mval, __shfl_xor(mval, off));
            float e = (c0 < CDIM) ? __expf(v - mval) : 0.f;
            float ssum = e;
            #pragma unroll
            for (int off = 1; off < 8; off <<= 1)
                ssum += __shfl_xor(ssum, off);
            int rowg = rbase + r;
            if (c0 < CDIM && rowg < N_NODES)
                out[(size_t)rowg*CDIM + c0] = e / ssum;
        }
        #pragma unroll
        for (int ks = 0; ks < 8; ks++) areg[ks] = anext[ks];
    }
}

extern "C" void kernel_launch(void* const* d_in, const int* in_sizes, int n_in,
                              void* d_out, int out_size, void* d_ws, size_t ws_size,
                              hipStream_t stream) {
    const float* x   = (const float*)d_in[0];
    const int*   ei  = (const int*)d_in[1];
    const float* Wl1 = (const float*)d_in[2];
    const float* bl1 = (const float*)d_in[3];
    const float* Wr1 = (const float*)d_in[4];
    const float* Wl2 = (const float*)d_in[5];
    const float* bl2 = (const float*)d_in[6];
    const float* Wr2 = (const float*)d_in[7];
    const float* W1  = (const float*)d_in[8];
    const float* b1  = (const float*)d_in[9];
    const float* W2  = (const float*)d_in[10];
    const float* b2  = (const float*)d_in[11];

    float* ws     = (float*)d_ws;
    float* part   = ws + OFF_PART;
    int*   deg    = (int*)(ws + OFF_DEG);
    int*   rowptr = (int*)(ws + OFF_ROWPTR);
    int*   bsums  = (int*)(ws + OFF_BSUMS);
    float4* h0    = (float4*)(ws + OFF_H0);
    int*   csr    = (int*)(ws + OFF_CSR);
    __hip_bfloat16* Wpk2 = (__hip_bfloat16*)(ws + OFF_WPK2);
    __hip_bfloat16* Wpk1 = (__hip_bfloat16*)(ws + OFF_WPK1);
    __hip_bfloat16* W2pk = (__hip_bfloat16*)(ws + OFF_W2PK);
    __hip_bfloat16* Xb   = (__hip_bfloat16*)(ws + OFF_XB);

    const int nb_scan = (N_NODES + 1023) / 1024;   // 98

    stats_partial_k<<<NB_STATS, 256, 0, stream>>>(x, part, deg);
    normalize_k<<<(N_NODES + 255) / 256, 256, 0, stream>>>(x, part, h0,
            Wl2, Wr2, W1, W2, Wpk2, Wpk1, W2pk);
    deg_count_k<<<(N_EDGES + 255) / 256, 256, 0, stream>>>(ei, deg);
    scan1_k<<<nb_scan, 256, 0, stream>>>(deg, rowptr, bsums);
    scan3_k<<<nb_scan, 256, 0, stream>>>(rowptr, bsums, nb_scan);
    scatter_k<<<(N_EDGES + 255) / 256, 256, 0, stream>>>(ei, rowptr, csr);

    agg1conv1_k<<<(N_NODES + 255) / 256, 256, 0, stream>>>(h0, rowptr, deg, csr,
            Wl1, bl1, Wr1, Xb);
    agg2_k<<<N_NODES / 8, 256, 0, stream>>>(Xb, rowptr, deg, csr);
    conv2mlp_k<<<256, 512, 0, stream>>>(Xb, Wpk2, bl2, Wpk1, b1, W2pk, b2,
            (float*)d_out);
}